// Round 1
// baseline (1265.713 us; speedup 1.0000x reference)
//
#include <hip/hip_runtime.h>
#include <math.h>

// Problem dims: B=16, N=64, D=512, H=512, R=8, HK=64, G=2
// Outputs: f_emb [16,64,64,64,2] (8388608 f32) then logits [16,512] (8192 f32)

// ---------------- workspace layout (float offsets), total ~65 MB ----------------
#define WS_NRM 0                      // 19 norms (pad 32)
#define WS_VT  32                     // v_t [1024][512]
#define WS_QT  (WS_VT  + 524288)      // q_t
#define WS_AT  (WS_QT  + 524288)      // a_t
#define WS_VRT (WS_AT  + 524288)      // v_r transposed [B][R][h][n]
#define WS_QRT (WS_VRT + 524288)      // q_r transposed [B][R][k][q]
#define WS_AR  (WS_QRT + 524288)      // a_r natural    [B][R][m][l]
#define WS_T4  (WS_AR  + 524288)      // T repack [g][r][l][h][k]  (4194304)
#define WS_P1  (WS_T4  + 4194304)     // rh=1 partial [g][b][v][q][m] (8388608)
#define WS_LP  (WS_P1  + 8388608)     // logits per-v partial [b][v][d] (524288)
#define WS_LR  (WS_LP  + 524288)      // raw logits [b][d] (8192)

// ---------------- K0: weight norms ----------------
__global__ __launch_bounds__(256) void k_norms(
    const float* __restrict__ Vv, const float* __restrict__ Vq, const float* __restrict__ Va,
    const float* __restrict__ Vnv, const float* __restrict__ Vnqa, float* __restrict__ wsn)
{
  int nb = blockIdx.x;
  const float* p; int cnt;
  if (nb < 3)       { p = (nb == 0 ? Vv : nb == 1 ? Vq : Va); cnt = 512 * 512; }
  else if (nb < 11) { p = Vnv  + (nb - 3) * 64 * 512; cnt = 64 * 512; }
  else              { p = Vnqa + (nb - 11) * 64 * 512; cnt = 64 * 512; }
  float s = 0.f;
  for (int i = threadIdx.x; i < cnt; i += 256) { float x = p[i]; s += x * x; }
  __shared__ float red[256];
  red[threadIdx.x] = s; __syncthreads();
  for (int off = 128; off > 0; off >>= 1) {
    if (threadIdx.x < off) red[threadIdx.x] += red[threadIdx.x + off];
    __syncthreads();
  }
  if (threadIdx.x == 0) wsn[nb] = sqrtf(red[0]);
}

// ---------------- KT: repack T_g[r][h][k][l][g] -> T4[g][r][l][h][k] ----------------
__global__ __launch_bounds__(256) void k_repack(const float* __restrict__ Tg, float* __restrict__ T4)
{
  int r = blockIdx.x >> 6, h = blockIdx.x & 63;
  const float2* in2 = (const float2*)(Tg + ((size_t)(r * 64 + h) * 64) * 128);
  __shared__ __align__(16) float t0[64][65];
  __shared__ __align__(16) float t1[64][65];
  int tid = threadIdx.x;
  {
    int l = tid & 63, kq = tid >> 6;
    #pragma unroll
    for (int p = 0; p < 16; ++p) {
      int k = p * 4 + kq;
      float2 v = in2[k * 64 + l];
      t0[k][l] = v.x; t1[k][l] = v.y;
    }
  }
  __syncthreads();
  {
    int k = tid & 63, lq = tid >> 6;
    float* o0 = T4 + ((size_t)((0 * 8 + r) * 64)) * 4096 + h * 64;
    float* o1 = T4 + ((size_t)((1 * 8 + r) * 64)) * 4096 + h * 64;
    #pragma unroll
    for (int p = 0; p < 16; ++p) {
      int ll = p * 4 + lq;
      o0[(size_t)ll * 4096 + k] = t0[k][ll];
      o1[(size_t)ll * 4096 + k] = t1[k][ll];
    }
  }
}

// ---------------- K1: v_t/q_t/a_t = relu(x @ (g*V/||V||)^T + b) ----------------
__global__ __launch_bounds__(256) void k_proj(
    const float* __restrict__ inv, const float* __restrict__ inq, const float* __restrict__ ina,
    const float* __restrict__ Wv, const float* __restrict__ Wq, const float* __restrict__ Wa,
    const float* __restrict__ gv, const float* __restrict__ gq, const float* __restrict__ ga,
    const float* __restrict__ bv, const float* __restrict__ bq, const float* __restrict__ ba,
    const float* __restrict__ wsn,
    float* __restrict__ ov, float* __restrict__ oq, float* __restrict__ oa)
{
  const int z = blockIdx.z;
  const float* in   = (z == 0) ? inv : (z == 1) ? inq : ina;
  const float* W    = (z == 0) ? Wv  : (z == 1) ? Wq  : Wa;
  const float* bias = (z == 0) ? bv  : (z == 1) ? bq  : ba;
  float* out        = (z == 0) ? ov  : (z == 1) ? oq  : oa;
  const float scale = ((z == 0) ? gv[0] : (z == 1) ? gq[0] : ga[0]) / wsn[z];

  const int m0 = blockIdx.y * 64, n0 = blockIdx.x * 64;
  __shared__ __align__(16) float As[32][68];
  __shared__ __align__(16) float Bs[32][68];
  const int tid = threadIdx.x;
  const int tx = tid & 15, ty = tid >> 4;
  float c[4][4] = {{0.f}};

  for (int k0 = 0; k0 < 512; k0 += 32) {
    #pragma unroll
    for (int i = 0; i < 8; ++i) {
      int idx = tid + i * 256;
      int kk = idx & 31, rr = idx >> 5;
      As[kk][rr] = in[(m0 + rr) * 512 + k0 + kk];
      Bs[kk][rr] = W[(n0 + rr) * 512 + k0 + kk];
    }
    __syncthreads();
    #pragma unroll
    for (int kk = 0; kk < 32; ++kk) {
      const float4 a4 = *(const float4*)&As[kk][ty * 4];
      const float4 b4 = *(const float4*)&Bs[kk][tx * 4];
      const float aa[4] = {a4.x, a4.y, a4.z, a4.w};
      const float bb[4] = {b4.x, b4.y, b4.z, b4.w};
      #pragma unroll
      for (int i = 0; i < 4; ++i)
        #pragma unroll
        for (int j = 0; j < 4; ++j)
          c[i][j] += aa[i] * bb[j];
    }
    __syncthreads();
  }
  #pragma unroll
  for (int i = 0; i < 4; ++i)
    #pragma unroll
    for (int j = 0; j < 4; ++j) {
      int m = m0 + ty * 4 + i, n = n0 + tx * 4 + j;
      float val = c[i][j] * scale + bias[n];
      out[m * 512 + n] = fmaxf(val, 0.f);
    }
}

// ---------------- K2: per-rank projections (writes v_rT, q_rT transposed; a_r natural) ----------------
__global__ __launch_bounds__(256) void k_rproj(
    const float* __restrict__ vt, const float* __restrict__ qt, const float* __restrict__ at,
    const float* __restrict__ Vnv, const float* __restrict__ Vnqa,
    const float* __restrict__ gnv, const float* __restrict__ gnqa,
    const float* __restrict__ bnv, const float* __restrict__ bnqa,
    const float* __restrict__ wsn,
    float* __restrict__ vrT, float* __restrict__ qrT, float* __restrict__ ar)
{
  const int z = blockIdx.z, r = blockIdx.x, m0 = blockIdx.y * 64;
  const float* in = (z == 0) ? vt : (z == 1) ? qt : at;
  const float* Wn = ((z == 0) ? Vnv : Vnqa) + r * 64 * 512;
  const float scale = (z == 0) ? (gnv[r] / wsn[3 + r]) : (gnqa[r] / wsn[11 + r]);
  const float* bias = ((z == 0) ? bnv : bnqa) + r * 64;

  __shared__ __align__(16) float As[32][68];
  __shared__ __align__(16) float Bs[32][68];
  const int tid = threadIdx.x;
  const int tx = tid & 15, ty = tid >> 4;
  float c[4][4] = {{0.f}};

  for (int k0 = 0; k0 < 512; k0 += 32) {
    #pragma unroll
    for (int i = 0; i < 8; ++i) {
      int idx = tid + i * 256;
      int kk = idx & 31, rr = idx >> 5;
      As[kk][rr] = in[(m0 + rr) * 512 + k0 + kk];
      Bs[kk][rr] = Wn[rr * 512 + k0 + kk];
    }
    __syncthreads();
    #pragma unroll
    for (int kk = 0; kk < 32; ++kk) {
      const float4 a4 = *(const float4*)&As[kk][ty * 4];
      const float4 b4 = *(const float4*)&Bs[kk][tx * 4];
      const float aa[4] = {a4.x, a4.y, a4.z, a4.w};
      const float bb[4] = {b4.x, b4.y, b4.z, b4.w};
      #pragma unroll
      for (int i = 0; i < 4; ++i)
        #pragma unroll
        for (int j = 0; j < 4; ++j)
          c[i][j] += aa[i] * bb[j];
    }
    __syncthreads();
  }
  #pragma unroll
  for (int i = 0; i < 4; ++i)
    #pragma unroll
    for (int j = 0; j < 4; ++j) {
      int m = m0 + ty * 4 + i;
      int b = m >> 6, nr = m & 63;
      int n = tx * 4 + j;
      float val = fmaxf(c[i][j] * scale + bias[n], 0.f);
      if (z == 0)      vrT[((b * 8 + r) * 64 + n) * 64 + nr] = val;
      else if (z == 1) qrT[((b * 8 + r) * 64 + n) * 64 + nr] = val;
      else             ar [((b * 8 + r) * 64 + nr) * 64 + n] = val;
    }
}

// ---------------- K3: Tucker core ----------------
// grid (vt=8, b=16, z=4) with z = rh*2+g; 512 threads.
// acc[v=wave(8)][q=lane(64)][m=reg(64)] over r in rh*4..rh*4+3, l-chunks of 8.
__global__ __launch_bounds__(512) void k_tucker(
    const float* __restrict__ vrT, const float* __restrict__ qrT, const float* __restrict__ ar,
    const float* __restrict__ T4, float* __restrict__ fout, float* __restrict__ P1)
{
  const int vt = blockIdx.x, b = blockIdx.y, z = blockIdx.z;
  const int g = z & 1, rh = z >> 1;
  const int tid = threadIdx.x, lane = tid & 63;
  const int wu = __builtin_amdgcn_readfirstlane(tid >> 6);

  __shared__ __align__(16) float U[64 * 65];   // [k][v*8+l], pitch 65
  __shared__ __align__(16) float Cb[8 * 520];  // [v][q*8+l], pitch 520

  float acc[64];
  #pragma unroll
  for (int m = 0; m < 64; ++m) acc[m] = 0.f;

  #pragma unroll 1
  for (int r4 = 0; r4 < 4; ++r4) {
    const int r = rh * 4 + r4;
    const float* vv_base = vrT + ((b * 8 + r) * 64) * 64 + vt * 8;  // + h*64 + j (uniform)
    const float* qq_base = qrT + ((b * 8 + r) * 64) * 64 + wu * 8;  // + k*64 + j (uniform)
    const float* ab      = ar  + ((b * 8 + r) * 64) * 64;           // + m*64 + l (uniform)
    const float* tb      = T4  + ((size_t)((g * 8 + r) * 64)) * 4096;

    #pragma unroll 1
    for (int lc = 0; lc < 8; ++lc) {
      const int l0 = lc * 8;
      // ---- Phase A: U[v,k,l] = sum_h v_r[v,h] * T[h,k,l]; lane=k, wave=l ----
      {
        float u[8] = {0.f, 0.f, 0.f, 0.f, 0.f, 0.f, 0.f, 0.f};
        const float* tp = tb + (size_t)(l0 + wu) * 4096 + lane;
        #pragma unroll 8
        for (int h = 0; h < 64; ++h) {
          float tv = tp[h * 64];
          const float* vv = vv_base + h * 64;
          #pragma unroll
          for (int j = 0; j < 8; ++j) u[j] += vv[j] * tv;
        }
        #pragma unroll
        for (int j = 0; j < 8; ++j) U[lane * 65 + j * 8 + wu] = u[j];
      }
      __syncthreads();
      // ---- Phase B: C[v,q,l] = sum_k U[v,k,l] * q_r[q,k]; lane=(v,l), wave=q-block ----
      {
        const int v = lane >> 3, ll = lane & 7;
        float creg[8] = {0.f, 0.f, 0.f, 0.f, 0.f, 0.f, 0.f, 0.f};
        #pragma unroll 8
        for (int k = 0; k < 64; ++k) {
          float uu = U[k * 65 + lane];
          const float* qq = qq_base + k * 64;
          #pragma unroll
          for (int j = 0; j < 8; ++j) creg[j] += uu * qq[j];
        }
        #pragma unroll
        for (int j = 0; j < 8; ++j) Cb[v * 520 + (wu * 8 + j) * 8 + ll] = creg[j];
      }
      __syncthreads();
      // ---- Phase C: acc[m] += sum_l C[v,q,l] * a_r[m,l]; lane=q, wave=v ----
      {
        const float4* cp = (const float4*)&Cb[wu * 520 + lane * 8];
        const float4 c0 = cp[0], c1 = cp[1];
        const float* ap = ab + l0;
        #pragma unroll
        for (int m = 0; m < 64; ++m) {
          const float* av = ap + m * 64;
          acc[m] += c0.x * av[0] + c0.y * av[1] + c0.z * av[2] + c0.w * av[3]
                  + c1.x * av[4] + c1.y * av[5] + c1.z * av[6] + c1.w * av[7];
        }
      }
      __syncthreads();
    }
  }

  const int v = vt * 8 + wu, q = lane;
  if (rh == 0) {
    float* fo = fout + ((size_t)((b * 64 + v) * 64 + q)) * 128 + g;
    #pragma unroll
    for (int m = 0; m < 64; ++m) fo[m * 2] = acc[m];
  } else {
    float* pp = P1 + ((size_t)((g * 16 + b) * 64 + v) * 64 + q) * 64;
    #pragma unroll
    for (int m = 0; m < 64; ++m) pp[m] = acc[m];
  }
}

// ---------------- K4: finalize f_emb (sum partials) + logits per-(b,v) ----------------
__global__ __launch_bounds__(512) void k_femb_logits(
    const float* __restrict__ vt, const float* __restrict__ qt, const float* __restrict__ at,
    float* __restrict__ P1, float* __restrict__ fout, float* __restrict__ Lp)
{
  const int v = blockIdx.x, b = blockIdx.y, d = threadIdx.x;

  float atm[64];
  #pragma unroll
  for (int m = 0; m < 64; ++m) atm[m] = at[(b * 64 + m) * 512 + d];

  // part i: f_emb = P0(in fout) + P1 ; also leave contiguous summed copy in P1
  float* fo = fout + (size_t)(b * 64 + v) * 8192;
  for (int g = 0; g < 2; ++g) {
    float* p1 = P1 + (size_t)((g * 16 + b) * 64 + v) * 4096;
    for (int j = d; j < 4096; j += 512) {
      float s = fo[j * 2 + g] + p1[j];
      fo[j * 2 + g] = s;
      p1[j] = s;
    }
  }
  __syncthreads();

  // part ii: sd = sum_g sum_q q_t[b,q,d] * sum_m F[q,m] * a_t[b,m,d]
  float sd = 0.f;
  for (int g = 0; g < 2; ++g) {
    const float* F = P1 + (size_t)((g * 16 + b) * 64 + v) * 4096;  // uniform -> s_load
    #pragma unroll 1
    for (int q = 0; q < 64; ++q) {
      float qv = qt[(b * 64 + q) * 512 + d];
      float inner = 0.f;
      #pragma unroll
      for (int m = 0; m < 64; ++m) inner += F[q * 64 + m] * atm[m];
      sd += qv * inner;
    }
  }
  Lp[(size_t)(b * 64 + v) * 512 + d] = vt[(b * 64 + v) * 512 + d] * sd;
}

// ---------------- K5: reduce logits over v ----------------
__global__ __launch_bounds__(512) void k_lred(const float* __restrict__ Lp, float* __restrict__ Lraw)
{
  const int b = blockIdx.x, d = threadIdx.x;
  float s = 0.f;
  for (int v = 0; v < 64; ++v) s += Lp[(size_t)(b * 64 + v) * 512 + d];
  Lraw[b * 512 + d] = s;
}

// ---------------- K6: batchnorm over batch dim ----------------
__global__ __launch_bounds__(512) void k_bn(
    const float* __restrict__ Lraw, const float* __restrict__ gamma,
    const float* __restrict__ beta, float* __restrict__ lout)
{
  const int d = threadIdx.x;
  float x[16]; float mu = 0.f;
  #pragma unroll
  for (int b = 0; b < 16; ++b) { x[b] = Lraw[b * 512 + d]; mu += x[b]; }
  mu *= (1.f / 16.f);
  float var = 0.f;
  #pragma unroll
  for (int b = 0; b < 16; ++b) { float t = x[b] - mu; var += t * t; }
  var *= (1.f / 16.f);
  const float sc = gamma[d] / sqrtf(var + 1e-5f);
  const float bt = beta[d];
  #pragma unroll
  for (int b = 0; b < 16; ++b) lout[b * 512 + d] = (x[b] - mu) * sc + bt;
}

extern "C" void kernel_launch(void* const* d_in, const int* in_sizes, int n_in,
                              void* d_out, int out_size, void* d_ws, size_t ws_size,
                              hipStream_t stream)
{
  const float* v    = (const float*)d_in[0];
  const float* q    = (const float*)d_in[1];
  const float* a    = (const float*)d_in[2];
  const float* Vv   = (const float*)d_in[3];
  const float* gv   = (const float*)d_in[4];
  const float* bv   = (const float*)d_in[5];
  const float* Vq   = (const float*)d_in[6];
  const float* gq   = (const float*)d_in[7];
  const float* bq   = (const float*)d_in[8];
  const float* Va   = (const float*)d_in[9];
  const float* ga   = (const float*)d_in[10];
  const float* ba   = (const float*)d_in[11];
  const float* Vnv  = (const float*)d_in[12];
  const float* gnv  = (const float*)d_in[13];
  const float* bnv  = (const float*)d_in[14];
  const float* Vnqa = (const float*)d_in[15];
  const float* gnqa = (const float*)d_in[16];
  const float* bnqa = (const float*)d_in[17];
  const float* Tg   = (const float*)d_in[18];
  const float* gamma= (const float*)d_in[19];
  const float* beta = (const float*)d_in[20];

  float* ws   = (float*)d_ws;
  float* fout = (float*)d_out;
  float* lout = fout + (size_t)16 * 64 * 64 * 64 * 2;

  k_norms<<<19, 256, 0, stream>>>(Vv, Vq, Va, Vnv, Vnqa, ws + WS_NRM);
  k_repack<<<512, 256, 0, stream>>>(Tg, ws + WS_T4);
  k_proj<<<dim3(8, 16, 3), 256, 0, stream>>>(v, q, a, Vv, Vq, Va, gv, gq, ga,
                                             bv, bq, ba, ws + WS_NRM,
                                             ws + WS_VT, ws + WS_QT, ws + WS_AT);
  k_rproj<<<dim3(8, 16, 3), 256, 0, stream>>>(ws + WS_VT, ws + WS_QT, ws + WS_AT,
                                              Vnv, Vnqa, gnv, gnqa, bnv, bnqa,
                                              ws + WS_NRM,
                                              ws + WS_VRT, ws + WS_QRT, ws + WS_AR);
  k_tucker<<<dim3(8, 16, 4), 512, 0, stream>>>(ws + WS_VRT, ws + WS_QRT, ws + WS_AR,
                                               ws + WS_T4, fout, ws + WS_P1);
  k_femb_logits<<<dim3(64, 16), 512, 0, stream>>>(ws + WS_VT, ws + WS_QT, ws + WS_AT,
                                                  ws + WS_P1, fout, ws + WS_LP);
  k_lred<<<16, 512, 0, stream>>>(ws + WS_LP, ws + WS_LR);
  k_bn<<<1, 512, 0, stream>>>(ws + WS_LR, gamma, beta, lout);
}

// Round 2
// 1079.446 us; speedup vs baseline: 1.1726x; 1.1726x over previous
//
#include <hip/hip_runtime.h>
#include <math.h>

// Problem dims: B=16, N=64, D=512, H=512, R=8, HK=64, G=2
// Outputs: f_emb [16,64,64,64,2] (8388608 f32) then logits [16,512] (8192 f32)

// ---------------- workspace layout (float offsets), total ~65 MB ----------------
#define WS_NRM 0                      // 19 norms (pad 32)
#define WS_VT  32                     // v_t [1024][512]
#define WS_QT  (WS_VT  + 524288)      // q_t
#define WS_AT  (WS_QT  + 524288)      // a_t
#define WS_VRT (WS_AT  + 524288)      // v_r transposed [B][R][h][n]
#define WS_QRT (WS_VRT + 524288)      // q_r transposed [B][R][k][q]
#define WS_AR  (WS_QRT + 524288)      // a_r natural    [B][R][m][l]
#define WS_T4  (WS_AR  + 524288)      // T repack [g][r][l][h][k]  (4194304)
#define WS_P1  (WS_T4  + 4194304)     // rh=1 partial [g][b][v][q][m] (8388608)
#define WS_LP  (WS_P1  + 8388608)     // logits per-v partial [b][v][d] (524288)
#define WS_LR  (WS_LP  + 524288)      // raw logits [b][d] (8192)

// ---------------- K0: weight norms ----------------
__global__ __launch_bounds__(256) void k_norms(
    const float* __restrict__ Vv, const float* __restrict__ Vq, const float* __restrict__ Va,
    const float* __restrict__ Vnv, const float* __restrict__ Vnqa, float* __restrict__ wsn)
{
  int nb = blockIdx.x;
  const float* p; int cnt;
  if (nb < 3)       { p = (nb == 0 ? Vv : nb == 1 ? Vq : Va); cnt = 512 * 512; }
  else if (nb < 11) { p = Vnv  + (nb - 3) * 64 * 512; cnt = 64 * 512; }
  else              { p = Vnqa + (nb - 11) * 64 * 512; cnt = 64 * 512; }
  float s = 0.f;
  for (int i = threadIdx.x; i < cnt; i += 256) { float x = p[i]; s += x * x; }
  __shared__ float red[256];
  red[threadIdx.x] = s; __syncthreads();
  for (int off = 128; off > 0; off >>= 1) {
    if (threadIdx.x < off) red[threadIdx.x] += red[threadIdx.x + off];
    __syncthreads();
  }
  if (threadIdx.x == 0) wsn[nb] = sqrtf(red[0]);
}

// ---------------- KT: repack T_g[r][h][k][l][g] -> T4[g][r][l][h][k] ----------------
__global__ __launch_bounds__(256) void k_repack(const float* __restrict__ Tg, float* __restrict__ T4)
{
  int r = blockIdx.x >> 6, h = blockIdx.x & 63;
  const float2* in2 = (const float2*)(Tg + ((size_t)(r * 64 + h) * 64) * 128);
  __shared__ __align__(16) float t0[64][65];
  __shared__ __align__(16) float t1[64][65];
  int tid = threadIdx.x;
  {
    int l = tid & 63, kq = tid >> 6;
    #pragma unroll
    for (int p = 0; p < 16; ++p) {
      int k = p * 4 + kq;
      float2 v = in2[k * 64 + l];
      t0[k][l] = v.x; t1[k][l] = v.y;
    }
  }
  __syncthreads();
  {
    int k = tid & 63, lq = tid >> 6;
    float* o0 = T4 + ((size_t)((0 * 8 + r) * 64)) * 4096 + h * 64;
    float* o1 = T4 + ((size_t)((1 * 8 + r) * 64)) * 4096 + h * 64;
    #pragma unroll
    for (int p = 0; p < 16; ++p) {
      int ll = p * 4 + lq;
      o0[(size_t)ll * 4096 + k] = t0[k][ll];
      o1[(size_t)ll * 4096 + k] = t1[k][ll];
    }
  }
}

// ---------------- K1: v_t/q_t/a_t = relu(x @ (g*V/||V||)^T + b) ----------------
__global__ __launch_bounds__(256) void k_proj(
    const float* __restrict__ inv, const float* __restrict__ inq, const float* __restrict__ ina,
    const float* __restrict__ Wv, const float* __restrict__ Wq, const float* __restrict__ Wa,
    const float* __restrict__ gv, const float* __restrict__ gq, const float* __restrict__ ga,
    const float* __restrict__ bv, const float* __restrict__ bq, const float* __restrict__ ba,
    const float* __restrict__ wsn,
    float* __restrict__ ov, float* __restrict__ oq, float* __restrict__ oa)
{
  const int z = blockIdx.z;
  const float* in   = (z == 0) ? inv : (z == 1) ? inq : ina;
  const float* W    = (z == 0) ? Wv  : (z == 1) ? Wq  : Wa;
  const float* bias = (z == 0) ? bv  : (z == 1) ? bq  : ba;
  float* out        = (z == 0) ? ov  : (z == 1) ? oq  : oa;
  const float scale = ((z == 0) ? gv[0] : (z == 1) ? gq[0] : ga[0]) / wsn[z];

  const int m0 = blockIdx.y * 64, n0 = blockIdx.x * 64;
  __shared__ __align__(16) float As[32][68];
  __shared__ __align__(16) float Bs[32][68];
  const int tid = threadIdx.x;
  const int tx = tid & 15, ty = tid >> 4;
  float c[4][4] = {{0.f}};

  for (int k0 = 0; k0 < 512; k0 += 32) {
    #pragma unroll
    for (int i = 0; i < 8; ++i) {
      int idx = tid + i * 256;
      int kk = idx & 31, rr = idx >> 5;
      As[kk][rr] = in[(m0 + rr) * 512 + k0 + kk];
      Bs[kk][rr] = W[(n0 + rr) * 512 + k0 + kk];
    }
    __syncthreads();
    #pragma unroll
    for (int kk = 0; kk < 32; ++kk) {
      const float4 a4 = *(const float4*)&As[kk][ty * 4];
      const float4 b4 = *(const float4*)&Bs[kk][tx * 4];
      const float aa[4] = {a4.x, a4.y, a4.z, a4.w};
      const float bb[4] = {b4.x, b4.y, b4.z, b4.w};
      #pragma unroll
      for (int i = 0; i < 4; ++i)
        #pragma unroll
        for (int j = 0; j < 4; ++j)
          c[i][j] += aa[i] * bb[j];
    }
    __syncthreads();
  }
  #pragma unroll
  for (int i = 0; i < 4; ++i)
    #pragma unroll
    for (int j = 0; j < 4; ++j) {
      int m = m0 + ty * 4 + i, n = n0 + tx * 4 + j;
      float val = c[i][j] * scale + bias[n];
      out[m * 512 + n] = fmaxf(val, 0.f);
    }
}

// ---------------- K2: per-rank projections (writes v_rT, q_rT transposed; a_r natural) ----------------
__global__ __launch_bounds__(256) void k_rproj(
    const float* __restrict__ vt, const float* __restrict__ qt, const float* __restrict__ at,
    const float* __restrict__ Vnv, const float* __restrict__ Vnqa,
    const float* __restrict__ gnv, const float* __restrict__ gnqa,
    const float* __restrict__ bnv, const float* __restrict__ bnqa,
    const float* __restrict__ wsn,
    float* __restrict__ vrT, float* __restrict__ qrT, float* __restrict__ ar)
{
  const int z = blockIdx.z, r = blockIdx.x, m0 = blockIdx.y * 64;
  const float* in = (z == 0) ? vt : (z == 1) ? qt : at;
  const float* Wn = ((z == 0) ? Vnv : Vnqa) + r * 64 * 512;
  const float scale = (z == 0) ? (gnv[r] / wsn[3 + r]) : (gnqa[r] / wsn[11 + r]);
  const float* bias = ((z == 0) ? bnv : bnqa) + r * 64;

  __shared__ __align__(16) float As[32][68];
  __shared__ __align__(16) float Bs[32][68];
  const int tid = threadIdx.x;
  const int tx = tid & 15, ty = tid >> 4;
  float c[4][4] = {{0.f}};

  for (int k0 = 0; k0 < 512; k0 += 32) {
    #pragma unroll
    for (int i = 0; i < 8; ++i) {
      int idx = tid + i * 256;
      int kk = idx & 31, rr = idx >> 5;
      As[kk][rr] = in[(m0 + rr) * 512 + k0 + kk];
      Bs[kk][rr] = Wn[rr * 512 + k0 + kk];
    }
    __syncthreads();
    #pragma unroll
    for (int kk = 0; kk < 32; ++kk) {
      const float4 a4 = *(const float4*)&As[kk][ty * 4];
      const float4 b4 = *(const float4*)&Bs[kk][tx * 4];
      const float aa[4] = {a4.x, a4.y, a4.z, a4.w};
      const float bb[4] = {b4.x, b4.y, b4.z, b4.w};
      #pragma unroll
      for (int i = 0; i < 4; ++i)
        #pragma unroll
        for (int j = 0; j < 4; ++j)
          c[i][j] += aa[i] * bb[j];
    }
    __syncthreads();
  }
  #pragma unroll
  for (int i = 0; i < 4; ++i)
    #pragma unroll
    for (int j = 0; j < 4; ++j) {
      int m = m0 + ty * 4 + i;
      int b = m >> 6, nr = m & 63;
      int n = tx * 4 + j;
      float val = fmaxf(c[i][j] * scale + bias[n], 0.f);
      if (z == 0)      vrT[((b * 8 + r) * 64 + n) * 64 + nr] = val;
      else if (z == 1) qrT[((b * 8 + r) * 64 + n) * 64 + nr] = val;
      else             ar [((b * 8 + r) * 64 + nr) * 64 + n] = val;
    }
}

// ---------------- K3: Tucker core ----------------
// grid (vt=8, b=16, z=4) with z = rh*2+g; 512 threads.
// acc[v=wave(8)][q=lane(64)][m=reg(64)] over r in rh*4..rh*4+3, l-chunks of 8.
__global__ __launch_bounds__(512) void k_tucker(
    const float* __restrict__ vrT, const float* __restrict__ qrT, const float* __restrict__ ar,
    const float* __restrict__ T4, float* __restrict__ fout, float* __restrict__ P1)
{
  const int vt = blockIdx.x, b = blockIdx.y, z = blockIdx.z;
  const int g = z & 1, rh = z >> 1;
  const int tid = threadIdx.x, lane = tid & 63;
  const int wu = __builtin_amdgcn_readfirstlane(tid >> 6);

  __shared__ __align__(16) float U[64 * 65];   // [k][v*8+l], pitch 65
  __shared__ __align__(16) float Cb[8 * 520];  // [v][q*8+l], pitch 520

  float acc[64];
  #pragma unroll
  for (int m = 0; m < 64; ++m) acc[m] = 0.f;

  #pragma unroll 1
  for (int r4 = 0; r4 < 4; ++r4) {
    const int r = rh * 4 + r4;
    const float* vv_base = vrT + ((b * 8 + r) * 64) * 64 + vt * 8;  // + h*64 + j (uniform)
    const float* qq_base = qrT + ((b * 8 + r) * 64) * 64 + wu * 8;  // + k*64 + j (uniform)
    const float* ab      = ar  + ((b * 8 + r) * 64) * 64;           // + m*64 + l (uniform)
    const float* tb      = T4  + ((size_t)((g * 8 + r) * 64)) * 4096;

    #pragma unroll 1
    for (int lc = 0; lc < 8; ++lc) {
      const int l0 = lc * 8;
      // ---- Phase A: U[v,k,l] = sum_h v_r[v,h] * T[h,k,l]; lane=k, wave=l ----
      {
        float u[8] = {0.f, 0.f, 0.f, 0.f, 0.f, 0.f, 0.f, 0.f};
        const float* tp = tb + (size_t)(l0 + wu) * 4096 + lane;
        #pragma unroll 8
        for (int h = 0; h < 64; ++h) {
          float tv = tp[h * 64];
          const float* vv = vv_base + h * 64;
          #pragma unroll
          for (int j = 0; j < 8; ++j) u[j] += vv[j] * tv;
        }
        #pragma unroll
        for (int j = 0; j < 8; ++j) U[lane * 65 + j * 8 + wu] = u[j];
      }
      __syncthreads();
      // ---- Phase B: C[v,q,l] = sum_k U[v,k,l] * q_r[q,k]; lane=(v,l), wave=q-block ----
      {
        const int v = lane >> 3, ll = lane & 7;
        float creg[8] = {0.f, 0.f, 0.f, 0.f, 0.f, 0.f, 0.f, 0.f};
        #pragma unroll 8
        for (int k = 0; k < 64; ++k) {
          float uu = U[k * 65 + lane];
          const float* qq = qq_base + k * 64;
          #pragma unroll
          for (int j = 0; j < 8; ++j) creg[j] += uu * qq[j];
        }
        #pragma unroll
        for (int j = 0; j < 8; ++j) Cb[v * 520 + (wu * 8 + j) * 8 + ll] = creg[j];
      }
      __syncthreads();
      // ---- Phase C: acc[m] += sum_l C[v,q,l] * a_r[m,l]; lane=q, wave=v ----
      {
        const float4* cp = (const float4*)&Cb[wu * 520 + lane * 8];
        const float4 c0 = cp[0], c1 = cp[1];
        const float* ap = ab + l0;
        #pragma unroll
        for (int m = 0; m < 64; ++m) {
          const float* av = ap + m * 64;
          acc[m] += c0.x * av[0] + c0.y * av[1] + c0.z * av[2] + c0.w * av[3]
                  + c1.x * av[4] + c1.y * av[5] + c1.z * av[6] + c1.w * av[7];
        }
      }
      __syncthreads();
    }
  }

  const int v = vt * 8 + wu, q = lane;
  if (rh == 0) {
    float* fo = fout + ((size_t)((b * 64 + v) * 64 + q)) * 128 + g;
    #pragma unroll
    for (int m = 0; m < 64; ++m) fo[m * 2] = acc[m];
  } else {
    float* pp = P1 + ((size_t)((g * 16 + b) * 64 + v) * 64 + q) * 64;
    #pragma unroll
    for (int m = 0; m < 64; ++m) pp[m] = acc[m];
  }
}

// ---------------- K4a: finalize f_emb: fout += P1 (both g), coalesced float2 ----------------
__global__ __launch_bounds__(256) void k_femb_final(
    float* __restrict__ fout, const float* __restrict__ P1)
{
  const int bv = blockIdx.x;           // b*64+v
  const int b = bv >> 6, v = bv & 63;
  float2* fo2 = (float2*)(fout + (size_t)bv * 8192);
  const float* p0 = P1 + ((size_t)((0 * 16 + b) * 64 + v)) * 4096;
  const float* p1 = P1 + ((size_t)((1 * 16 + b) * 64 + v)) * 4096;
  #pragma unroll 4
  for (int j = threadIdx.x; j < 4096; j += 256) {
    float2 x = fo2[j];
    x.x += p0[j];
    x.y += p1[j];
    fo2[j] = x;
  }
}

// ---------------- K4b: logits partial per (b,v): Lp[b,v,d] ----------------
// sd = sum_q qt[b,q,d] * sum_m (F[q,m,g0]+F[q,m,g1]) * at[b,m,d];  Lp = vt[b,v,d]*sd
// F rows are block-uniform -> scalar loads; atm[64] stays in VGPRs (static idx only).
__global__ __launch_bounds__(512) void k_logits(
    const float* __restrict__ vt, const float* __restrict__ qt, const float* __restrict__ at,
    const float* __restrict__ fout, float* __restrict__ Lp)
{
  const int v = blockIdx.x, b = blockIdx.y, d = threadIdx.x;
  const float* fo = fout + ((size_t)(b * 64 + v)) * 8192;

  float atm[64];
  #pragma unroll
  for (int m = 0; m < 64; ++m) atm[m] = at[(b * 64 + m) * 512 + d];

  float sd = 0.f;
  #pragma unroll 1
  for (int q = 0; q < 64; ++q) {
    const float qv = qt[(b * 64 + q) * 512 + d];
    const float4* Fq = (const float4*)(fo + q * 128);  // block-uniform address
    float inner = 0.f;
    #pragma unroll
    for (int mq = 0; mq < 4; ++mq) {
      float4 f[8];
      #pragma unroll
      for (int t = 0; t < 8; ++t) f[t] = Fq[mq * 8 + t];
      #pragma unroll
      for (int t = 0; t < 8; ++t) {
        const int m = mq * 16 + t * 2;
        inner += (f[t].x + f[t].y) * atm[m] + (f[t].z + f[t].w) * atm[m + 1];
      }
    }
    sd += qv * inner;
  }
  Lp[((size_t)(b * 64 + v)) * 512 + d] = vt[(b * 64 + v) * 512 + d] * sd;
}

// ---------------- K5: reduce logits over v ----------------
__global__ __launch_bounds__(512) void k_lred(const float* __restrict__ Lp, float* __restrict__ Lraw)
{
  const int b = blockIdx.x, d = threadIdx.x;
  float s = 0.f;
  for (int v = 0; v < 64; ++v) s += Lp[(size_t)(b * 64 + v) * 512 + d];
  Lraw[b * 512 + d] = s;
}

// ---------------- K6: batchnorm over batch dim ----------------
__global__ __launch_bounds__(512) void k_bn(
    const float* __restrict__ Lraw, const float* __restrict__ gamma,
    const float* __restrict__ beta, float* __restrict__ lout)
{
  const int d = threadIdx.x;
  float x[16]; float mu = 0.f;
  #pragma unroll
  for (int b = 0; b < 16; ++b) { x[b] = Lraw[b * 512 + d]; mu += x[b]; }
  mu *= (1.f / 16.f);
  float var = 0.f;
  #pragma unroll
  for (int b = 0; b < 16; ++b) { float t = x[b] - mu; var += t * t; }
  var *= (1.f / 16.f);
  const float sc = gamma[d] / sqrtf(var + 1e-5f);
  const float bt = beta[d];
  #pragma unroll
  for (int b = 0; b < 16; ++b) lout[b * 512 + d] = (x[b] - mu) * sc + bt;
}

extern "C" void kernel_launch(void* const* d_in, const int* in_sizes, int n_in,
                              void* d_out, int out_size, void* d_ws, size_t ws_size,
                              hipStream_t stream)
{
  const float* v    = (const float*)d_in[0];
  const float* q    = (const float*)d_in[1];
  const float* a    = (const float*)d_in[2];
  const float* Vv   = (const float*)d_in[3];
  const float* gv   = (const float*)d_in[4];
  const float* bv   = (const float*)d_in[5];
  const float* Vq   = (const float*)d_in[6];
  const float* gq   = (const float*)d_in[7];
  const float* bq   = (const float*)d_in[8];
  const float* Va   = (const float*)d_in[9];
  const float* ga   = (const float*)d_in[10];
  const float* ba   = (const float*)d_in[11];
  const float* Vnv  = (const float*)d_in[12];
  const float* gnv  = (const float*)d_in[13];
  const float* bnv  = (const float*)d_in[14];
  const float* Vnqa = (const float*)d_in[15];
  const float* gnqa = (const float*)d_in[16];
  const float* bnqa = (const float*)d_in[17];
  const float* Tg   = (const float*)d_in[18];
  const float* gamma= (const float*)d_in[19];
  const float* beta = (const float*)d_in[20];

  float* ws   = (float*)d_ws;
  float* fout = (float*)d_out;
  float* lout = fout + (size_t)16 * 64 * 64 * 64 * 2;

  k_norms<<<19, 256, 0, stream>>>(Vv, Vq, Va, Vnv, Vnqa, ws + WS_NRM);
  k_repack<<<512, 256, 0, stream>>>(Tg, ws + WS_T4);
  k_proj<<<dim3(8, 16, 3), 256, 0, stream>>>(v, q, a, Vv, Vq, Va, gv, gq, ga,
                                             bv, bq, ba, ws + WS_NRM,
                                             ws + WS_VT, ws + WS_QT, ws + WS_AT);
  k_rproj<<<dim3(8, 16, 3), 256, 0, stream>>>(ws + WS_VT, ws + WS_QT, ws + WS_AT,
                                              Vnv, Vnqa, gnv, gnqa, bnv, bnqa,
                                              ws + WS_NRM,
                                              ws + WS_VRT, ws + WS_QRT, ws + WS_AR);
  k_tucker<<<dim3(8, 16, 4), 512, 0, stream>>>(ws + WS_VRT, ws + WS_QRT, ws + WS_AR,
                                               ws + WS_T4, fout, ws + WS_P1);
  k_femb_final<<<1024, 256, 0, stream>>>(fout, ws + WS_P1);
  k_logits<<<dim3(64, 16), 512, 0, stream>>>(ws + WS_VT, ws + WS_QT, ws + WS_AT,
                                             fout, ws + WS_LP);
  k_lred<<<16, 512, 0, stream>>>(ws + WS_LP, ws + WS_LR);
  k_bn<<<1, 512, 0, stream>>>(ws + WS_LR, gamma, beta, lout);
}

// Round 3
// 780.575 us; speedup vs baseline: 1.6215x; 1.3829x over previous
//
#include <hip/hip_runtime.h>
#include <hip/hip_fp16.h>
#include <math.h>

// Problem dims: B=16, N=64, D=512, H=512, R=8, HK=64, G=2
// Outputs: f_emb [16,64,64,64,2] (8388608 f32) then logits [16,512] (8192 f32)

typedef _Float16 f16x8 __attribute__((ext_vector_type(8)));
typedef float f32x4 __attribute__((ext_vector_type(4)));

__device__ __forceinline__ unsigned short f2h(float x) {
  _Float16 h = (_Float16)x;
  return __builtin_bit_cast(unsigned short, h);
}

// fragment scatter map for 16x16x32 (row16, kr in 0..31):
//   lane = (row&15) + (((kr>>2)&3)<<4) ; j = (kr&3) + (((kr>>4)&1)<<2)
// element offset within a 512-el frag-tile = lane*8 + j
__device__ __forceinline__ int fragoff(int row, int kr) {
  return (((row & 15) + (((kr >> 2) & 3) << 4)) << 3) + (kr & 3) + (((kr >> 4) & 1) << 2);
}

// ---------------- workspace layout ----------------
// float region:
#define WS_NRM 0                      // 32 floats
#define WS_VT  32                     // v_t [1024][512] f32
#define WS_QT  (WS_VT + 524288)
#define WS_AT  (WS_QT + 524288)
#define WS_LP  (WS_AT + 524288)       // logits per-v partial [b][v][d]
#define WS_LR  (WS_LP + 524288)       // raw logits [b][d]
#define WS_H   (WS_LR + 8192)         // half region starts here (16B aligned)
// half (ushort) offsets from hbase:
#define H_VR2 0                        // v_r frags [b][r][mt4][ks2][512]  (524288)
#define H_QR2 524288                   // q_r frags [b][r][nt4][ks2][512]
#define H_AR2 1048576                  // a_r frags [b][r][lc2][nt4][512]
#define H_T2  1572864                  // T frags [g][r][Nt256][ks2][512]  (4194304)
#define H_U   5767168                  // U frags per (g,rh): [b][vt][rq][lc][16384] (16777216)

// ---------------- K0: weight norms ----------------
__global__ __launch_bounds__(256) void k_norms(
    const float* __restrict__ Vv, const float* __restrict__ Vq, const float* __restrict__ Va,
    const float* __restrict__ Vnv, const float* __restrict__ Vnqa, float* __restrict__ wsn)
{
  int nb = blockIdx.x;
  const float* p; int cnt;
  if (nb < 3)       { p = (nb == 0 ? Vv : nb == 1 ? Vq : Va); cnt = 512 * 512; }
  else if (nb < 11) { p = Vnv  + (nb - 3) * 64 * 512; cnt = 64 * 512; }
  else              { p = Vnqa + (nb - 11) * 64 * 512; cnt = 64 * 512; }
  float s = 0.f;
  for (int i = threadIdx.x; i < cnt; i += 256) { float x = p[i]; s += x * x; }
  __shared__ float red[256];
  red[threadIdx.x] = s; __syncthreads();
  for (int off = 128; off > 0; off >>= 1) {
    if (threadIdx.x < off) red[threadIdx.x] += red[threadIdx.x + off];
    __syncthreads();
  }
  if (threadIdx.x == 0) wsn[nb] = sqrtf(red[0]);
}

// ---------------- KT: repack T_g[r][h][k][l][g] -> fp16 frag tiles ----------------
// T2[g][r][Nt=l*4+(k>>4)][ks=h>>5][fragoff(k&15, h&31)]
__global__ __launch_bounds__(256) void k_repack2(const float* __restrict__ Tg, unsigned short* __restrict__ T2)
{
  const int r = blockIdx.x >> 6, h = blockIdx.x & 63;
  const float2* in2 = (const float2*)(Tg + (size_t)(r * 64 + h) * 8192);
  const int tid = threadIdx.x;
  const int ks = h >> 5, hr = h & 31;
  #pragma unroll
  for (int p = 0; p < 16; ++p) {
    int idx = tid + p * 256;
    int k = idx >> 6, l = idx & 63;
    float2 tv = in2[k * 64 + l];
    size_t fo = fragoff(k & 15, hr);
    size_t base0 = ((((size_t)(0 * 8 + r) * 256 + l * 4 + (k >> 4)) * 2 + ks) << 9) + fo;
    size_t base1 = ((((size_t)(1 * 8 + r) * 256 + l * 4 + (k >> 4)) * 2 + ks) << 9) + fo;
    T2[base0] = f2h(tv.x);
    T2[base1] = f2h(tv.y);
  }
}

// ---------------- K1: v_t/q_t/a_t = relu(x @ (g*V/||V||)^T + b) (fp32) ----------------
__global__ __launch_bounds__(256) void k_proj(
    const float* __restrict__ inv, const float* __restrict__ inq, const float* __restrict__ ina,
    const float* __restrict__ Wv, const float* __restrict__ Wq, const float* __restrict__ Wa,
    const float* __restrict__ gv, const float* __restrict__ gq, const float* __restrict__ ga,
    const float* __restrict__ bv, const float* __restrict__ bq, const float* __restrict__ ba,
    const float* __restrict__ wsn,
    float* __restrict__ ov, float* __restrict__ oq, float* __restrict__ oa)
{
  const int z = blockIdx.z;
  const float* in   = (z == 0) ? inv : (z == 1) ? inq : ina;
  const float* W    = (z == 0) ? Wv  : (z == 1) ? Wq  : Wa;
  const float* bias = (z == 0) ? bv  : (z == 1) ? bq  : ba;
  float* out        = (z == 0) ? ov  : (z == 1) ? oq  : oa;
  const float scale = ((z == 0) ? gv[0] : (z == 1) ? gq[0] : ga[0]) / wsn[z];

  const int m0 = blockIdx.y * 64, n0 = blockIdx.x * 64;
  __shared__ __align__(16) float As[32][68];
  __shared__ __align__(16) float Bs[32][68];
  const int tid = threadIdx.x;
  const int tx = tid & 15, ty = tid >> 4;
  float c[4][4] = {{0.f}};

  for (int k0 = 0; k0 < 512; k0 += 32) {
    #pragma unroll
    for (int i = 0; i < 8; ++i) {
      int idx = tid + i * 256;
      int kk = idx & 31, rr = idx >> 5;
      As[kk][rr] = in[(m0 + rr) * 512 + k0 + kk];
      Bs[kk][rr] = W[(n0 + rr) * 512 + k0 + kk];
    }
    __syncthreads();
    #pragma unroll
    for (int kk = 0; kk < 32; ++kk) {
      const float4 a4 = *(const float4*)&As[kk][ty * 4];
      const float4 b4 = *(const float4*)&Bs[kk][tx * 4];
      const float aa[4] = {a4.x, a4.y, a4.z, a4.w};
      const float bb[4] = {b4.x, b4.y, b4.z, b4.w};
      #pragma unroll
      for (int i = 0; i < 4; ++i)
        #pragma unroll
        for (int j = 0; j < 4; ++j)
          c[i][j] += aa[i] * bb[j];
    }
    __syncthreads();
  }
  #pragma unroll
  for (int i = 0; i < 4; ++i)
    #pragma unroll
    for (int j = 0; j < 4; ++j) {
      int m = m0 + ty * 4 + i, n = n0 + tx * 4 + j;
      float val = c[i][j] * scale + bias[n];
      out[m * 512 + n] = fmaxf(val, 0.f);
    }
}

// ---------------- K2: per-rank projections -> fp16 fragment-order operands ----------------
__global__ __launch_bounds__(256) void k_rproj2(
    const float* __restrict__ vt, const float* __restrict__ qt, const float* __restrict__ at,
    const float* __restrict__ Vnv, const float* __restrict__ Vnqa,
    const float* __restrict__ gnv, const float* __restrict__ gnqa,
    const float* __restrict__ bnv, const float* __restrict__ bnqa,
    const float* __restrict__ wsn,
    unsigned short* __restrict__ vrT2, unsigned short* __restrict__ qrT2,
    unsigned short* __restrict__ arT2)
{
  const int z = blockIdx.z, r = blockIdx.x, m0 = blockIdx.y * 64;
  const float* in = (z == 0) ? vt : (z == 1) ? qt : at;
  const float* Wn = ((z == 0) ? Vnv : Vnqa) + r * 64 * 512;
  const float scale = (z == 0) ? (gnv[r] / wsn[3 + r]) : (gnqa[r] / wsn[11 + r]);
  const float* bias = ((z == 0) ? bnv : bnqa) + r * 64;

  __shared__ __align__(16) float As[32][68];
  __shared__ __align__(16) float Bs[32][68];
  const int tid = threadIdx.x;
  const int tx = tid & 15, ty = tid >> 4;
  float c[4][4] = {{0.f}};

  for (int k0 = 0; k0 < 512; k0 += 32) {
    #pragma unroll
    for (int i = 0; i < 8; ++i) {
      int idx = tid + i * 256;
      int kk = idx & 31, rr = idx >> 5;
      As[kk][rr] = in[(m0 + rr) * 512 + k0 + kk];
      Bs[kk][rr] = Wn[rr * 512 + k0 + kk];
    }
    __syncthreads();
    #pragma unroll
    for (int kk = 0; kk < 32; ++kk) {
      const float4 a4 = *(const float4*)&As[kk][ty * 4];
      const float4 b4 = *(const float4*)&Bs[kk][tx * 4];
      const float aa[4] = {a4.x, a4.y, a4.z, a4.w};
      const float bb[4] = {b4.x, b4.y, b4.z, b4.w};
      #pragma unroll
      for (int i = 0; i < 4; ++i)
        #pragma unroll
        for (int j = 0; j < 4; ++j)
          c[i][j] += aa[i] * bb[j];
    }
    __syncthreads();
  }
  #pragma unroll
  for (int i = 0; i < 4; ++i)
    #pragma unroll
    for (int j = 0; j < 4; ++j) {
      int mm = m0 + ty * 4 + i;
      int bb = mm >> 6, nr = mm & 63;   // nr = position index (v/q/m)
      int n = tx * 4 + j;               // n = unit index (h/k/l)
      float val = fmaxf(c[i][j] * scale + bias[n], 0.f);
      unsigned short hv = f2h(val);
      if (z == 0) {
        vrT2[(size_t)(bb * 8 + r) * 4096 + ((nr >> 4) * 2 + (n >> 5)) * 512 + fragoff(nr, n & 31)] = hv;
      } else if (z == 1) {
        qrT2[(size_t)(bb * 8 + r) * 4096 + ((nr >> 4) * 2 + (n >> 5)) * 512 + fragoff(nr, n & 31)] = hv;
      } else {
        arT2[(size_t)(((bb * 8 + r) * 2 + (n >> 5)) * 4 + (nr >> 4)) * 512 + fragoff(nr, n & 31)] = hv;
      }
    }
}

// ---------------- K3a: stage1 U[v,(l,k)] = v_r @ T (fp16 MFMA) ----------------
// grid (b16, rq4, ntB4), 512 thr. Writes U frag-tiles for stage2.
__global__ __launch_bounds__(512) void k_stage1(
    const unsigned short* __restrict__ vrT2, const unsigned short* __restrict__ T2,
    unsigned short* __restrict__ U, int g, int rh)
{
  const int b = blockIdx.x, rq = blockIdx.y, ntB = blockIdx.z;
  const int r = rh * 4 + rq;
  const int tid = threadIdx.x, lane = tid & 63;
  const int w = __builtin_amdgcn_readfirstlane(tid >> 6);

  __shared__ __align__(16) unsigned short VR[4096];
  __shared__ __align__(16) unsigned short TC[16384];
  __shared__ __align__(16) unsigned short ST[16384];

  // stage v_r frags (8 KB)
  {
    const float4* s = (const float4*)(vrT2 + (size_t)(b * 8 + r) * 4096);
    *(float4*)&VR[tid * 8] = s[tid];
  }

  const size_t t2base = ((size_t)(g * 8 + r) * 256 + ntB * 64) * 1024;

  for (int sb = 0; sb < 4; ++sb) {
    // stage T chunk (32 KB, contiguous)
    {
      const float4* s = (const float4*)(T2 + t2base + (size_t)sb * 16384);
      float4* d = (float4*)TC;
      #pragma unroll
      for (int i = 0; i < 4; ++i) d[tid + i * 512] = s[tid + i * 512];
    }
    __syncthreads();

    f32x4 c[4][2];
    #pragma unroll
    for (int mt = 0; mt < 4; ++mt)
      #pragma unroll
      for (int nt = 0; nt < 2; ++nt)
        c[mt][nt] = (f32x4){0.f, 0.f, 0.f, 0.f};

    f16x8 af[4][2], bf[2][2];
    #pragma unroll
    for (int mt = 0; mt < 4; ++mt)
      #pragma unroll
      for (int ks = 0; ks < 2; ++ks)
        af[mt][ks] = *(const f16x8*)&VR[mt * 1024 + ks * 512 + lane * 8];
    #pragma unroll
    for (int nt = 0; nt < 2; ++nt)
      #pragma unroll
      for (int ks = 0; ks < 2; ++ks)
        bf[nt][ks] = *(const f16x8*)&TC[(w * 2 + nt) * 1024 + ks * 512 + lane * 8];

    #pragma unroll
    for (int mt = 0; mt < 4; ++mt)
      #pragma unroll
      for (int nt = 0; nt < 2; ++nt)
        #pragma unroll
        for (int ks = 0; ks < 2; ++ks)
          c[mt][nt] = __builtin_amdgcn_mfma_f32_16x16x32_f16(af[mt][ks], bf[nt][ks], c[mt][nt], 0, 0, 0);

    // epilogue: scatter D into ST in U-frag order
    #pragma unroll
    for (int mt = 0; mt < 4; ++mt)
      #pragma unroll
      for (int nt = 0; nt < 2; ++nt) {
        const int Nt = ntB * 64 + sb * 16 + w * 2 + nt;
        const int n = Nt * 16 + (lane & 15);
        const int l = n >> 6, k = n & 63;
        #pragma unroll
        for (int i = 0; i < 4; ++i) {
          const int v = mt * 16 + 4 * (lane >> 4) + i;
          const int row16 = 8 * (l & 1) + (v & 7);
          const int el = ((v >> 3) * 2 + ((l >> 1) & 1)) * 1024 + (k >> 5) * 512 + fragoff(row16, k & 31);
          ST[el] = f2h(c[mt][nt][i]);
        }
      }
    __syncthreads();

    // copy ST -> U (16 regions of 2 KB, each contiguous in U)
    {
      const int l0 = ntB * 16 + sb * 4;
      const int lc = l0 >> 5;
      const int mtU0 = (l0 >> 1) & 15;
      const int rg = tid >> 5, idx = tid & 31;
      const int vt = rg >> 1, mtrel = rg & 1;
      unsigned short* dst = U + ((size_t)(((b * 8 + vt) * 4 + rq) * 2 + lc)) * 16384
                              + (size_t)(mtU0 + mtrel) * 1024;
      const float4* s = (const float4*)&ST[rg * 1024];
      float4* d = (float4*)dst;
      #pragma unroll
      for (int i = 0; i < 4; ++i) d[idx + i * 32] = s[idx + i * 32];
    }
    __syncthreads();
  }
}

// ---------------- K3b: stage2+3 fused: C = U @ q_r^T ; f += C @ a_r^T ----------------
// grid (b16, vt8, qh2), 512 thr. Accumulates 4 ranks in MFMA regs; accum adds into fout.
__global__ __launch_bounds__(512) void k_stage23(
    const unsigned short* __restrict__ U, const unsigned short* __restrict__ qrT2,
    const unsigned short* __restrict__ arT2, float* __restrict__ fout,
    int g, int rh, int accum)
{
  const int b = blockIdx.x, vt = blockIdx.y, qh = blockIdx.z;
  const int tid = threadIdx.x, lane = tid & 63;
  const int w = __builtin_amdgcn_readfirstlane(tid >> 6);

  __shared__ __align__(16) unsigned short UA[16384];
  __shared__ __align__(16) unsigned short QB[2048];
  __shared__ __align__(16) unsigned short AB[2048];
  __shared__ __align__(16) unsigned short CC[8192];

  f32x4 f[2][4];
  #pragma unroll
  for (int qt = 0; qt < 2; ++qt)
    #pragma unroll
    for (int nt = 0; nt < 4; ++nt)
      f[qt][nt] = (f32x4){0.f, 0.f, 0.f, 0.f};

  for (int rq = 0; rq < 4; ++rq) {
    const int r = rh * 4 + rq;
    const float4* sq = (const float4*)(qrT2 + (size_t)(b * 8 + r) * 4096 + qh * 2048);

    for (int lc = 0; lc < 2; ++lc) {
      // stage UA (32 KB)
      {
        const float4* su = (const float4*)(U + ((size_t)(((b * 8 + vt) * 4 + rq) * 2 + lc)) * 16384);
        float4* du = (float4*)UA;
        #pragma unroll
        for (int i = 0; i < 4; ++i) du[tid + i * 512] = su[tid + i * 512];
      }
      // stage AB (4 KB)
      {
        const float4* sa = (const float4*)(arT2 + ((size_t)((b * 8 + r) * 2 + lc)) * 2048);
        if (tid < 256) ((float4*)AB)[tid] = sa[tid];
      }
      // stage QB (4 KB, once per r)
      if (lc == 0 && tid >= 256) ((float4*)QB)[tid - 256] = sq[tid - 256];
      __syncthreads();

      // ---- stage2: C[(l,v), q] = sum_k U * q_r ----
      f32x4 c2[2][2];
      #pragma unroll
      for (int mi = 0; mi < 2; ++mi)
        #pragma unroll
        for (int nt = 0; nt < 2; ++nt)
          c2[mi][nt] = (f32x4){0.f, 0.f, 0.f, 0.f};

      f16x8 a2[2][2], b2[2][2];
      #pragma unroll
      for (int mi = 0; mi < 2; ++mi)
        #pragma unroll
        for (int ks = 0; ks < 2; ++ks)
          a2[mi][ks] = *(const f16x8*)&UA[(w * 2 + mi) * 1024 + ks * 512 + lane * 8];
      #pragma unroll
      for (int nt = 0; nt < 2; ++nt)
        #pragma unroll
        for (int ks = 0; ks < 2; ++ks)
          b2[nt][ks] = *(const f16x8*)&QB[nt * 1024 + ks * 512 + lane * 8];

      #pragma unroll
      for (int mi = 0; mi < 2; ++mi)
        #pragma unroll
        for (int nt = 0; nt < 2; ++nt)
          #pragma unroll
          for (int ks = 0; ks < 2; ++ks)
            c2[mi][nt] = __builtin_amdgcn_mfma_f32_16x16x32_f16(a2[mi][ks], b2[nt][ks], c2[mi][nt], 0, 0, 0);

      // write C into CC in stage3-frag order
      #pragma unroll
      for (int mi = 0; mi < 2; ++mi)
        #pragma unroll
        for (int nt = 0; nt < 2; ++nt)
          #pragma unroll
          for (int i = 0; i < 4; ++i) {
            const int row = (w * 2 + mi) * 16 + 4 * (lane >> 4) + i;
            const int l = row >> 3, v = row & 7;
            const int el = (v * 2 + nt) * 512 + fragoff(lane & 15, l);
            CC[el] = f2h(c2[mi][nt][i]);
          }
      __syncthreads();

      // ---- stage3: f[v=w] += C @ a_r^T ----
      f16x8 a3[2], b3[4];
      #pragma unroll
      for (int qt = 0; qt < 2; ++qt)
        a3[qt] = *(const f16x8*)&CC[(w * 2 + qt) * 512 + lane * 8];
      #pragma unroll
      for (int nt = 0; nt < 4; ++nt)
        b3[nt] = *(const f16x8*)&AB[nt * 512 + lane * 8];

      #pragma unroll
      for (int qt = 0; qt < 2; ++qt)
        #pragma unroll
        for (int nt = 0; nt < 4; ++nt)
          f[qt][nt] = __builtin_amdgcn_mfma_f32_16x16x32_f16(a3[qt], b3[nt], f[qt][nt], 0, 0, 0);
      __syncthreads();
    }
  }

  // epilogue: write f tile to fout[b][v][q][m][g]
  #pragma unroll
  for (int qt = 0; qt < 2; ++qt)
    #pragma unroll
    for (int nt = 0; nt < 4; ++nt)
      #pragma unroll
      for (int i = 0; i < 4; ++i) {
        const int q = qh * 32 + qt * 16 + 4 * (lane >> 4) + i;
        const int m = nt * 16 + (lane & 15);
        size_t addr = ((((size_t)b * 64 + vt * 8 + w) * 64 + q) * 64 + m) * 2 + g;
        float val = f[qt][nt][i];
        if (accum) val += fout[addr];
        fout[addr] = val;
      }
}

// ---------------- K4b: logits partial per (b,v): Lp[b,v,d] ----------------
__global__ __launch_bounds__(512) void k_logits(
    const float* __restrict__ vt, const float* __restrict__ qt, const float* __restrict__ at,
    const float* __restrict__ fout, float* __restrict__ Lp)
{
  const int v = blockIdx.x, b = blockIdx.y, d = threadIdx.x;
  const float* fo = fout + ((size_t)(b * 64 + v)) * 8192;

  float atm[64];
  #pragma unroll
  for (int m = 0; m < 64; ++m) atm[m] = at[(b * 64 + m) * 512 + d];

  float sd = 0.f;
  #pragma unroll 1
  for (int q = 0; q < 64; ++q) {
    const float qv = qt[(b * 64 + q) * 512 + d];
    const float4* Fq = (const float4*)(fo + q * 128);  // block-uniform address
    float inner = 0.f;
    #pragma unroll
    for (int mq = 0; mq < 4; ++mq) {
      float4 fv[8];
      #pragma unroll
      for (int t = 0; t < 8; ++t) fv[t] = Fq[mq * 8 + t];
      #pragma unroll
      for (int t = 0; t < 8; ++t) {
        const int m = mq * 16 + t * 2;
        inner += (fv[t].x + fv[t].y) * atm[m] + (fv[t].z + fv[t].w) * atm[m + 1];
      }
    }
    sd += qv * inner;
  }
  Lp[((size_t)(b * 64 + v)) * 512 + d] = vt[(b * 64 + v) * 512 + d] * sd;
}

// ---------------- K5: reduce logits over v ----------------
__global__ __launch_bounds__(512) void k_lred(const float* __restrict__ Lp, float* __restrict__ Lraw)
{
  const int b = blockIdx.x, d = threadIdx.x;
  float s = 0.f;
  for (int v = 0; v < 64; ++v) s += Lp[(size_t)(b * 64 + v) * 512 + d];
  Lraw[b * 512 + d] = s;
}

// ---------------- K6: batchnorm over batch dim ----------------
__global__ __launch_bounds__(512) void k_bn(
    const float* __restrict__ Lraw, const float* __restrict__ gamma,
    const float* __restrict__ beta, float* __restrict__ lout)
{
  const int d = threadIdx.x;
  float x[16]; float mu = 0.f;
  #pragma unroll
  for (int b = 0; b < 16; ++b) { x[b] = Lraw[b * 512 + d]; mu += x[b]; }
  mu *= (1.f / 16.f);
  float var = 0.f;
  #pragma unroll
  for (int b = 0; b < 16; ++b) { float t = x[b] - mu; var += t * t; }
  var *= (1.f / 16.f);
  const float sc = gamma[d] / sqrtf(var + 1e-5f);
  const float bt = beta[d];
  #pragma unroll
  for (int b = 0; b < 16; ++b) lout[b * 512 + d] = (x[b] - mu) * sc + bt;
}

extern "C" void kernel_launch(void* const* d_in, const int* in_sizes, int n_in,
                              void* d_out, int out_size, void* d_ws, size_t ws_size,
                              hipStream_t stream)
{
  const float* v    = (const float*)d_in[0];
  const float* q    = (const float*)d_in[1];
  const float* a    = (const float*)d_in[2];
  const float* Vv   = (const float*)d_in[3];
  const float* gv   = (const float*)d_in[4];
  const float* bv   = (const float*)d_in[5];
  const float* Vq   = (const float*)d_in[6];
  const float* gq   = (const float*)d_in[7];
  const float* bq   = (const float*)d_in[8];
  const float* Va   = (const float*)d_in[9];
  const float* ga   = (const float*)d_in[10];
  const float* ba   = (const float*)d_in[11];
  const float* Vnv  = (const float*)d_in[12];
  const float* gnv  = (const float*)d_in[13];
  const float* bnv  = (const float*)d_in[14];
  const float* Vnqa = (const float*)d_in[15];
  const float* gnqa = (const float*)d_in[16];
  const float* bnqa = (const float*)d_in[17];
  const float* Tg   = (const float*)d_in[18];
  const float* gamma= (const float*)d_in[19];
  const float* beta = (const float*)d_in[20];

  float* ws   = (float*)d_ws;
  unsigned short* hb = (unsigned short*)(ws + WS_H);
  float* fout = (float*)d_out;
  float* lout = fout + (size_t)16 * 64 * 64 * 64 * 2;

  k_norms<<<19, 256, 0, stream>>>(Vv, Vq, Va, Vnv, Vnqa, ws + WS_NRM);
  k_repack2<<<512, 256, 0, stream>>>(Tg, hb + H_T2);
  k_proj<<<dim3(8, 16, 3), 256, 0, stream>>>(v, q, a, Vv, Vq, Va, gv, gq, ga,
                                             bv, bq, ba, ws + WS_NRM,
                                             ws + WS_VT, ws + WS_QT, ws + WS_AT);
  k_rproj2<<<dim3(8, 16, 3), 256, 0, stream>>>(ws + WS_VT, ws + WS_QT, ws + WS_AT,
                                               Vnv, Vnqa, gnv, gnqa, bnv, bnqa,
                                               ws + WS_NRM,
                                               hb + H_VR2, hb + H_QR2, hb + H_AR2);
  for (int g = 0; g < 2; ++g)
    for (int rh = 0; rh < 2; ++rh) {
      k_stage1<<<dim3(16, 4, 4), 512, 0, stream>>>(hb + H_VR2, hb + H_T2, hb + H_U, g, rh);
      k_stage23<<<dim3(16, 8, 2), 512, 0, stream>>>(hb + H_U, hb + H_QR2, hb + H_AR2,
                                                    fout, g, rh, rh);
    }
  k_logits<<<dim3(64, 16), 512, 0, stream>>>(ws + WS_VT, ws + WS_QT, ws + WS_AT,
                                             fout, ws + WS_LP);
  k_lred<<<16, 512, 0, stream>>>(ws + WS_LP, ws + WS_LR);
  k_bn<<<1, 512, 0, stream>>>(ws + WS_LR, gamma, beta, lout);
}

// Round 4
// 545.791 us; speedup vs baseline: 2.3190x; 1.4302x over previous
//
#include <hip/hip_runtime.h>
#include <hip/hip_fp16.h>
#include <math.h>

// Problem dims: B=16, N=64, D=512, H=512, R=8, HK=64, G=2
// Outputs: f_emb [16,64,64,64,2] (8388608 f32) then logits [16,512] (8192 f32)

typedef _Float16 f16x8 __attribute__((ext_vector_type(8)));
typedef float f32x4 __attribute__((ext_vector_type(4)));

__device__ __forceinline__ unsigned short f2h(float x) {
  _Float16 h = (_Float16)x;
  return __builtin_bit_cast(unsigned short, h);
}

// fragment scatter map for 16x16x32 (row16, kr in 0..31):
//   lane = (row&15) + (((kr>>2)&3)<<4) ; j = (kr&3) + (((kr>>4)&1)<<2)
// element offset within a 512-el frag-tile = lane*8 + j
__device__ __forceinline__ int fragoff(int row, int kr) {
  return (((row & 15) + (((kr >> 2) & 3) << 4)) << 3) + (kr & 3) + (((kr >> 4) & 1) << 2);
}

// ---------------- workspace layout ----------------
// float region:
#define WS_NRM 0                      // 32 floats
#define WS_VT  32                     // v_t [1024][512] f32
#define WS_QT  (WS_VT + 524288)
#define WS_AT  (WS_QT + 524288)
#define WS_LP  (WS_AT + 524288)       // logits per-v partial [b][v][d]
#define WS_LR  (WS_LP + 524288)       // raw logits [b][d]
#define WS_PRT (WS_LR + 8192)         // norm partials 19*64 (pad 1280)
#define WS_H   (WS_PRT + 1280)        // half region starts here (16B aligned)
// half (ushort) offsets from hbase:
#define H_VR2 0                        // v_r frags [b][r][mt4][ks2][512]  (524288)
#define H_QR2 524288                   // q_r frags [b][r][nt4][ks2][512]
#define H_AR2 1048576                  // a_r frags [b][r][lc2][nt4][512]
#define H_T2  1572864                  // T frags [g][r][Nt256][ks2][512]  (4194304)
#define H_U   5767168                  // U frags per (g,rh): [b][vt][rq][lc][16384] (16777216)

// ---------------- K0a: norm partials (parallel, coalesced float4) ----------------
// grid 320: norms 0..2 get 64 blocks each (1 MB matrices), norms 3..18 get 8 blocks (128 KB)
__global__ __launch_bounds__(256) void k_norms_part(
    const float* __restrict__ Vv, const float* __restrict__ Vq, const float* __restrict__ Va,
    const float* __restrict__ Vnv, const float* __restrict__ Vnqa, float* __restrict__ prt)
{
  const int bx = blockIdx.x;
  int n, j;
  const float* base;
  if (bx < 192) {
    n = bx >> 6; j = bx & 63;
    base = (n == 0 ? Vv : n == 1 ? Vq : Va) + j * 4096;
  } else {
    int t = bx - 192;
    n = 3 + (t >> 3); j = t & 7;
    base = (n < 11 ? Vnv + (n - 3) * 32768 : Vnqa + (n - 11) * 32768) + j * 4096;
  }
  const float4* p4 = (const float4*)base;
  float s = 0.f;
  #pragma unroll
  for (int i = 0; i < 4; ++i) {
    float4 x = p4[threadIdx.x + i * 256];
    s += x.x * x.x + x.y * x.y + x.z * x.z + x.w * x.w;
  }
  __shared__ float red[256];
  red[threadIdx.x] = s; __syncthreads();
  for (int off = 128; off > 0; off >>= 1) {
    if (threadIdx.x < off) red[threadIdx.x] += red[threadIdx.x + off];
    __syncthreads();
  }
  if (threadIdx.x == 0) prt[n * 64 + j] = red[0];
}

// ---------------- K0b: finalize norms ----------------
__global__ __launch_bounds__(64) void k_norms_fin(const float* __restrict__ prt, float* __restrict__ wsn)
{
  const int n = blockIdx.x, t = threadIdx.x;
  const int cnt = (n < 3) ? 64 : 8;
  float s = (t < cnt) ? prt[n * 64 + t] : 0.f;
  #pragma unroll
  for (int off = 32; off > 0; off >>= 1) s += __shfl_down(s, off);
  if (t == 0) wsn[n] = sqrtf(s);
}

// ---------------- KT: repack T_g[r][h][k][l][g] -> fp16 frag tiles ----------------
// T2[g][r][Nt=l*4+(k>>4)][ks=h>>5][fragoff(k&15, h&31)]
__global__ __launch_bounds__(256) void k_repack2(const float* __restrict__ Tg, unsigned short* __restrict__ T2)
{
  const int r = blockIdx.x >> 6, h = blockIdx.x & 63;
  const float2* in2 = (const float2*)(Tg + (size_t)(r * 64 + h) * 8192);
  const int tid = threadIdx.x;
  const int ks = h >> 5, hr = h & 31;
  #pragma unroll
  for (int p = 0; p < 16; ++p) {
    int idx = tid + p * 256;
    int k = idx >> 6, l = idx & 63;
    float2 tv = in2[k * 64 + l];
    size_t fo = fragoff(k & 15, hr);
    size_t base0 = ((((size_t)(0 * 8 + r) * 256 + l * 4 + (k >> 4)) * 2 + ks) << 9) + fo;
    size_t base1 = ((((size_t)(1 * 8 + r) * 256 + l * 4 + (k >> 4)) * 2 + ks) << 9) + fo;
    T2[base0] = f2h(tv.x);
    T2[base1] = f2h(tv.y);
  }
}

// ---------------- K1: v_t/q_t/a_t = relu(x @ (g*V/||V||)^T + b) (fp32) ----------------
__global__ __launch_bounds__(256) void k_proj(
    const float* __restrict__ inv, const float* __restrict__ inq, const float* __restrict__ ina,
    const float* __restrict__ Wv, const float* __restrict__ Wq, const float* __restrict__ Wa,
    const float* __restrict__ gv, const float* __restrict__ gq, const float* __restrict__ ga,
    const float* __restrict__ bv, const float* __restrict__ bq, const float* __restrict__ ba,
    const float* __restrict__ wsn,
    float* __restrict__ ov, float* __restrict__ oq, float* __restrict__ oa)
{
  const int z = blockIdx.z;
  const float* in   = (z == 0) ? inv : (z == 1) ? inq : ina;
  const float* W    = (z == 0) ? Wv  : (z == 1) ? Wq  : Wa;
  const float* bias = (z == 0) ? bv  : (z == 1) ? bq  : ba;
  float* out        = (z == 0) ? ov  : (z == 1) ? oq  : oa;
  const float scale = ((z == 0) ? gv[0] : (z == 1) ? gq[0] : ga[0]) / wsn[z];

  const int m0 = blockIdx.y * 64, n0 = blockIdx.x * 64;
  __shared__ __align__(16) float As[32][68];
  __shared__ __align__(16) float Bs[32][68];
  const int tid = threadIdx.x;
  const int tx = tid & 15, ty = tid >> 4;
  float c[4][4] = {{0.f}};

  for (int k0 = 0; k0 < 512; k0 += 32) {
    #pragma unroll
    for (int i = 0; i < 8; ++i) {
      int idx = tid + i * 256;
      int kk = idx & 31, rr = idx >> 5;
      As[kk][rr] = in[(m0 + rr) * 512 + k0 + kk];
      Bs[kk][rr] = W[(n0 + rr) * 512 + k0 + kk];
    }
    __syncthreads();
    #pragma unroll
    for (int kk = 0; kk < 32; ++kk) {
      const float4 a4 = *(const float4*)&As[kk][ty * 4];
      const float4 b4 = *(const float4*)&Bs[kk][tx * 4];
      const float aa[4] = {a4.x, a4.y, a4.z, a4.w};
      const float bb[4] = {b4.x, b4.y, b4.z, b4.w};
      #pragma unroll
      for (int i = 0; i < 4; ++i)
        #pragma unroll
        for (int j = 0; j < 4; ++j)
          c[i][j] += aa[i] * bb[j];
    }
    __syncthreads();
  }
  #pragma unroll
  for (int i = 0; i < 4; ++i)
    #pragma unroll
    for (int j = 0; j < 4; ++j) {
      int m = m0 + ty * 4 + i, n = n0 + tx * 4 + j;
      float val = c[i][j] * scale + bias[n];
      out[m * 512 + n] = fmaxf(val, 0.f);
    }
}

// ---------------- K2: per-rank projections -> fp16 fragment-order operands ----------------
__global__ __launch_bounds__(256) void k_rproj2(
    const float* __restrict__ vt, const float* __restrict__ qt, const float* __restrict__ at,
    const float* __restrict__ Vnv, const float* __restrict__ Vnqa,
    const float* __restrict__ gnv, const float* __restrict__ gnqa,
    const float* __restrict__ bnv, const float* __restrict__ bnqa,
    const float* __restrict__ wsn,
    unsigned short* __restrict__ vrT2, unsigned short* __restrict__ qrT2,
    unsigned short* __restrict__ arT2)
{
  const int z = blockIdx.z, r = blockIdx.x, m0 = blockIdx.y * 64;
  const float* in = (z == 0) ? vt : (z == 1) ? qt : at;
  const float* Wn = ((z == 0) ? Vnv : Vnqa) + r * 64 * 512;
  const float scale = (z == 0) ? (gnv[r] / wsn[3 + r]) : (gnqa[r] / wsn[11 + r]);
  const float* bias = ((z == 0) ? bnv : bnqa) + r * 64;

  __shared__ __align__(16) float As[32][68];
  __shared__ __align__(16) float Bs[32][68];
  const int tid = threadIdx.x;
  const int tx = tid & 15, ty = tid >> 4;
  float c[4][4] = {{0.f}};

  for (int k0 = 0; k0 < 512; k0 += 32) {
    #pragma unroll
    for (int i = 0; i < 8; ++i) {
      int idx = tid + i * 256;
      int kk = idx & 31, rr = idx >> 5;
      As[kk][rr] = in[(m0 + rr) * 512 + k0 + kk];
      Bs[kk][rr] = Wn[rr * 512 + k0 + kk];
    }
    __syncthreads();
    #pragma unroll
    for (int kk = 0; kk < 32; ++kk) {
      const float4 a4 = *(const float4*)&As[kk][ty * 4];
      const float4 b4 = *(const float4*)&Bs[kk][tx * 4];
      const float aa[4] = {a4.x, a4.y, a4.z, a4.w};
      const float bb[4] = {b4.x, b4.y, b4.z, b4.w};
      #pragma unroll
      for (int i = 0; i < 4; ++i)
        #pragma unroll
        for (int j = 0; j < 4; ++j)
          c[i][j] += aa[i] * bb[j];
    }
    __syncthreads();
  }
  #pragma unroll
  for (int i = 0; i < 4; ++i)
    #pragma unroll
    for (int j = 0; j < 4; ++j) {
      int mm = m0 + ty * 4 + i;
      int bb = mm >> 6, nr = mm & 63;   // nr = position index (v/q/m)
      int n = tx * 4 + j;               // n = unit index (h/k/l)
      float val = fmaxf(c[i][j] * scale + bias[n], 0.f);
      unsigned short hv = f2h(val);
      if (z == 0) {
        vrT2[(size_t)(bb * 8 + r) * 4096 + ((nr >> 4) * 2 + (n >> 5)) * 512 + fragoff(nr, n & 31)] = hv;
      } else if (z == 1) {
        qrT2[(size_t)(bb * 8 + r) * 4096 + ((nr >> 4) * 2 + (n >> 5)) * 512 + fragoff(nr, n & 31)] = hv;
      } else {
        arT2[(size_t)(((bb * 8 + r) * 2 + (n >> 5)) * 4 + (nr >> 4)) * 512 + fragoff(nr, n & 31)] = hv;
      }
    }
}

// ---------------- K3a: stage1 U[v,(l,k)] = v_r @ T (fp16 MFMA) ----------------
// grid (b16, rq4, ntB4), 512 thr. Writes U frag-tiles for stage2.
__global__ __launch_bounds__(512) void k_stage1(
    const unsigned short* __restrict__ vrT2, const unsigned short* __restrict__ T2,
    unsigned short* __restrict__ U, int g, int rh)
{
  const int b = blockIdx.x, rq = blockIdx.y, ntB = blockIdx.z;
  const int r = rh * 4 + rq;
  const int tid = threadIdx.x, lane = tid & 63;
  const int w = __builtin_amdgcn_readfirstlane(tid >> 6);

  __shared__ __align__(16) unsigned short VR[4096];
  __shared__ __align__(16) unsigned short TC[16384];
  __shared__ __align__(16) unsigned short ST[16384];

  // stage v_r frags (8 KB)
  {
    const float4* s = (const float4*)(vrT2 + (size_t)(b * 8 + r) * 4096);
    *(float4*)&VR[tid * 8] = s[tid];
  }

  const size_t t2base = ((size_t)(g * 8 + r) * 256 + ntB * 64) * 1024;

  for (int sb = 0; sb < 4; ++sb) {
    // stage T chunk (32 KB, contiguous)
    {
      const float4* s = (const float4*)(T2 + t2base + (size_t)sb * 16384);
      float4* d = (float4*)TC;
      #pragma unroll
      for (int i = 0; i < 4; ++i) d[tid + i * 512] = s[tid + i * 512];
    }
    __syncthreads();

    f32x4 c[4][2];
    #pragma unroll
    for (int mt = 0; mt < 4; ++mt)
      #pragma unroll
      for (int nt = 0; nt < 2; ++nt)
        c[mt][nt] = (f32x4){0.f, 0.f, 0.f, 0.f};

    f16x8 af[4][2], bf[2][2];
    #pragma unroll
    for (int mt = 0; mt < 4; ++mt)
      #pragma unroll
      for (int ks = 0; ks < 2; ++ks)
        af[mt][ks] = *(const f16x8*)&VR[mt * 1024 + ks * 512 + lane * 8];
    #pragma unroll
    for (int nt = 0; nt < 2; ++nt)
      #pragma unroll
      for (int ks = 0; ks < 2; ++ks)
        bf[nt][ks] = *(const f16x8*)&TC[(w * 2 + nt) * 1024 + ks * 512 + lane * 8];

    #pragma unroll
    for (int mt = 0; mt < 4; ++mt)
      #pragma unroll
      for (int nt = 0; nt < 2; ++nt)
        #pragma unroll
        for (int ks = 0; ks < 2; ++ks)
          c[mt][nt] = __builtin_amdgcn_mfma_f32_16x16x32_f16(af[mt][ks], bf[nt][ks], c[mt][nt], 0, 0, 0);

    // epilogue: scatter D into ST in U-frag order
    #pragma unroll
    for (int mt = 0; mt < 4; ++mt)
      #pragma unroll
      for (int nt = 0; nt < 2; ++nt) {
        const int Nt = ntB * 64 + sb * 16 + w * 2 + nt;
        const int n = Nt * 16 + (lane & 15);
        const int l = n >> 6, k = n & 63;
        #pragma unroll
        for (int i = 0; i < 4; ++i) {
          const int v = mt * 16 + 4 * (lane >> 4) + i;
          const int row16 = 8 * (l & 1) + (v & 7);
          const int el = ((v >> 3) * 2 + ((l >> 1) & 1)) * 1024 + (k >> 5) * 512 + fragoff(row16, k & 31);
          ST[el] = f2h(c[mt][nt][i]);
        }
      }
    __syncthreads();

    // copy ST -> U (16 regions of 2 KB, each contiguous in U)
    {
      const int l0 = ntB * 16 + sb * 4;
      const int lc = l0 >> 5;
      const int mtU0 = (l0 >> 1) & 15;
      const int rg = tid >> 5, idx = tid & 31;
      const int vt = rg >> 1, mtrel = rg & 1;
      unsigned short* dst = U + ((size_t)(((b * 8 + vt) * 4 + rq) * 2 + lc)) * 16384
                              + (size_t)(mtU0 + mtrel) * 1024;
      const float4* s = (const float4*)&ST[rg * 1024];
      float4* d = (float4*)dst;
      #pragma unroll
      for (int i = 0; i < 4; ++i) d[idx + i * 32] = s[idx + i * 32];
    }
    __syncthreads();
  }
}

// ---------------- K3b: stage2+3 fused: C = U @ q_r^T ; f += C @ a_r^T ----------------
// grid (b16, vt8, qh2), 512 thr. Accumulates 4 ranks in MFMA regs; accum adds into fout.
__global__ __launch_bounds__(512) void k_stage23(
    const unsigned short* __restrict__ U, const unsigned short* __restrict__ qrT2,
    const unsigned short* __restrict__ arT2, float* __restrict__ fout,
    int g, int rh, int accum)
{
  const int b = blockIdx.x, vt = blockIdx.y, qh = blockIdx.z;
  const int tid = threadIdx.x, lane = tid & 63;
  const int w = __builtin_amdgcn_readfirstlane(tid >> 6);

  __shared__ __align__(16) unsigned short UA[16384];
  __shared__ __align__(16) unsigned short QB[2048];
  __shared__ __align__(16) unsigned short AB[2048];
  __shared__ __align__(16) unsigned short CC[8192];

  f32x4 f[2][4];
  #pragma unroll
  for (int qt = 0; qt < 2; ++qt)
    #pragma unroll
    for (int nt = 0; nt < 4; ++nt)
      f[qt][nt] = (f32x4){0.f, 0.f, 0.f, 0.f};

  for (int rq = 0; rq < 4; ++rq) {
    const int r = rh * 4 + rq;
    const float4* sq = (const float4*)(qrT2 + (size_t)(b * 8 + r) * 4096 + qh * 2048);

    for (int lc = 0; lc < 2; ++lc) {
      // stage UA (32 KB)
      {
        const float4* su = (const float4*)(U + ((size_t)(((b * 8 + vt) * 4 + rq) * 2 + lc)) * 16384);
        float4* du = (float4*)UA;
        #pragma unroll
        for (int i = 0; i < 4; ++i) du[tid + i * 512] = su[tid + i * 512];
      }
      // stage AB (4 KB)
      {
        const float4* sa = (const float4*)(arT2 + ((size_t)((b * 8 + r) * 2 + lc)) * 2048);
        if (tid < 256) ((float4*)AB)[tid] = sa[tid];
      }
      // stage QB (4 KB, once per r)
      if (lc == 0 && tid >= 256) ((float4*)QB)[tid - 256] = sq[tid - 256];
      __syncthreads();

      // ---- stage2: C[(l,v), q] = sum_k U * q_r ----
      f32x4 c2[2][2];
      #pragma unroll
      for (int mi = 0; mi < 2; ++mi)
        #pragma unroll
        for (int nt = 0; nt < 2; ++nt)
          c2[mi][nt] = (f32x4){0.f, 0.f, 0.f, 0.f};

      f16x8 a2[2][2], b2[2][2];
      #pragma unroll
      for (int mi = 0; mi < 2; ++mi)
        #pragma unroll
        for (int ks = 0; ks < 2; ++ks)
          a2[mi][ks] = *(const f16x8*)&UA[(w * 2 + mi) * 1024 + ks * 512 + lane * 8];
      #pragma unroll
      for (int nt = 0; nt < 2; ++nt)
        #pragma unroll
        for (int ks = 0; ks < 2; ++ks)
          b2[nt][ks] = *(const f16x8*)&QB[nt * 1024 + ks * 512 + lane * 8];

      #pragma unroll
      for (int mi = 0; mi < 2; ++mi)
        #pragma unroll
        for (int nt = 0; nt < 2; ++nt)
          #pragma unroll
          for (int ks = 0; ks < 2; ++ks)
            c2[mi][nt] = __builtin_amdgcn_mfma_f32_16x16x32_f16(a2[mi][ks], b2[nt][ks], c2[mi][nt], 0, 0, 0);

      // write C into CC in stage3-frag order
      #pragma unroll
      for (int mi = 0; mi < 2; ++mi)
        #pragma unroll
        for (int nt = 0; nt < 2; ++nt)
          #pragma unroll
          for (int i = 0; i < 4; ++i) {
            const int row = (w * 2 + mi) * 16 + 4 * (lane >> 4) + i;
            const int l = row >> 3, v = row & 7;
            const int el = (v * 2 + nt) * 512 + fragoff(lane & 15, l);
            CC[el] = f2h(c2[mi][nt][i]);
          }
      __syncthreads();

      // ---- stage3: f[v=w] += C @ a_r^T ----
      f16x8 a3[2], b3[4];
      #pragma unroll
      for (int qt = 0; qt < 2; ++qt)
        a3[qt] = *(const f16x8*)&CC[(w * 2 + qt) * 512 + lane * 8];
      #pragma unroll
      for (int nt = 0; nt < 4; ++nt)
        b3[nt] = *(const f16x8*)&AB[nt * 512 + lane * 8];

      #pragma unroll
      for (int qt = 0; qt < 2; ++qt)
        #pragma unroll
        for (int nt = 0; nt < 4; ++nt)
          f[qt][nt] = __builtin_amdgcn_mfma_f32_16x16x32_f16(a3[qt], b3[nt], f[qt][nt], 0, 0, 0);
      __syncthreads();
    }
  }

  // epilogue: write f tile to fout[b][v][q][m][g]
  #pragma unroll
  for (int qt = 0; qt < 2; ++qt)
    #pragma unroll
    for (int nt = 0; nt < 4; ++nt)
      #pragma unroll
      for (int i = 0; i < 4; ++i) {
        const int q = qh * 32 + qt * 16 + 4 * (lane >> 4) + i;
        const int m = nt * 16 + (lane & 15);
        size_t addr = ((((size_t)b * 64 + vt * 8 + w) * 64 + q) * 64 + m) * 2 + g;
        float val = f[qt][nt][i];
        if (accum) val += fout[addr];
        fout[addr] = val;
      }
}

// ---------------- K4b: logits partial per (b,v): Lp[b,v,d] ----------------
__global__ __launch_bounds__(512) void k_logits(
    const float* __restrict__ vt, const float* __restrict__ qt, const float* __restrict__ at,
    const float* __restrict__ fout, float* __restrict__ Lp)
{
  const int v = blockIdx.x, b = blockIdx.y, d = threadIdx.x;
  const float* fo = fout + ((size_t)(b * 64 + v)) * 8192;

  float atm[64];
  #pragma unroll
  for (int m = 0; m < 64; ++m) atm[m] = at[(b * 64 + m) * 512 + d];

  float sd = 0.f;
  #pragma unroll 1
  for (int q = 0; q < 64; ++q) {
    const float qv = qt[(b * 64 + q) * 512 + d];
    const float4* Fq = (const float4*)(fo + q * 128);  // block-uniform address
    float inner = 0.f;
    #pragma unroll
    for (int mq = 0; mq < 4; ++mq) {
      float4 fv[8];
      #pragma unroll
      for (int t = 0; t < 8; ++t) fv[t] = Fq[mq * 8 + t];
      #pragma unroll
      for (int t = 0; t < 8; ++t) {
        const int m = mq * 16 + t * 2;
        inner += (fv[t].x + fv[t].y) * atm[m] + (fv[t].z + fv[t].w) * atm[m + 1];
      }
    }
    sd += qv * inner;
  }
  Lp[((size_t)(b * 64 + v)) * 512 + d] = vt[(b * 64 + v) * 512 + d] * sd;
}

// ---------------- K5: reduce logits over v ----------------
__global__ __launch_bounds__(512) void k_lred(const float* __restrict__ Lp, float* __restrict__ Lraw)
{
  const int b = blockIdx.x, d = threadIdx.x;
  float s = 0.f;
  for (int v = 0; v < 64; ++v) s += Lp[(size_t)(b * 64 + v) * 512 + d];
  Lraw[b * 512 + d] = s;
}

// ---------------- K6: batchnorm over batch dim ----------------
__global__ __launch_bounds__(512) void k_bn(
    const float* __restrict__ Lraw, const float* __restrict__ gamma,
    const float* __restrict__ beta, float* __restrict__ lout)
{
  const int d = threadIdx.x;
  float x[16]; float mu = 0.f;
  #pragma unroll
  for (int b = 0; b < 16; ++b) { x[b] = Lraw[b * 512 + d]; mu += x[b]; }
  mu *= (1.f / 16.f);
  float var = 0.f;
  #pragma unroll
  for (int b = 0; b < 16; ++b) { float t = x[b] - mu; var += t * t; }
  var *= (1.f / 16.f);
  const float sc = gamma[d] / sqrtf(var + 1e-5f);
  const float bt = beta[d];
  #pragma unroll
  for (int b = 0; b < 16; ++b) lout[b * 512 + d] = (x[b] - mu) * sc + bt;
}

extern "C" void kernel_launch(void* const* d_in, const int* in_sizes, int n_in,
                              void* d_out, int out_size, void* d_ws, size_t ws_size,
                              hipStream_t stream)
{
  const float* v    = (const float*)d_in[0];
  const float* q    = (const float*)d_in[1];
  const float* a    = (const float*)d_in[2];
  const float* Vv   = (const float*)d_in[3];
  const float* gv   = (const float*)d_in[4];
  const float* bv   = (const float*)d_in[5];
  const float* Vq   = (const float*)d_in[6];
  const float* gq   = (const float*)d_in[7];
  const float* bq   = (const float*)d_in[8];
  const float* Va   = (const float*)d_in[9];
  const float* ga   = (const float*)d_in[10];
  const float* ba   = (const float*)d_in[11];
  const float* Vnv  = (const float*)d_in[12];
  const float* gnv  = (const float*)d_in[13];
  const float* bnv  = (const float*)d_in[14];
  const float* Vnqa = (const float*)d_in[15];
  const float* gnqa = (const float*)d_in[16];
  const float* bnqa = (const float*)d_in[17];
  const float* Tg   = (const float*)d_in[18];
  const float* gamma= (const float*)d_in[19];
  const float* beta = (const float*)d_in[20];

  float* ws   = (float*)d_ws;
  unsigned short* hb = (unsigned short*)(ws + WS_H);
  float* fout = (float*)d_out;
  float* lout = fout + (size_t)16 * 64 * 64 * 64 * 2;

  k_norms_part<<<320, 256, 0, stream>>>(Vv, Vq, Va, Vnv, Vnqa, ws + WS_PRT);
  k_norms_fin<<<19, 64, 0, stream>>>(ws + WS_PRT, ws + WS_NRM);
  k_repack2<<<512, 256, 0, stream>>>(Tg, hb + H_T2);
  k_proj<<<dim3(8, 16, 3), 256, 0, stream>>>(v, q, a, Vv, Vq, Va, gv, gq, ga,
                                             bv, bq, ba, ws + WS_NRM,
                                             ws + WS_VT, ws + WS_QT, ws + WS_AT);
  k_rproj2<<<dim3(8, 16, 3), 256, 0, stream>>>(ws + WS_VT, ws + WS_QT, ws + WS_AT,
                                               Vnv, Vnqa, gnv, gnqa, bnv, bnqa,
                                               ws + WS_NRM,
                                               hb + H_VR2, hb + H_QR2, hb + H_AR2);
  for (int g = 0; g < 2; ++g)
    for (int rh = 0; rh < 2; ++rh) {
      k_stage1<<<dim3(16, 4, 4), 512, 0, stream>>>(hb + H_VR2, hb + H_T2, hb + H_U, g, rh);
      k_stage23<<<dim3(16, 8, 2), 512, 0, stream>>>(hb + H_U, hb + H_QR2, hb + H_AR2,
                                                    fout, g, rh, rh);
    }
  k_logits<<<dim3(64, 16), 512, 0, stream>>>(ws + WS_VT, ws + WS_QT, ws + WS_AT,
                                             fout, ws + WS_LP);
  k_lred<<<16, 512, 0, stream>>>(ws + WS_LP, ws + WS_LR);
  k_bn<<<1, 512, 0, stream>>>(ws + WS_LR, gamma, beta, lout);
}

// Round 5
// 295.115 us; speedup vs baseline: 4.2889x; 1.8494x over previous
//
#include <hip/hip_runtime.h>
#include <hip/hip_fp16.h>
#include <math.h>

// Problem dims: B=16, N=64, D=512, H=512, R=8, HK=64, G=2
// Outputs: f_emb [16,64,64,64,2] (8388608 f32) then logits [16,512] (8192 f32)

typedef _Float16 f16x8 __attribute__((ext_vector_type(8)));
typedef float f32x4 __attribute__((ext_vector_type(4)));

__device__ __forceinline__ unsigned short f2h(float x) {
  _Float16 h = (_Float16)x;
  return __builtin_bit_cast(unsigned short, h);
}

// fragment scatter map for 16x16x32 (row16, kr in 0..31):
//   lane = (row&15) + (((kr>>2)&3)<<4) ; j = (kr&3) + (((kr>>4)&1)<<2)
// element offset within a 512-el frag-tile = lane*8 + j
__device__ __forceinline__ int fragoff(int row, int kr) {
  return (((row & 15) + (((kr >> 2) & 3) << 4)) << 3) + (kr & 3) + (((kr >> 4) & 1) << 2);
}

// ---------------- workspace layout ----------------
// float region:
#define WS_NRM 0                      // 32 floats
#define WS_VT  32                     // v_t [1024][512] f32
#define WS_QT  (WS_VT + 524288)
#define WS_AT  (WS_QT + 524288)
#define WS_LP  (WS_AT + 524288)       // logits per-v partial [b][v][d]
#define WS_LR  (WS_LP + 524288)       // raw logits [b][d]
#define WS_PRT (WS_LR + 8192)         // norm partials 19*64 (pad 1280)
#define WS_H   (WS_PRT + 1280)        // half region starts here (16B aligned)
// half (ushort) offsets from hbase:
#define H_VR2 0                        // v_r frags [b][r][mt4][ks2][512]  (524288)
#define H_QR2 524288                   // q_r frags [b][r][nt4][ks2][512]
#define H_AR2 1048576                  // a_r frags [b][r][lc2][nt4][512]
#define H_T2  1572864                  // T frags [g][r][Nt256][ks2][512]  (4194304)
#define H_U   5767168                  // U frags per (g,rh): [b][vt][rq][lc][16384] (16777216)
#define H_AT16 22544384                // at fp16 B-frags [b][dt32][ks2][512] (524288)

// ---------------- K0a: norm partials (parallel, coalesced float4) ----------------
__global__ __launch_bounds__(256) void k_norms_part(
    const float* __restrict__ Vv, const float* __restrict__ Vq, const float* __restrict__ Va,
    const float* __restrict__ Vnv, const float* __restrict__ Vnqa, float* __restrict__ prt)
{
  const int bx = blockIdx.x;
  int n, j;
  const float* base;
  if (bx < 192) {
    n = bx >> 6; j = bx & 63;
    base = (n == 0 ? Vv : n == 1 ? Vq : Va) + j * 4096;
  } else {
    int t = bx - 192;
    n = 3 + (t >> 3); j = t & 7;
    base = (n < 11 ? Vnv + (n - 3) * 32768 : Vnqa + (n - 11) * 32768) + j * 4096;
  }
  const float4* p4 = (const float4*)base;
  float s = 0.f;
  #pragma unroll
  for (int i = 0; i < 4; ++i) {
    float4 x = p4[threadIdx.x + i * 256];
    s += x.x * x.x + x.y * x.y + x.z * x.z + x.w * x.w;
  }
  __shared__ float red[256];
  red[threadIdx.x] = s; __syncthreads();
  for (int off = 128; off > 0; off >>= 1) {
    if (threadIdx.x < off) red[threadIdx.x] += red[threadIdx.x + off];
    __syncthreads();
  }
  if (threadIdx.x == 0) prt[n * 64 + j] = red[0];
}

// ---------------- K0b: finalize norms ----------------
__global__ __launch_bounds__(64) void k_norms_fin(const float* __restrict__ prt, float* __restrict__ wsn)
{
  const int n = blockIdx.x, t = threadIdx.x;
  const int cnt = (n < 3) ? 64 : 8;
  float s = (t < cnt) ? prt[n * 64 + t] : 0.f;
  #pragma unroll
  for (int off = 32; off > 0; off >>= 1) s += __shfl_down(s, off);
  if (t == 0) wsn[n] = sqrtf(s);
}

// ---------------- KT: repack T_g[r][h][k][l][g] -> fp16 frag tiles ----------------
__global__ __launch_bounds__(256) void k_repack2(const float* __restrict__ Tg, unsigned short* __restrict__ T2)
{
  const int r = blockIdx.x >> 6, h = blockIdx.x & 63;
  const float2* in2 = (const float2*)(Tg + (size_t)(r * 64 + h) * 8192);
  const int tid = threadIdx.x;
  const int ks = h >> 5, hr = h & 31;
  #pragma unroll
  for (int p = 0; p < 16; ++p) {
    int idx = tid + p * 256;
    int k = idx >> 6, l = idx & 63;
    float2 tv = in2[k * 64 + l];
    size_t fo = fragoff(k & 15, hr);
    size_t base0 = ((((size_t)(0 * 8 + r) * 256 + l * 4 + (k >> 4)) * 2 + ks) << 9) + fo;
    size_t base1 = ((((size_t)(1 * 8 + r) * 256 + l * 4 + (k >> 4)) * 2 + ks) << 9) + fo;
    T2[base0] = f2h(tv.x);
    T2[base1] = f2h(tv.y);
  }
}

// ---------------- K1: v_t/q_t/a_t = relu(x @ (g*V/||V||)^T + b) (fp32) ----------------
__global__ __launch_bounds__(256) void k_proj(
    const float* __restrict__ inv, const float* __restrict__ inq, const float* __restrict__ ina,
    const float* __restrict__ Wv, const float* __restrict__ Wq, const float* __restrict__ Wa,
    const float* __restrict__ gv, const float* __restrict__ gq, const float* __restrict__ ga,
    const float* __restrict__ bv, const float* __restrict__ bq, const float* __restrict__ ba,
    const float* __restrict__ wsn,
    float* __restrict__ ov, float* __restrict__ oq, float* __restrict__ oa)
{
  const int z = blockIdx.z;
  const float* in   = (z == 0) ? inv : (z == 1) ? inq : ina;
  const float* W    = (z == 0) ? Wv  : (z == 1) ? Wq  : Wa;
  const float* bias = (z == 0) ? bv  : (z == 1) ? bq  : ba;
  float* out        = (z == 0) ? ov  : (z == 1) ? oq  : oa;
  const float scale = ((z == 0) ? gv[0] : (z == 1) ? gq[0] : ga[0]) / wsn[z];

  const int m0 = blockIdx.y * 64, n0 = blockIdx.x * 64;
  __shared__ __align__(16) float As[32][68];
  __shared__ __align__(16) float Bs[32][68];
  const int tid = threadIdx.x;
  const int tx = tid & 15, ty = tid >> 4;
  float c[4][4] = {{0.f}};

  for (int k0 = 0; k0 < 512; k0 += 32) {
    #pragma unroll
    for (int i = 0; i < 8; ++i) {
      int idx = tid + i * 256;
      int kk = idx & 31, rr = idx >> 5;
      As[kk][rr] = in[(m0 + rr) * 512 + k0 + kk];
      Bs[kk][rr] = W[(n0 + rr) * 512 + k0 + kk];
    }
    __syncthreads();
    #pragma unroll
    for (int kk = 0; kk < 32; ++kk) {
      const float4 a4 = *(const float4*)&As[kk][ty * 4];
      const float4 b4 = *(const float4*)&Bs[kk][tx * 4];
      const float aa[4] = {a4.x, a4.y, a4.z, a4.w};
      const float bb[4] = {b4.x, b4.y, b4.z, b4.w};
      #pragma unroll
      for (int i = 0; i < 4; ++i)
        #pragma unroll
        for (int j = 0; j < 4; ++j)
          c[i][j] += aa[i] * bb[j];
    }
    __syncthreads();
  }
  #pragma unroll
  for (int i = 0; i < 4; ++i)
    #pragma unroll
    for (int j = 0; j < 4; ++j) {
      int m = m0 + ty * 4 + i, n = n0 + tx * 4 + j;
      float val = c[i][j] * scale + bias[n];
      out[m * 512 + n] = fmaxf(val, 0.f);
    }
}

// ---------------- K2: per-rank projections -> fp16 fragment-order operands ----------------
__global__ __launch_bounds__(256) void k_rproj2(
    const float* __restrict__ vt, const float* __restrict__ qt, const float* __restrict__ at,
    const float* __restrict__ Vnv, const float* __restrict__ Vnqa,
    const float* __restrict__ gnv, const float* __restrict__ gnqa,
    const float* __restrict__ bnv, const float* __restrict__ bnqa,
    const float* __restrict__ wsn,
    unsigned short* __restrict__ vrT2, unsigned short* __restrict__ qrT2,
    unsigned short* __restrict__ arT2)
{
  const int z = blockIdx.z, r = blockIdx.x, m0 = blockIdx.y * 64;
  const float* in = (z == 0) ? vt : (z == 1) ? qt : at;
  const float* Wn = ((z == 0) ? Vnv : Vnqa) + r * 64 * 512;
  const float scale = (z == 0) ? (gnv[r] / wsn[3 + r]) : (gnqa[r] / wsn[11 + r]);
  const float* bias = ((z == 0) ? bnv : bnqa) + r * 64;

  __shared__ __align__(16) float As[32][68];
  __shared__ __align__(16) float Bs[32][68];
  const int tid = threadIdx.x;
  const int tx = tid & 15, ty = tid >> 4;
  float c[4][4] = {{0.f}};

  for (int k0 = 0; k0 < 512; k0 += 32) {
    #pragma unroll
    for (int i = 0; i < 8; ++i) {
      int idx = tid + i * 256;
      int kk = idx & 31, rr = idx >> 5;
      As[kk][rr] = in[(m0 + rr) * 512 + k0 + kk];
      Bs[kk][rr] = Wn[rr * 512 + k0 + kk];
    }
    __syncthreads();
    #pragma unroll
    for (int kk = 0; kk < 32; ++kk) {
      const float4 a4 = *(const float4*)&As[kk][ty * 4];
      const float4 b4 = *(const float4*)&Bs[kk][tx * 4];
      const float aa[4] = {a4.x, a4.y, a4.z, a4.w};
      const float bb[4] = {b4.x, b4.y, b4.z, b4.w};
      #pragma unroll
      for (int i = 0; i < 4; ++i)
        #pragma unroll
        for (int j = 0; j < 4; ++j)
          c[i][j] += aa[i] * bb[j];
    }
    __syncthreads();
  }
  #pragma unroll
  for (int i = 0; i < 4; ++i)
    #pragma unroll
    for (int j = 0; j < 4; ++j) {
      int mm = m0 + ty * 4 + i;
      int bb = mm >> 6, nr = mm & 63;   // nr = position index (v/q/m)
      int n = tx * 4 + j;               // n = unit index (h/k/l)
      float val = fmaxf(c[i][j] * scale + bias[n], 0.f);
      unsigned short hv = f2h(val);
      if (z == 0) {
        vrT2[(size_t)(bb * 8 + r) * 4096 + ((nr >> 4) * 2 + (n >> 5)) * 512 + fragoff(nr, n & 31)] = hv;
      } else if (z == 1) {
        qrT2[(size_t)(bb * 8 + r) * 4096 + ((nr >> 4) * 2 + (n >> 5)) * 512 + fragoff(nr, n & 31)] = hv;
      } else {
        arT2[(size_t)(((bb * 8 + r) * 2 + (n >> 5)) * 4 + (nr >> 4)) * 512 + fragoff(nr, n & 31)] = hv;
      }
    }
}

// ---------------- K2b: at (fp32) -> fp16 B-frags for logits GEMM ----------------
// AT16[b][d>>4][m>>5][fragoff(d&15, m&31)]
__global__ __launch_bounds__(256) void k_at16(
    const float* __restrict__ at, unsigned short* __restrict__ AT16)
{
  const int b = blockIdx.x >> 3, slice = blockIdx.x & 7;
  const float4* src = (const float4*)(at + (size_t)b * 32768 + slice * 4096);
  unsigned short* dst = AT16 + (size_t)b * 32768;
  #pragma unroll
  for (int i = 0; i < 4; ++i) {
    int fi = threadIdx.x + i * 256;           // float4 idx within slice (0..1023)
    int gfi = slice * 1024 + fi;              // global float4 idx within b-slice
    int m = gfi >> 7, d0 = (gfi & 127) * 4;
    float4 x = src[fi];
    float xv[4] = {x.x, x.y, x.z, x.w};
    #pragma unroll
    for (int t = 0; t < 4; ++t) {
      int d = d0 + t;
      dst[((d >> 4) * 2 + (m >> 5)) * 512 + fragoff(d & 15, m & 31)] = f2h(xv[t]);
    }
  }
}

// ---------------- K3a: stage1 U[v,(l,k)] = v_r @ T (fp16 MFMA) ----------------
__global__ __launch_bounds__(512) void k_stage1(
    const unsigned short* __restrict__ vrT2, const unsigned short* __restrict__ T2,
    unsigned short* __restrict__ U, int g, int rh)
{
  const int b = blockIdx.x, rq = blockIdx.y, ntB = blockIdx.z;
  const int r = rh * 4 + rq;
  const int tid = threadIdx.x, lane = tid & 63;
  const int w = __builtin_amdgcn_readfirstlane(tid >> 6);

  __shared__ __align__(16) unsigned short VR[4096];
  __shared__ __align__(16) unsigned short TC[16384];
  __shared__ __align__(16) unsigned short ST[16384];

  // stage v_r frags (8 KB)
  {
    const float4* s = (const float4*)(vrT2 + (size_t)(b * 8 + r) * 4096);
    *(float4*)&VR[tid * 8] = s[tid];
  }

  const size_t t2base = ((size_t)(g * 8 + r) * 256 + ntB * 64) * 1024;

  for (int sb = 0; sb < 4; ++sb) {
    // stage T chunk (32 KB, contiguous)
    {
      const float4* s = (const float4*)(T2 + t2base + (size_t)sb * 16384);
      float4* d = (float4*)TC;
      #pragma unroll
      for (int i = 0; i < 4; ++i) d[tid + i * 512] = s[tid + i * 512];
    }
    __syncthreads();

    f32x4 c[4][2];
    #pragma unroll
    for (int mt = 0; mt < 4; ++mt)
      #pragma unroll
      for (int nt = 0; nt < 2; ++nt)
        c[mt][nt] = (f32x4){0.f, 0.f, 0.f, 0.f};

    f16x8 af[4][2], bf[2][2];
    #pragma unroll
    for (int mt = 0; mt < 4; ++mt)
      #pragma unroll
      for (int ks = 0; ks < 2; ++ks)
        af[mt][ks] = *(const f16x8*)&VR[mt * 1024 + ks * 512 + lane * 8];
    #pragma unroll
    for (int nt = 0; nt < 2; ++nt)
      #pragma unroll
      for (int ks = 0; ks < 2; ++ks)
        bf[nt][ks] = *(const f16x8*)&TC[(w * 2 + nt) * 1024 + ks * 512 + lane * 8];

    #pragma unroll
    for (int mt = 0; mt < 4; ++mt)
      #pragma unroll
      for (int nt = 0; nt < 2; ++nt)
        #pragma unroll
        for (int ks = 0; ks < 2; ++ks)
          c[mt][nt] = __builtin_amdgcn_mfma_f32_16x16x32_f16(af[mt][ks], bf[nt][ks], c[mt][nt], 0, 0, 0);

    // epilogue: scatter D into ST in U-frag order
    #pragma unroll
    for (int mt = 0; mt < 4; ++mt)
      #pragma unroll
      for (int nt = 0; nt < 2; ++nt) {
        const int Nt = ntB * 64 + sb * 16 + w * 2 + nt;
        const int n = Nt * 16 + (lane & 15);
        const int l = n >> 6, k = n & 63;
        #pragma unroll
        for (int i = 0; i < 4; ++i) {
          const int v = mt * 16 + 4 * (lane >> 4) + i;
          const int row16 = 8 * (l & 1) + (v & 7);
          const int el = ((v >> 3) * 2 + ((l >> 1) & 1)) * 1024 + (k >> 5) * 512 + fragoff(row16, k & 31);
          ST[el] = f2h(c[mt][nt][i]);
        }
      }
    __syncthreads();

    // copy ST -> U (16 regions of 2 KB, each contiguous in U)
    {
      const int l0 = ntB * 16 + sb * 4;
      const int lc = l0 >> 5;
      const int mtU0 = (l0 >> 1) & 15;
      const int rg = tid >> 5, idx = tid & 31;
      const int vt = rg >> 1, mtrel = rg & 1;
      unsigned short* dst = U + ((size_t)(((b * 8 + vt) * 4 + rq) * 2 + lc)) * 16384
                              + (size_t)(mtU0 + mtrel) * 1024;
      const float4* s = (const float4*)&ST[rg * 1024];
      float4* d = (float4*)dst;
      #pragma unroll
      for (int i = 0; i < 4; ++i) d[idx + i * 32] = s[idx + i * 32];
    }
    __syncthreads();
  }
}

// ---------------- K3b: stage2+3 fused: C = U @ q_r^T ; f += C @ a_r^T ----------------
__global__ __launch_bounds__(512) void k_stage23(
    const unsigned short* __restrict__ U, const unsigned short* __restrict__ qrT2,
    const unsigned short* __restrict__ arT2, float* __restrict__ fout,
    int g, int rh, int accum)
{
  const int b = blockIdx.x, vt = blockIdx.y, qh = blockIdx.z;
  const int tid = threadIdx.x, lane = tid & 63;
  const int w = __builtin_amdgcn_readfirstlane(tid >> 6);

  __shared__ __align__(16) unsigned short UA[16384];
  __shared__ __align__(16) unsigned short QB[2048];
  __shared__ __align__(16) unsigned short AB[2048];
  __shared__ __align__(16) unsigned short CC[8192];

  f32x4 f[2][4];
  #pragma unroll
  for (int qt = 0; qt < 2; ++qt)
    #pragma unroll
    for (int nt = 0; nt < 4; ++nt)
      f[qt][nt] = (f32x4){0.f, 0.f, 0.f, 0.f};

  for (int rq = 0; rq < 4; ++rq) {
    const int r = rh * 4 + rq;
    const float4* sq = (const float4*)(qrT2 + (size_t)(b * 8 + r) * 4096 + qh * 2048);

    for (int lc = 0; lc < 2; ++lc) {
      // stage UA (32 KB)
      {
        const float4* su = (const float4*)(U + ((size_t)(((b * 8 + vt) * 4 + rq) * 2 + lc)) * 16384);
        float4* du = (float4*)UA;
        #pragma unroll
        for (int i = 0; i < 4; ++i) du[tid + i * 512] = su[tid + i * 512];
      }
      // stage AB (4 KB)
      {
        const float4* sa = (const float4*)(arT2 + ((size_t)((b * 8 + r) * 2 + lc)) * 2048);
        if (tid < 256) ((float4*)AB)[tid] = sa[tid];
      }
      // stage QB (4 KB, once per r)
      if (lc == 0 && tid >= 256) ((float4*)QB)[tid - 256] = sq[tid - 256];
      __syncthreads();

      // ---- stage2: C[(l,v), q] = sum_k U * q_r ----
      f32x4 c2[2][2];
      #pragma unroll
      for (int mi = 0; mi < 2; ++mi)
        #pragma unroll
        for (int nt = 0; nt < 2; ++nt)
          c2[mi][nt] = (f32x4){0.f, 0.f, 0.f, 0.f};

      f16x8 a2[2][2], b2[2][2];
      #pragma unroll
      for (int mi = 0; mi < 2; ++mi)
        #pragma unroll
        for (int ks = 0; ks < 2; ++ks)
          a2[mi][ks] = *(const f16x8*)&UA[(w * 2 + mi) * 1024 + ks * 512 + lane * 8];
      #pragma unroll
      for (int nt = 0; nt < 2; ++nt)
        #pragma unroll
        for (int ks = 0; ks < 2; ++ks)
          b2[nt][ks] = *(const f16x8*)&QB[nt * 1024 + ks * 512 + lane * 8];

      #pragma unroll
      for (int mi = 0; mi < 2; ++mi)
        #pragma unroll
        for (int nt = 0; nt < 2; ++nt)
          #pragma unroll
          for (int ks = 0; ks < 2; ++ks)
            c2[mi][nt] = __builtin_amdgcn_mfma_f32_16x16x32_f16(a2[mi][ks], b2[nt][ks], c2[mi][nt], 0, 0, 0);

      // write C into CC in stage3-frag order
      #pragma unroll
      for (int mi = 0; mi < 2; ++mi)
        #pragma unroll
        for (int nt = 0; nt < 2; ++nt)
          #pragma unroll
          for (int i = 0; i < 4; ++i) {
            const int row = (w * 2 + mi) * 16 + 4 * (lane >> 4) + i;
            const int l = row >> 3, v = row & 7;
            const int el = (v * 2 + nt) * 512 + fragoff(lane & 15, l);
            CC[el] = f2h(c2[mi][nt][i]);
          }
      __syncthreads();

      // ---- stage3: f[v=w] += C @ a_r^T ----
      f16x8 a3[2], b3[4];
      #pragma unroll
      for (int qt = 0; qt < 2; ++qt)
        a3[qt] = *(const f16x8*)&CC[(w * 2 + qt) * 512 + lane * 8];
      #pragma unroll
      for (int nt = 0; nt < 4; ++nt)
        b3[nt] = *(const f16x8*)&AB[nt * 512 + lane * 8];

      #pragma unroll
      for (int qt = 0; qt < 2; ++qt)
        #pragma unroll
        for (int nt = 0; nt < 4; ++nt)
          f[qt][nt] = __builtin_amdgcn_mfma_f32_16x16x32_f16(a3[qt], b3[nt], f[qt][nt], 0, 0, 0);
      __syncthreads();
    }
  }

  // epilogue: write f tile to fout[b][v][q][m][g]
  #pragma unroll
  for (int qt = 0; qt < 2; ++qt)
    #pragma unroll
    for (int nt = 0; nt < 4; ++nt)
      #pragma unroll
      for (int i = 0; i < 4; ++i) {
        const int q = qh * 32 + qt * 16 + 4 * (lane >> 4) + i;
        const int m = nt * 16 + (lane & 15);
        size_t addr = ((((size_t)b * 64 + vt * 8 + w) * 64 + q) * 64 + m) * 2 + g;
        float val = f[qt][nt][i];
        if (accum) val += fout[addr];
        fout[addr] = val;
      }
}

// ---------------- K4: logits via MFMA per (b,v) ----------------
// inner[q,d] = sum_m (F[q,m,0]+F[q,m,1]) * at[m,d]  (fp16 MFMA)
// Lp[b,v,d] = vt[b,v,d] * sum_q qt[b,q,d] * inner[q,d]
__global__ __launch_bounds__(512) void k_logits2(
    const float* __restrict__ vt, const float* __restrict__ qt,
    const unsigned short* __restrict__ AT16, const float* __restrict__ fout,
    float* __restrict__ Lp)
{
  const int v = blockIdx.x, b = blockIdx.y;
  const int tid = threadIdx.x, lane = tid & 63;
  const int w = __builtin_amdgcn_readfirstlane(tid >> 6);

  __shared__ __align__(16) unsigned int FAu[2048];  // Fsum A-frags [mt2+ks? -> (mt*2+ks)][512 halves]

  // stage Fsum -> fp16 A-frags (coalesced float4 reads, packed u32 LDS writes)
  {
    const float4* fo4 = (const float4*)(fout + ((size_t)(b * 64 + v)) * 8192);
    #pragma unroll
    for (int i = 0; i < 4; ++i) {
      int fi = tid + i * 512;            // 0..2047
      int q = fi >> 5, mpair = fi & 31;  // m0 = mpair*2
      float4 x = fo4[fi];
      float s0 = x.x + x.y, s1 = x.z + x.w;
      int m0 = mpair * 2;
      int off = fragoff(q & 15, m0 & 31);  // even
      int idx2 = (((q >> 4) * 2 + (m0 >> 5)) * 512 + off) >> 1;
      unsigned int pk = (unsigned int)f2h(s0) | ((unsigned int)f2h(s1) << 16);
      FAu[idx2] = pk;
    }
  }
  __syncthreads();

  const unsigned short* FAh = (const unsigned short*)FAu;

  // load A-frags from LDS, B-frags from global (each wave: d-chunk = w*64)
  f16x8 af[4][2], bf[4][2];
  #pragma unroll
  for (int mt = 0; mt < 4; ++mt)
    #pragma unroll
    for (int ks = 0; ks < 2; ++ks)
      af[mt][ks] = *(const f16x8*)&FAh[(mt * 2 + ks) * 512 + lane * 8];
  #pragma unroll
  for (int nt = 0; nt < 4; ++nt)
    #pragma unroll
    for (int ks = 0; ks < 2; ++ks)
      bf[nt][ks] = *(const f16x8*)&AT16[(size_t)((b * 32 + w * 4 + nt) * 2 + ks) * 512 + lane * 8];

  f32x4 c[4][4];
  #pragma unroll
  for (int mt = 0; mt < 4; ++mt)
    #pragma unroll
    for (int nt = 0; nt < 4; ++nt)
      c[mt][nt] = (f32x4){0.f, 0.f, 0.f, 0.f};

  #pragma unroll
  for (int mt = 0; mt < 4; ++mt)
    #pragma unroll
    for (int nt = 0; nt < 4; ++nt)
      #pragma unroll
      for (int ks = 0; ks < 2; ++ks)
        c[mt][nt] = __builtin_amdgcn_mfma_f32_16x16x32_f16(af[mt][ks], bf[nt][ks], c[mt][nt], 0, 0, 0);

  // epilogue: s_d = sum_q qt[q,d]*inner[q,d]; Lp = vt*s_d
  const int gr = lane >> 4, dl = lane & 15;
  #pragma unroll
  for (int nt = 0; nt < 4; ++nt) {
    const int d = w * 64 + nt * 16 + dl;
    float partial = 0.f;
    #pragma unroll
    for (int mt = 0; mt < 4; ++mt) {
      #pragma unroll
      for (int i = 0; i < 4; ++i) {
        const int q = mt * 16 + gr * 4 + i;
        partial += qt[(b * 64 + q) * 512 + d] * c[mt][nt][i];
      }
    }
    partial += __shfl_xor(partial, 16);
    partial += __shfl_xor(partial, 32);
    const float val = vt[(b * 64 + v) * 512 + d] * partial;
    if (lane < 16) Lp[((size_t)(b * 64 + v)) * 512 + d] = val;
  }
}

// ---------------- K5: reduce logits over v ----------------
__global__ __launch_bounds__(512) void k_lred(const float* __restrict__ Lp, float* __restrict__ Lraw)
{
  const int b = blockIdx.x, d = threadIdx.x;
  float s = 0.f;
  for (int v = 0; v < 64; ++v) s += Lp[(size_t)(b * 64 + v) * 512 + d];
  Lraw[b * 512 + d] = s;
}

// ---------------- K6: batchnorm over batch dim ----------------
__global__ __launch_bounds__(512) void k_bn(
    const float* __restrict__ Lraw, const float* __restrict__ gamma,
    const float* __restrict__ beta, float* __restrict__ lout)
{
  const int d = threadIdx.x;
  float x[16]; float mu = 0.f;
  #pragma unroll
  for (int b = 0; b < 16; ++b) { x[b] = Lraw[b * 512 + d]; mu += x[b]; }
  mu *= (1.f / 16.f);
  float var = 0.f;
  #pragma unroll
  for (int b = 0; b < 16; ++b) { float t = x[b] - mu; var += t * t; }
  var *= (1.f / 16.f);
  const float sc = gamma[d] / sqrtf(var + 1e-5f);
  const float bt = beta[d];
  #pragma unroll
  for (int b = 0; b < 16; ++b) lout[b * 512 + d] = (x[b] - mu) * sc + bt;
}

extern "C" void kernel_launch(void* const* d_in, const int* in_sizes, int n_in,
                              void* d_out, int out_size, void* d_ws, size_t ws_size,
                              hipStream_t stream)
{
  const float* v    = (const float*)d_in[0];
  const float* q    = (const float*)d_in[1];
  const float* a    = (const float*)d_in[2];
  const float* Vv   = (const float*)d_in[3];
  const float* gv   = (const float*)d_in[4];
  const float* bv   = (const float*)d_in[5];
  const float* Vq   = (const float*)d_in[6];
  const float* gq   = (const float*)d_in[7];
  const float* bq   = (const float*)d_in[8];
  const float* Va   = (const float*)d_in[9];
  const float* ga   = (const float*)d_in[10];
  const float* ba   = (const float*)d_in[11];
  const float* Vnv  = (const float*)d_in[12];
  const float* gnv  = (const float*)d_in[13];
  const float* bnv  = (const float*)d_in[14];
  const float* Vnqa = (const float*)d_in[15];
  const float* gnqa = (const float*)d_in[16];
  const float* bnqa = (const float*)d_in[17];
  const float* Tg   = (const float*)d_in[18];
  const float* gamma= (const float*)d_in[19];
  const float* beta = (const float*)d_in[20];

  float* ws   = (float*)d_ws;
  unsigned short* hb = (unsigned short*)(ws + WS_H);
  float* fout = (float*)d_out;
  float* lout = fout + (size_t)16 * 64 * 64 * 64 * 2;

  k_norms_part<<<320, 256, 0, stream>>>(Vv, Vq, Va, Vnv, Vnqa, ws + WS_PRT);
  k_norms_fin<<<19, 64, 0, stream>>>(ws + WS_PRT, ws + WS_NRM);
  k_repack2<<<512, 256, 0, stream>>>(Tg, hb + H_T2);
  k_proj<<<dim3(8, 16, 3), 256, 0, stream>>>(v, q, a, Vv, Vq, Va, gv, gq, ga,
                                             bv, bq, ba, ws + WS_NRM,
                                             ws + WS_VT, ws + WS_QT, ws + WS_AT);
  k_rproj2<<<dim3(8, 16, 3), 256, 0, stream>>>(ws + WS_VT, ws + WS_QT, ws + WS_AT,
                                               Vnv, Vnqa, gnv, gnqa, bnv, bnqa,
                                               ws + WS_NRM,
                                               hb + H_VR2, hb + H_QR2, hb + H_AR2);
  k_at16<<<128, 256, 0, stream>>>(ws + WS_AT, hb + H_AT16);
  for (int g = 0; g < 2; ++g)
    for (int rh = 0; rh < 2; ++rh) {
      k_stage1<<<dim3(16, 4, 4), 512, 0, stream>>>(hb + H_VR2, hb + H_T2, hb + H_U, g, rh);
      k_stage23<<<dim3(16, 8, 2), 512, 0, stream>>>(hb + H_U, hb + H_QR2, hb + H_AR2,
                                                    fout, g, rh, rh);
    }
  k_logits2<<<dim3(64, 16), 512, 0, stream>>>(ws + WS_VT, ws + WS_QT,
                                              hb + H_AT16, fout, ws + WS_LP);
  k_lred<<<16, 512, 0, stream>>>(ws + WS_LP, ws + WS_LR);
  k_bn<<<1, 512, 0, stream>>>(ws + WS_LR, gamma, beta, lout);
}

// Round 6
// 236.732 us; speedup vs baseline: 5.3466x; 1.2466x over previous
//
#include <hip/hip_runtime.h>
#include <hip/hip_fp16.h>
#include <math.h>

// Problem dims: B=16, N=64, D=512, H=512, R=8, HK=64, G=2
// Outputs: f_emb [16,64,64,64,2] (8388608 f32) then logits [16,512] (8192 f32)

typedef _Float16 f16x8 __attribute__((ext_vector_type(8)));
typedef float f32x4 __attribute__((ext_vector_type(4)));

__device__ __forceinline__ unsigned short f2h(float x) {
  _Float16 h = (_Float16)x;
  return __builtin_bit_cast(unsigned short, h);
}

// fragment scatter map for 16x16x32 (row16, kr in 0..31):
//   lane = (row&15) + (((kr>>2)&3)<<4) ; j = (kr&3) + (((kr>>4)&1)<<2)
// element offset within a 512-el frag-tile = lane*8 + j
__device__ __forceinline__ int fragoff(int row, int kr) {
  return (((row & 15) + (((kr >> 2) & 3) << 4)) << 3) + (kr & 3) + (((kr >> 4) & 1) << 2);
}

// ---------------- workspace layout ----------------
// float region:
#define WS_NRM 0                      // 32 floats
#define WS_VT  32                     // v_t [1024][512] f32
#define WS_QT  (WS_VT + 524288)
#define WS_AT  (WS_QT + 524288)
#define WS_LP  (WS_AT + 524288)       // logits per-v partial [b][v][d]
#define WS_LR  (WS_LP + 524288)       // raw logits [b][d]
#define WS_PRT (WS_LR + 8192)         // norm partials 19*64 (pad 1280)
#define WS_H   (WS_PRT + 1280)        // half region starts here (16B aligned)
// half (ushort) offsets from hbase:
#define H_VR2 0                        // v_r frags [b][r][mt4][ks2][512]  (524288)
#define H_QR2 524288                   // q_r frags
#define H_AR2 1048576                  // a_r frags
#define H_T2  1572864                  // T frags [g][r][Nt256][ks2][512]  (4194304)
#define H_U   5767168                  // U frags per (g,rh) (16777216)
#define H_AT16 22544384                // at fp16 B-frags for logits (524288)
#define H_IN16 23068672                // raw inputs v/q/a A-frags [z][rt64][ks16][512] (1572864)
#define H_WB16 24641536                // scaled proj weights B-frags [z][nt32][ks16][512] (786432)
#define H_WN16 25427968                // scaled rank weights B-frags [zq*8+r][nt4][ks16][512] (524288)
#define H_RP16 25952256                // proj outputs A-frags [z][rt64][ks16][512] (1572864)

// ---------------- K0a: norm partials (parallel, coalesced float4) ----------------
__global__ __launch_bounds__(256) void k_norms_part(
    const float* __restrict__ Vv, const float* __restrict__ Vq, const float* __restrict__ Va,
    const float* __restrict__ Vnv, const float* __restrict__ Vnqa, float* __restrict__ prt)
{
  const int bx = blockIdx.x;
  int n, j;
  const float* base;
  if (bx < 192) {
    n = bx >> 6; j = bx & 63;
    base = (n == 0 ? Vv : n == 1 ? Vq : Va) + j * 4096;
  } else {
    int t = bx - 192;
    n = 3 + (t >> 3); j = t & 7;
    base = (n < 11 ? Vnv + (n - 3) * 32768 : Vnqa + (n - 11) * 32768) + j * 4096;
  }
  const float4* p4 = (const float4*)base;
  float s = 0.f;
  #pragma unroll
  for (int i = 0; i < 4; ++i) {
    float4 x = p4[threadIdx.x + i * 256];
    s += x.x * x.x + x.y * x.y + x.z * x.z + x.w * x.w;
  }
  __shared__ float red[256];
  red[threadIdx.x] = s; __syncthreads();
  for (int off = 128; off > 0; off >>= 1) {
    if (threadIdx.x < off) red[threadIdx.x] += red[threadIdx.x + off];
    __syncthreads();
  }
  if (threadIdx.x == 0) prt[n * 64 + j] = red[0];
}

// ---------------- K0b: finalize norms ----------------
__global__ __launch_bounds__(64) void k_norms_fin(const float* __restrict__ prt, float* __restrict__ wsn)
{
  const int n = blockIdx.x, t = threadIdx.x;
  const int cnt = (n < 3) ? 64 : 8;
  float s = (t < cnt) ? prt[n * 64 + t] : 0.f;
  #pragma unroll
  for (int off = 32; off > 0; off >>= 1) s += __shfl_down(s, off);
  if (t == 0) wsn[n] = sqrtf(s);
}

// ---------------- KC1: raw inputs v/q/a -> fp16 A-frags [z][rt][ks][512] ----------------
__global__ __launch_bounds__(256) void k_inconv16(
    const float* __restrict__ v, const float* __restrict__ q, const float* __restrict__ a,
    unsigned short* __restrict__ IN16)
{
  const int z = blockIdx.y;
  const float4* src = (const float4*)((z == 0) ? v : (z == 1) ? q : a);
  #pragma unroll
  for (int i = 0; i < 8; ++i) {
    int f = blockIdx.x * 2048 + threadIdx.x + i * 256;  // f4 idx, row=f>>7
    int row = f >> 7, d0 = (f & 127) * 4;
    float4 x = src[f];
    ushort4 pk;
    pk.x = f2h(x.x); pk.y = f2h(x.y); pk.z = f2h(x.z); pk.w = f2h(x.w);
    int lanep = (row & 15) + (((d0 >> 2) & 3) << 4);
    int jb = ((d0 >> 4) & 1) << 2;
    size_t off = ((size_t)(z * 64 + (row >> 4)) * 16 + (d0 >> 5)) * 512 + lanep * 8 + jb;
    *(ushort4*)&IN16[off] = pk;
  }
}

// ---------------- KC2: proj weights * (g/||V||) -> fp16 B-frags [z][nt32][ks16][512] ----------------
__global__ __launch_bounds__(256) void k_wconv16(
    const float* __restrict__ Wv, const float* __restrict__ Wq, const float* __restrict__ Wa,
    const float* __restrict__ gv, const float* __restrict__ gq, const float* __restrict__ ga,
    const float* __restrict__ wsn, unsigned short* __restrict__ WB16)
{
  const int z = blockIdx.y;
  const float4* src = (const float4*)((z == 0) ? Wv : (z == 1) ? Wq : Wa);
  const float scale = ((z == 0) ? gv[0] : (z == 1) ? gq[0] : ga[0]) / wsn[z];
  #pragma unroll
  for (int i = 0; i < 8; ++i) {
    int f = blockIdx.x * 2048 + threadIdx.x + i * 256;  // over 512x512/4
    int n = f >> 7, d0 = (f & 127) * 4;
    float4 x = src[f];
    ushort4 pk;
    pk.x = f2h(x.x * scale); pk.y = f2h(x.y * scale);
    pk.z = f2h(x.z * scale); pk.w = f2h(x.w * scale);
    int lanep = (n & 15) + (((d0 >> 2) & 3) << 4);
    int jb = ((d0 >> 4) & 1) << 2;
    size_t off = ((size_t)(z * 32 + (n >> 4)) * 16 + (d0 >> 5)) * 512 + lanep * 8 + jb;
    *(ushort4*)&WB16[off] = pk;
  }
}

// ---------------- KC3: rank weights * (gn/||Vn||) -> fp16 B-frags [(zq*8+r)][nt4][ks16][512] ----------------
__global__ __launch_bounds__(256) void k_wnconv16(
    const float* __restrict__ Vnv, const float* __restrict__ Vnqa,
    const float* __restrict__ gnv, const float* __restrict__ gnqa,
    const float* __restrict__ wsn, unsigned short* __restrict__ WN16)
{
  const int zr = blockIdx.x >> 2, sub = blockIdx.x & 3;
  const int zq = zr >> 3, r = zr & 7;
  const float4* src = (const float4*)((zq == 0 ? Vnv : Vnqa) + (size_t)r * 32768);
  const float scale = (zq == 0) ? (gnv[r] / wsn[3 + r]) : (gnqa[r] / wsn[11 + r]);
  #pragma unroll
  for (int i = 0; i < 8; ++i) {
    int f = sub * 2048 + threadIdx.x + i * 256;  // over 64*512/4 = 8192
    int n = f >> 7, d0 = (f & 127) * 4;
    float4 x = src[f];
    ushort4 pk;
    pk.x = f2h(x.x * scale); pk.y = f2h(x.y * scale);
    pk.z = f2h(x.z * scale); pk.w = f2h(x.w * scale);
    int lanep = (n & 15) + (((d0 >> 2) & 3) << 4);
    int jb = ((d0 >> 4) & 1) << 2;
    size_t off = ((size_t)(zr * 4 + (n >> 4)) * 16 + (d0 >> 5)) * 512 + lanep * 8 + jb;
    *(ushort4*)&WN16[off] = pk;
  }
}

// ---------------- KT: repack T via LDS bounce (coalesced in and out) ----------------
// block (r, lB): l-range of 4; out tiles T2[g][r][Nt = lB*16 .. +16][ks2][512]
__global__ __launch_bounds__(256) void k_repack2b(const float* __restrict__ Tg, unsigned short* __restrict__ T2)
{
  const int r = blockIdx.x >> 4, lB = blockIdx.x & 15;
  __shared__ unsigned short lds[32768];  // [g2][Nt_rel16][ks2][512]
  const int tid = threadIdx.x;

  // read: 8192 float4 over [h64][k64][lpair2] at l0 = lB*4 + lpair*2
  #pragma unroll
  for (int i = 0; i < 32; ++i) {
    int f = tid + i * 256;
    int lpair = f & 1, k = (f >> 1) & 63, h = f >> 7;
    int l0 = lB * 4 + lpair * 2;
    const float4 x = *(const float4*)(Tg + ((size_t)((r * 64 + h) * 64 + k) * 64 + l0) * 2);
    const int el = fragoff(k & 15, h & 31);
    const int ks = h >> 5;
    const int ntr0 = (l0 & 3) * 4 + (k >> 4);
    const int ntr1 = ((l0 + 1) & 3) * 4 + (k >> 4);
    lds[((0 * 16 + ntr0) * 2 + ks) * 512 + el] = f2h(x.x);
    lds[((1 * 16 + ntr0) * 2 + ks) * 512 + el] = f2h(x.y);
    lds[((0 * 16 + ntr1) * 2 + ks) * 512 + el] = f2h(x.z);
    lds[((1 * 16 + ntr1) * 2 + ks) * 512 + el] = f2h(x.w);
  }
  __syncthreads();

  // write: per g, 16384 halves contiguous
  #pragma unroll
  for (int g = 0; g < 2; ++g) {
    unsigned short* dst = T2 + ((size_t)(g * 8 + r) * 256 + lB * 16) * 1024;
    const float4* s = (const float4*)&lds[g * 16384];
    float4* d = (float4*)dst;
    #pragma unroll
    for (int i = 0; i < 8; ++i) d[tid + i * 256] = s[tid + i * 256];
  }
}

// ---------------- K1: proj via fp16 MFMA ----------------
// grid (nB8, mB16, z3), 256 thr = 4 waves; block tile M64 x N64; wave tile M64 x N16.
// Writes f32 out (vt/qt/at) + fp16 A-frags RP16 for rproj.
__global__ __launch_bounds__(256) void k_proj16(
    const unsigned short* __restrict__ IN16, const unsigned short* __restrict__ WB16,
    const float* __restrict__ bv, const float* __restrict__ bq, const float* __restrict__ ba,
    float* __restrict__ ov, float* __restrict__ oq, float* __restrict__ oa,
    unsigned short* __restrict__ RP16)
{
  const int nB = blockIdx.x, mB = blockIdx.y, z = blockIdx.z;
  const float* bias = (z == 0) ? bv : (z == 1) ? bq : ba;
  float* out = (z == 0) ? ov : (z == 1) ? oq : oa;
  const int tid = threadIdx.x, lane = tid & 63;
  const int w = __builtin_amdgcn_readfirstlane(tid >> 6);

  f32x4 c[4];
  #pragma unroll
  for (int mt = 0; mt < 4; ++mt) c[mt] = (f32x4){0.f, 0.f, 0.f, 0.f};

  #pragma unroll 4
  for (int ks = 0; ks < 16; ++ks) {
    f16x8 af[4], bfr;
    #pragma unroll
    for (int mt = 0; mt < 4; ++mt)
      af[mt] = *(const f16x8*)&IN16[((size_t)(z * 64 + mB * 4 + mt) * 16 + ks) * 512 + lane * 8];
    bfr = *(const f16x8*)&WB16[((size_t)(z * 32 + nB * 4 + w) * 16 + ks) * 512 + lane * 8];
    #pragma unroll
    for (int mt = 0; mt < 4; ++mt)
      c[mt] = __builtin_amdgcn_mfma_f32_16x16x32_f16(af[mt], bfr, c[mt], 0, 0, 0);
  }

  const int col = nB * 64 + w * 16 + (lane & 15);
  const float bb = bias[col];
  #pragma unroll
  for (int mt = 0; mt < 4; ++mt)
    #pragma unroll
    for (int i = 0; i < 4; ++i) {
      const int row = mB * 64 + mt * 16 + 4 * (lane >> 4) + i;
      float val = fmaxf(c[mt][i] + bb, 0.f);
      out[(size_t)row * 512 + col] = val;
      RP16[((size_t)(z * 64 + (row >> 4)) * 16 + (col >> 5)) * 512 + fragoff(row, col & 31)] = f2h(val);
    }
}

// ---------------- K2: per-rank proj via fp16 MFMA ----------------
// grid (r8, mB16, z3), 256 thr = 4 waves (2m x 2n); block tile M64 x N64; wave M32 x N32.
__global__ __launch_bounds__(256) void k_rproj16(
    const unsigned short* __restrict__ RP16, const unsigned short* __restrict__ WN16,
    const float* __restrict__ bnv, const float* __restrict__ bnqa,
    unsigned short* __restrict__ vrT2, unsigned short* __restrict__ qrT2,
    unsigned short* __restrict__ arT2)
{
  const int r = blockIdx.x, mB = blockIdx.y, z = blockIdx.z;
  const int zq = (z == 0) ? 0 : 1;
  const float* bias = ((z == 0) ? bnv : bnqa) + r * 64;
  const int tid = threadIdx.x, lane = tid & 63;
  const int w = __builtin_amdgcn_readfirstlane(tid >> 6);
  const int wm = w >> 1, wn = w & 1;

  f32x4 c[2][2];
  #pragma unroll
  for (int mi = 0; mi < 2; ++mi)
    #pragma unroll
    for (int ni = 0; ni < 2; ++ni) c[mi][ni] = (f32x4){0.f, 0.f, 0.f, 0.f};

  #pragma unroll 4
  for (int ks = 0; ks < 16; ++ks) {
    f16x8 af[2], bf[2];
    #pragma unroll
    for (int mi = 0; mi < 2; ++mi)
      af[mi] = *(const f16x8*)&RP16[((size_t)(z * 64 + mB * 4 + wm * 2 + mi) * 16 + ks) * 512 + lane * 8];
    #pragma unroll
    for (int ni = 0; ni < 2; ++ni)
      bf[ni] = *(const f16x8*)&WN16[((size_t)((zq * 8 + r) * 4 + wn * 2 + ni) * 16 + ks) * 512 + lane * 8];
    #pragma unroll
    for (int mi = 0; mi < 2; ++mi)
      #pragma unroll
      for (int ni = 0; ni < 2; ++ni)
        c[mi][ni] = __builtin_amdgcn_mfma_f32_16x16x32_f16(af[mi], bf[ni], c[mi][ni], 0, 0, 0);
  }

  #pragma unroll
  for (int mi = 0; mi < 2; ++mi)
    #pragma unroll
    for (int ni = 0; ni < 2; ++ni) {
      const int n = (wn * 2 + ni) * 16 + (lane & 15);
      const float bb2 = bias[n];
      #pragma unroll
      for (int i = 0; i < 4; ++i) {
        const int mm = mB * 64 + (wm * 2 + mi) * 16 + 4 * (lane >> 4) + i;
        const int bb = mm >> 6, nr = mm & 63;
        float val = fmaxf(c[mi][ni][i] + bb2, 0.f);
        unsigned short hv = f2h(val);
        if (z == 0)
          vrT2[(size_t)(bb * 8 + r) * 4096 + ((nr >> 4) * 2 + (n >> 5)) * 512 + fragoff(nr, n & 31)] = hv;
        else if (z == 1)
          qrT2[(size_t)(bb * 8 + r) * 4096 + ((nr >> 4) * 2 + (n >> 5)) * 512 + fragoff(nr, n & 31)] = hv;
        else
          arT2[(size_t)(((bb * 8 + r) * 2 + (n >> 5)) * 4 + (nr >> 4)) * 512 + fragoff(nr, n & 31)] = hv;
      }
    }
}

// ---------------- K2b: at (fp32) -> fp16 B-frags for logits GEMM ----------------
__global__ __launch_bounds__(256) void k_at16(
    const float* __restrict__ at, unsigned short* __restrict__ AT16)
{
  const int b = blockIdx.x >> 3, slice = blockIdx.x & 7;
  const float4* src = (const float4*)(at + (size_t)b * 32768 + slice * 4096);
  unsigned short* dst = AT16 + (size_t)b * 32768;
  #pragma unroll
  for (int i = 0; i < 4; ++i) {
    int fi = threadIdx.x + i * 256;
    int gfi = slice * 1024 + fi;
    int m = gfi >> 7, d0 = (gfi & 127) * 4;
    float4 x = src[fi];
    float xv[4] = {x.x, x.y, x.z, x.w};
    #pragma unroll
    for (int t = 0; t < 4; ++t) {
      int d = d0 + t;
      dst[((d >> 4) * 2 + (m >> 5)) * 512 + fragoff(d & 15, m & 31)] = f2h(xv[t]);
    }
  }
}

// ---------------- K3a: stage1 U[v,(l,k)] = v_r @ T (fp16 MFMA) ----------------
__global__ __launch_bounds__(512) void k_stage1(
    const unsigned short* __restrict__ vrT2, const unsigned short* __restrict__ T2,
    unsigned short* __restrict__ U, int g, int rh)
{
  const int b = blockIdx.x, rq = blockIdx.y, ntB = blockIdx.z;
  const int r = rh * 4 + rq;
  const int tid = threadIdx.x, lane = tid & 63;
  const int w = __builtin_amdgcn_readfirstlane(tid >> 6);

  __shared__ __align__(16) unsigned short VR[4096];
  __shared__ __align__(16) unsigned short TC[16384];
  __shared__ __align__(16) unsigned short ST[16384];

  {
    const float4* s = (const float4*)(vrT2 + (size_t)(b * 8 + r) * 4096);
    *(float4*)&VR[tid * 8] = s[tid];
  }

  const size_t t2base = ((size_t)(g * 8 + r) * 256 + ntB * 64) * 1024;

  for (int sb = 0; sb < 4; ++sb) {
    {
      const float4* s = (const float4*)(T2 + t2base + (size_t)sb * 16384);
      float4* d = (float4*)TC;
      #pragma unroll
      for (int i = 0; i < 4; ++i) d[tid + i * 512] = s[tid + i * 512];
    }
    __syncthreads();

    f32x4 c[4][2];
    #pragma unroll
    for (int mt = 0; mt < 4; ++mt)
      #pragma unroll
      for (int nt = 0; nt < 2; ++nt)
        c[mt][nt] = (f32x4){0.f, 0.f, 0.f, 0.f};

    f16x8 af[4][2], bf[2][2];
    #pragma unroll
    for (int mt = 0; mt < 4; ++mt)
      #pragma unroll
      for (int ks = 0; ks < 2; ++ks)
        af[mt][ks] = *(const f16x8*)&VR[mt * 1024 + ks * 512 + lane * 8];
    #pragma unroll
    for (int nt = 0; nt < 2; ++nt)
      #pragma unroll
      for (int ks = 0; ks < 2; ++ks)
        bf[nt][ks] = *(const f16x8*)&TC[(w * 2 + nt) * 1024 + ks * 512 + lane * 8];

    #pragma unroll
    for (int mt = 0; mt < 4; ++mt)
      #pragma unroll
      for (int nt = 0; nt < 2; ++nt)
        #pragma unroll
        for (int ks = 0; ks < 2; ++ks)
          c[mt][nt] = __builtin_amdgcn_mfma_f32_16x16x32_f16(af[mt][ks], bf[nt][ks], c[mt][nt], 0, 0, 0);

    #pragma unroll
    for (int mt = 0; mt < 4; ++mt)
      #pragma unroll
      for (int nt = 0; nt < 2; ++nt) {
        const int Nt = ntB * 64 + sb * 16 + w * 2 + nt;
        const int n = Nt * 16 + (lane & 15);
        const int l = n >> 6, k = n & 63;
        #pragma unroll
        for (int i = 0; i < 4; ++i) {
          const int v = mt * 16 + 4 * (lane >> 4) + i;
          const int row16 = 8 * (l & 1) + (v & 7);
          const int el = ((v >> 3) * 2 + ((l >> 1) & 1)) * 1024 + (k >> 5) * 512 + fragoff(row16, k & 31);
          ST[el] = f2h(c[mt][nt][i]);
        }
      }
    __syncthreads();

    {
      const int l0 = ntB * 16 + sb * 4;
      const int lc = l0 >> 5;
      const int mtU0 = (l0 >> 1) & 15;
      const int rg = tid >> 5, idx = tid & 31;
      const int vt = rg >> 1, mtrel = rg & 1;
      unsigned short* dst = U + ((size_t)(((b * 8 + vt) * 4 + rq) * 2 + lc)) * 16384
                              + (size_t)(mtU0 + mtrel) * 1024;
      const float4* s = (const float4*)&ST[rg * 1024];
      float4* d = (float4*)dst;
      #pragma unroll
      for (int i = 0; i < 4; ++i) d[idx + i * 32] = s[idx + i * 32];
    }
    __syncthreads();
  }
}

// ---------------- K3b: stage2+3 fused ----------------
__global__ __launch_bounds__(512) void k_stage23(
    const unsigned short* __restrict__ U, const unsigned short* __restrict__ qrT2,
    const unsigned short* __restrict__ arT2, float* __restrict__ fout,
    int g, int rh, int accum)
{
  const int b = blockIdx.x, vt = blockIdx.y, qh = blockIdx.z;
  const int tid = threadIdx.x, lane = tid & 63;
  const int w = __builtin_amdgcn_readfirstlane(tid >> 6);

  __shared__ __align__(16) unsigned short UA[16384];
  __shared__ __align__(16) unsigned short QB[2048];
  __shared__ __align__(16) unsigned short AB[2048];
  __shared__ __align__(16) unsigned short CC[8192];

  f32x4 f[2][4];
  #pragma unroll
  for (int qt = 0; qt < 2; ++qt)
    #pragma unroll
    for (int nt = 0; nt < 4; ++nt)
      f[qt][nt] = (f32x4){0.f, 0.f, 0.f, 0.f};

  for (int rq = 0; rq < 4; ++rq) {
    const int r = rh * 4 + rq;
    const float4* sq = (const float4*)(qrT2 + (size_t)(b * 8 + r) * 4096 + qh * 2048);

    for (int lc = 0; lc < 2; ++lc) {
      {
        const float4* su = (const float4*)(U + ((size_t)(((b * 8 + vt) * 4 + rq) * 2 + lc)) * 16384);
        float4* du = (float4*)UA;
        #pragma unroll
        for (int i = 0; i < 4; ++i) du[tid + i * 512] = su[tid + i * 512];
      }
      {
        const float4* sa = (const float4*)(arT2 + ((size_t)((b * 8 + r) * 2 + lc)) * 2048);
        if (tid < 256) ((float4*)AB)[tid] = sa[tid];
      }
      if (lc == 0 && tid >= 256) ((float4*)QB)[tid - 256] = sq[tid - 256];
      __syncthreads();

      f32x4 c2[2][2];
      #pragma unroll
      for (int mi = 0; mi < 2; ++mi)
        #pragma unroll
        for (int nt = 0; nt < 2; ++nt)
          c2[mi][nt] = (f32x4){0.f, 0.f, 0.f, 0.f};

      f16x8 a2[2][2], b2[2][2];
      #pragma unroll
      for (int mi = 0; mi < 2; ++mi)
        #pragma unroll
        for (int ks = 0; ks < 2; ++ks)
          a2[mi][ks] = *(const f16x8*)&UA[(w * 2 + mi) * 1024 + ks * 512 + lane * 8];
      #pragma unroll
      for (int nt = 0; nt < 2; ++nt)
        #pragma unroll
        for (int ks = 0; ks < 2; ++ks)
          b2[nt][ks] = *(const f16x8*)&QB[nt * 1024 + ks * 512 + lane * 8];

      #pragma unroll
      for (int mi = 0; mi < 2; ++mi)
        #pragma unroll
        for (int nt = 0; nt < 2; ++nt)
          #pragma unroll
          for (int ks = 0; ks < 2; ++ks)
            c2[mi][nt] = __builtin_amdgcn_mfma_f32_16x16x32_f16(a2[mi][ks], b2[nt][ks], c2[mi][nt], 0, 0, 0);

      #pragma unroll
      for (int mi = 0; mi < 2; ++mi)
        #pragma unroll
        for (int nt = 0; nt < 2; ++nt)
          #pragma unroll
          for (int i = 0; i < 4; ++i) {
            const int row = (w * 2 + mi) * 16 + 4 * (lane >> 4) + i;
            const int l = row >> 3, v = row & 7;
            const int el = (v * 2 + nt) * 512 + fragoff(lane & 15, l);
            CC[el] = f2h(c2[mi][nt][i]);
          }
      __syncthreads();

      f16x8 a3[2], b3[4];
      #pragma unroll
      for (int qt = 0; qt < 2; ++qt)
        a3[qt] = *(const f16x8*)&CC[(w * 2 + qt) * 512 + lane * 8];
      #pragma unroll
      for (int nt = 0; nt < 4; ++nt)
        b3[nt] = *(const f16x8*)&AB[nt * 512 + lane * 8];

      #pragma unroll
      for (int qt = 0; qt < 2; ++qt)
        #pragma unroll
        for (int nt = 0; nt < 4; ++nt)
          f[qt][nt] = __builtin_amdgcn_mfma_f32_16x16x32_f16(a3[qt], b3[nt], f[qt][nt], 0, 0, 0);
      __syncthreads();
    }
  }

  #pragma unroll
  for (int qt = 0; qt < 2; ++qt)
    #pragma unroll
    for (int nt = 0; nt < 4; ++nt)
      #pragma unroll
      for (int i = 0; i < 4; ++i) {
        const int q = qh * 32 + qt * 16 + 4 * (lane >> 4) + i;
        const int m = nt * 16 + (lane & 15);
        size_t addr = ((((size_t)b * 64 + vt * 8 + w) * 64 + q) * 64 + m) * 2 + g;
        float val = f[qt][nt][i];
        if (accum) val += fout[addr];
        fout[addr] = val;
      }
}

// ---------------- K4: logits via MFMA per (b,v) ----------------
__global__ __launch_bounds__(512) void k_logits2(
    const float* __restrict__ vt, const float* __restrict__ qt,
    const unsigned short* __restrict__ AT16, const float* __restrict__ fout,
    float* __restrict__ Lp)
{
  const int v = blockIdx.x, b = blockIdx.y;
  const int tid = threadIdx.x, lane = tid & 63;
  const int w = __builtin_amdgcn_readfirstlane(tid >> 6);

  __shared__ __align__(16) unsigned int FAu[2048];

  {
    const float4* fo4 = (const float4*)(fout + ((size_t)(b * 64 + v)) * 8192);
    #pragma unroll
    for (int i = 0; i < 4; ++i) {
      int fi = tid + i * 512;
      int q = fi >> 5, mpair = fi & 31;
      float4 x = fo4[fi];
      float s0 = x.x + x.y, s1 = x.z + x.w;
      int m0 = mpair * 2;
      int off = fragoff(q & 15, m0 & 31);
      int idx2 = (((q >> 4) * 2 + (m0 >> 5)) * 512 + off) >> 1;
      unsigned int pk = (unsigned int)f2h(s0) | ((unsigned int)f2h(s1) << 16);
      FAu[idx2] = pk;
    }
  }
  __syncthreads();

  const unsigned short* FAh = (const unsigned short*)FAu;

  f16x8 af[4][2], bf[4][2];
  #pragma unroll
  for (int mt = 0; mt < 4; ++mt)
    #pragma unroll
    for (int ks = 0; ks < 2; ++ks)
      af[mt][ks] = *(const f16x8*)&FAh[(mt * 2 + ks) * 512 + lane * 8];
  #pragma unroll
  for (int nt = 0; nt < 4; ++nt)
    #pragma unroll
    for (int ks = 0; ks < 2; ++ks)
      bf[nt][ks] = *(const f16x8*)&AT16[(size_t)((b * 32 + w * 4 + nt) * 2 + ks) * 512 + lane * 8];

  f32x4 c[4][4];
  #pragma unroll
  for (int mt = 0; mt < 4; ++mt)
    #pragma unroll
    for (int nt = 0; nt < 4; ++nt)
      c[mt][nt] = (f32x4){0.f, 0.f, 0.f, 0.f};

  #pragma unroll
  for (int mt = 0; mt < 4; ++mt)
    #pragma unroll
    for (int nt = 0; nt < 4; ++nt)
      #pragma unroll
      for (int ks = 0; ks < 2; ++ks)
        c[mt][nt] = __builtin_amdgcn_mfma_f32_16x16x32_f16(af[mt][ks], bf[nt][ks], c[mt][nt], 0, 0, 0);

  const int gr = lane >> 4, dl = lane & 15;
  #pragma unroll
  for (int nt = 0; nt < 4; ++nt) {
    const int d = w * 64 + nt * 16 + dl;
    float partial = 0.f;
    #pragma unroll
    for (int mt = 0; mt < 4; ++mt) {
      #pragma unroll
      for (int i = 0; i < 4; ++i) {
        const int q = mt * 16 + gr * 4 + i;
        partial += qt[(b * 64 + q) * 512 + d] * c[mt][nt][i];
      }
    }
    partial += __shfl_xor(partial, 16);
    partial += __shfl_xor(partial, 32);
    const float val = vt[(b * 64 + v) * 512 + d] * partial;
    if (lane < 16) Lp[((size_t)(b * 64 + v)) * 512 + d] = val;
  }
}

// ---------------- K5: reduce logits over v ----------------
__global__ __launch_bounds__(512) void k_lred(const float* __restrict__ Lp, float* __restrict__ Lraw)
{
  const int b = blockIdx.x, d = threadIdx.x;
  float s = 0.f;
  for (int v = 0; v < 64; ++v) s += Lp[(size_t)(b * 64 + v) * 512 + d];
  Lraw[b * 512 + d] = s;
}

// ---------------- K6: batchnorm over batch dim ----------------
__global__ __launch_bounds__(512) void k_bn(
    const float* __restrict__ Lraw, const float* __restrict__ gamma,
    const float* __restrict__ beta, float* __restrict__ lout)
{
  const int d = threadIdx.x;
  float x[16]; float mu = 0.f;
  #pragma unroll
  for (int b = 0; b < 16; ++b) { x[b] = Lraw[b * 512 + d]; mu += x[b]; }
  mu *= (1.f / 16.f);
  float var = 0.f;
  #pragma unroll
  for (int b = 0; b < 16; ++b) { float t = x[b] - mu; var += t * t; }
  var *= (1.f / 16.f);
  const float sc = gamma[d] / sqrtf(var + 1e-5f);
  const float bt = beta[d];
  #pragma unroll
  for (int b = 0; b < 16; ++b) lout[b * 512 + d] = (x[b] - mu) * sc + bt;
}

extern "C" void kernel_launch(void* const* d_in, const int* in_sizes, int n_in,
                              void* d_out, int out_size, void* d_ws, size_t ws_size,
                              hipStream_t stream)
{
  const float* v    = (const float*)d_in[0];
  const float* q    = (const float*)d_in[1];
  const float* a    = (const float*)d_in[2];
  const float* Vv   = (const float*)d_in[3];
  const float* gv   = (const float*)d_in[4];
  const float* bv   = (const float*)d_in[5];
  const float* Vq   = (const float*)d_in[6];
  const float* gq   = (const float*)d_in[7];
  const float* bq   = (const float*)d_in[8];
  const float* Va   = (const float*)d_in[9];
  const float* ga   = (const float*)d_in[10];
  const float* ba   = (const float*)d_in[11];
  const float* Vnv  = (const float*)d_in[12];
  const float* gnv  = (const float*)d_in[13];
  const float* bnv  = (const float*)d_in[14];
  const float* Vnqa = (const float*)d_in[15];
  const float* gnqa = (const float*)d_in[16];
  const float* bnqa = (const float*)d_in[17];
  const float* Tg   = (const float*)d_in[18];
  const float* gamma= (const float*)d_in[19];
  const float* beta = (const float*)d_in[20];

  float* ws   = (float*)d_ws;
  unsigned short* hb = (unsigned short*)(ws + WS_H);
  float* fout = (float*)d_out;
  float* lout = fout + (size_t)16 * 64 * 64 * 64 * 2;

  k_norms_part<<<320, 256, 0, stream>>>(Vv, Vq, Va, Vnv, Vnqa, ws + WS_PRT);
  k_norms_fin<<<19, 64, 0, stream>>>(ws + WS_PRT, ws + WS_NRM);
  k_inconv16<<<dim3(64, 3), 256, 0, stream>>>(v, q, a, hb + H_IN16);
  k_wconv16<<<dim3(32, 3), 256, 0, stream>>>(Vv, Vq, Va, gv, gq, ga, ws + WS_NRM, hb + H_WB16);
  k_wnconv16<<<64, 256, 0, stream>>>(Vnv, Vnqa, gnv, gnqa, ws + WS_NRM, hb + H_WN16);
  k_repack2b<<<128, 256, 0, stream>>>(Tg, hb + H_T2);
  k_proj16<<<dim3(8, 16, 3), 256, 0, stream>>>(hb + H_IN16, hb + H_WB16, bv, bq, ba,
                                               ws + WS_VT, ws + WS_QT, ws + WS_AT,
                                               hb + H_RP16);
  k_at16<<<128, 256, 0, stream>>>(ws + WS_AT, hb + H_AT16);
  k_rproj16<<<dim3(8, 16, 3), 256, 0, stream>>>(hb + H_RP16, hb + H_WN16, bnv, bnqa,
                                                hb + H_VR2, hb + H_QR2, hb + H_AR2);
  for (int g = 0; g < 2; ++g)
    for (int rh = 0; rh < 2; ++rh) {
      k_stage1<<<dim3(16, 4, 4), 512, 0, stream>>>(hb + H_VR2, hb + H_T2, hb + H_U, g, rh);
      k_stage23<<<dim3(16, 8, 2), 512, 0, stream>>>(hb + H_U, hb + H_QR2, hb + H_AR2,
                                                    fout, g, rh, rh);
    }
  k_logits2<<<dim3(64, 16), 512, 0, stream>>>(ws + WS_VT, ws + WS_QT,
                                              hb + H_AT16, fout, ws + WS_LP);
  k_lred<<<16, 512, 0, stream>>>(ws + WS_LP, ws + WS_LR);
  k_bn<<<1, 512, 0, stream>>>(ws + WS_LR, gamma, beta, lout);
}

// Round 7
// 161.507 us; speedup vs baseline: 7.8369x; 1.4658x over previous
//
#include <hip/hip_runtime.h>
#include <hip/hip_fp16.h>
#include <math.h>

// Problem dims: B=16, N=64, D=512, H=512, R=8, HK=64, G=2
// Outputs: f_emb [16,64,64,64,2] (8388608 f32) then logits [16,512] (8192 f32)

typedef _Float16 f16x8 __attribute__((ext_vector_type(8)));
typedef float f32x4 __attribute__((ext_vector_type(4)));

__device__ __forceinline__ unsigned short f2h(float x) {
  _Float16 h = (_Float16)x;
  return __builtin_bit_cast(unsigned short, h);
}

// fragment scatter map for 16x16x32 (row16, kr in 0..31):
//   lane = (row&15) + (((kr>>2)&3)<<4) ; j = (kr&3) + (((kr>>4)&1)<<2)
// element offset within a 512-el frag-tile = lane*8 + j
__device__ __forceinline__ int fragoff(int row, int kr) {
  return (((row & 15) + (((kr >> 2) & 3) << 4)) << 3) + (kr & 3) + (((kr >> 4) & 1) << 2);
}

// ---------------- workspace layout (ws_size = 256 MiB confirmed by harness poison) ----------------
// float region:
#define WS_NRM 0                      // 32 floats
#define WS_VT  32                     // v_t [1024][512] f32
#define WS_QT  (WS_VT + 524288)
#define WS_AT  (WS_QT + 524288)
#define WS_LP  (WS_AT + 524288)       // logits per-v partial [b][v][d]
#define WS_LR  (WS_LP + 524288)       // raw logits [b][d]
#define WS_PRT (WS_LR + 8192)         // norm partials 19*64 (pad 1280)
#define WS_H   (WS_PRT + 1280)        // half region starts here (16B aligned)
// half (ushort) offsets from hbase:
#define H_VR2 0                        // v_r frags [b][r][mt4][ks2][512]  (524288)
#define H_QR2 524288                   // q_r frags
#define H_AR2 1048576                  // a_r frags
#define H_T2  1572864                  // T frags [g][r][Nt256][ks2][512]  (4194304) -> end 5767168
#define H_AT16 5767168                 // at fp16 B-frags for logits (524288) -> end 6291456
#define H_IN16 6291456                 // raw inputs A-frags (1572864) -> end 7864320
#define H_WB16 7864320                 // proj weights B-frags (786432) -> end 8650752
#define H_WN16 8650752                 // rank weights B-frags (524288) -> end 9175040
#define H_RP16 9175040                 // proj outputs A-frags (1572864) -> end 10747904
#define H_U   10747904                 // U frags ALL (g,b,vt,r,lc): 2*16*8*8*2*16384 = 67108864

// ---------------- K0a: norm partials ----------------
__global__ __launch_bounds__(256) void k_norms_part(
    const float* __restrict__ Vv, const float* __restrict__ Vq, const float* __restrict__ Va,
    const float* __restrict__ Vnv, const float* __restrict__ Vnqa, float* __restrict__ prt)
{
  const int bx = blockIdx.x;
  int n, j;
  const float* base;
  if (bx < 192) {
    n = bx >> 6; j = bx & 63;
    base = (n == 0 ? Vv : n == 1 ? Vq : Va) + j * 4096;
  } else {
    int t = bx - 192;
    n = 3 + (t >> 3); j = t & 7;
    base = (n < 11 ? Vnv + (n - 3) * 32768 : Vnqa + (n - 11) * 32768) + j * 4096;
  }
  const float4* p4 = (const float4*)base;
  float s = 0.f;
  #pragma unroll
  for (int i = 0; i < 4; ++i) {
    float4 x = p4[threadIdx.x + i * 256];
    s += x.x * x.x + x.y * x.y + x.z * x.z + x.w * x.w;
  }
  __shared__ float red[256];
  red[threadIdx.x] = s; __syncthreads();
  for (int off = 128; off > 0; off >>= 1) {
    if (threadIdx.x < off) red[threadIdx.x] += red[threadIdx.x + off];
    __syncthreads();
  }
  if (threadIdx.x == 0) prt[n * 64 + j] = red[0];
}

// ---------------- K0b: finalize norms ----------------
__global__ __launch_bounds__(64) void k_norms_fin(const float* __restrict__ prt, float* __restrict__ wsn)
{
  const int n = blockIdx.x, t = threadIdx.x;
  const int cnt = (n < 3) ? 64 : 8;
  float s = (t < cnt) ? prt[n * 64 + t] : 0.f;
  #pragma unroll
  for (int off = 32; off > 0; off >>= 1) s += __shfl_down(s, off);
  if (t == 0) wsn[n] = sqrtf(s);
}

// ---------------- KC1: raw inputs v/q/a -> fp16 A-frags ----------------
__global__ __launch_bounds__(256) void k_inconv16(
    const float* __restrict__ v, const float* __restrict__ q, const float* __restrict__ a,
    unsigned short* __restrict__ IN16)
{
  const int z = blockIdx.y;
  const float4* src = (const float4*)((z == 0) ? v : (z == 1) ? q : a);
  #pragma unroll
  for (int i = 0; i < 8; ++i) {
    int f = blockIdx.x * 2048 + threadIdx.x + i * 256;
    int row = f >> 7, d0 = (f & 127) * 4;
    float4 x = src[f];
    ushort4 pk;
    pk.x = f2h(x.x); pk.y = f2h(x.y); pk.z = f2h(x.z); pk.w = f2h(x.w);
    int lanep = (row & 15) + (((d0 >> 2) & 3) << 4);
    int jb = ((d0 >> 4) & 1) << 2;
    size_t off = ((size_t)(z * 64 + (row >> 4)) * 16 + (d0 >> 5)) * 512 + lanep * 8 + jb;
    *(ushort4*)&IN16[off] = pk;
  }
}

// ---------------- KC2: proj weights scaled -> fp16 B-frags ----------------
__global__ __launch_bounds__(256) void k_wconv16(
    const float* __restrict__ Wv, const float* __restrict__ Wq, const float* __restrict__ Wa,
    const float* __restrict__ gv, const float* __restrict__ gq, const float* __restrict__ ga,
    const float* __restrict__ wsn, unsigned short* __restrict__ WB16)
{
  const int z = blockIdx.y;
  const float4* src = (const float4*)((z == 0) ? Wv : (z == 1) ? Wq : Wa);
  const float scale = ((z == 0) ? gv[0] : (z == 1) ? gq[0] : ga[0]) / wsn[z];
  #pragma unroll
  for (int i = 0; i < 8; ++i) {
    int f = blockIdx.x * 2048 + threadIdx.x + i * 256;
    int n = f >> 7, d0 = (f & 127) * 4;
    float4 x = src[f];
    ushort4 pk;
    pk.x = f2h(x.x * scale); pk.y = f2h(x.y * scale);
    pk.z = f2h(x.z * scale); pk.w = f2h(x.w * scale);
    int lanep = (n & 15) + (((d0 >> 2) & 3) << 4);
    int jb = ((d0 >> 4) & 1) << 2;
    size_t off = ((size_t)(z * 32 + (n >> 4)) * 16 + (d0 >> 5)) * 512 + lanep * 8 + jb;
    *(ushort4*)&WB16[off] = pk;
  }
}

// ---------------- KC3: rank weights scaled -> fp16 B-frags ----------------
__global__ __launch_bounds__(256) void k_wnconv16(
    const float* __restrict__ Vnv, const float* __restrict__ Vnqa,
    const float* __restrict__ gnv, const float* __restrict__ gnqa,
    const float* __restrict__ wsn, unsigned short* __restrict__ WN16)
{
  const int zr = blockIdx.x >> 2, sub = blockIdx.x & 3;
  const int zq = zr >> 3, r = zr & 7;
  const float4* src = (const float4*)((zq == 0 ? Vnv : Vnqa) + (size_t)r * 32768);
  const float scale = (zq == 0) ? (gnv[r] / wsn[3 + r]) : (gnqa[r] / wsn[11 + r]);
  #pragma unroll
  for (int i = 0; i < 8; ++i) {
    int f = sub * 2048 + threadIdx.x + i * 256;
    int n = f >> 7, d0 = (f & 127) * 4;
    float4 x = src[f];
    ushort4 pk;
    pk.x = f2h(x.x * scale); pk.y = f2h(x.y * scale);
    pk.z = f2h(x.z * scale); pk.w = f2h(x.w * scale);
    int lanep = (n & 15) + (((d0 >> 2) & 3) << 4);
    int jb = ((d0 >> 4) & 1) << 2;
    size_t off = ((size_t)(zr * 4 + (n >> 4)) * 16 + (d0 >> 5)) * 512 + lanep * 8 + jb;
    *(ushort4*)&WN16[off] = pk;
  }
}

// ---------------- KT: repack T via LDS bounce ----------------
__global__ __launch_bounds__(256) void k_repack2b(const float* __restrict__ Tg, unsigned short* __restrict__ T2)
{
  const int r = blockIdx.x >> 4, lB = blockIdx.x & 15;
  __shared__ unsigned short lds[32768];
  const int tid = threadIdx.x;

  #pragma unroll
  for (int i = 0; i < 32; ++i) {
    int f = tid + i * 256;
    int lpair = f & 1, k = (f >> 1) & 63, h = f >> 7;
    int l0 = lB * 4 + lpair * 2;
    const float4 x = *(const float4*)(Tg + ((size_t)((r * 64 + h) * 64 + k) * 64 + l0) * 2);
    const int el = fragoff(k & 15, h & 31);
    const int ks = h >> 5;
    const int ntr0 = (l0 & 3) * 4 + (k >> 4);
    const int ntr1 = ((l0 + 1) & 3) * 4 + (k >> 4);
    lds[((0 * 16 + ntr0) * 2 + ks) * 512 + el] = f2h(x.x);
    lds[((1 * 16 + ntr0) * 2 + ks) * 512 + el] = f2h(x.y);
    lds[((0 * 16 + ntr1) * 2 + ks) * 512 + el] = f2h(x.z);
    lds[((1 * 16 + ntr1) * 2 + ks) * 512 + el] = f2h(x.w);
  }
  __syncthreads();

  #pragma unroll
  for (int g = 0; g < 2; ++g) {
    unsigned short* dst = T2 + ((size_t)(g * 8 + r) * 256 + lB * 16) * 1024;
    const float4* s = (const float4*)&lds[g * 16384];
    float4* d = (float4*)dst;
    #pragma unroll
    for (int i = 0; i < 8; ++i) d[tid + i * 256] = s[tid + i * 256];
  }
}

// ---------------- K1: proj via fp16 MFMA (also emits AT16 for logits when z==2) ----------------
__global__ __launch_bounds__(256) void k_proj16(
    const unsigned short* __restrict__ IN16, const unsigned short* __restrict__ WB16,
    const float* __restrict__ bv, const float* __restrict__ bq, const float* __restrict__ ba,
    float* __restrict__ ov, float* __restrict__ oq, float* __restrict__ oa,
    unsigned short* __restrict__ RP16, unsigned short* __restrict__ AT16)
{
  const int nB = blockIdx.x, mB = blockIdx.y, z = blockIdx.z;
  const float* bias = (z == 0) ? bv : (z == 1) ? bq : ba;
  float* out = (z == 0) ? ov : (z == 1) ? oq : oa;
  const int tid = threadIdx.x, lane = tid & 63;
  const int w = __builtin_amdgcn_readfirstlane(tid >> 6);

  f32x4 c[4];
  #pragma unroll
  for (int mt = 0; mt < 4; ++mt) c[mt] = (f32x4){0.f, 0.f, 0.f, 0.f};

  #pragma unroll 4
  for (int ks = 0; ks < 16; ++ks) {
    f16x8 af[4], bfr;
    #pragma unroll
    for (int mt = 0; mt < 4; ++mt)
      af[mt] = *(const f16x8*)&IN16[((size_t)(z * 64 + mB * 4 + mt) * 16 + ks) * 512 + lane * 8];
    bfr = *(const f16x8*)&WB16[((size_t)(z * 32 + nB * 4 + w) * 16 + ks) * 512 + lane * 8];
    #pragma unroll
    for (int mt = 0; mt < 4; ++mt)
      c[mt] = __builtin_amdgcn_mfma_f32_16x16x32_f16(af[mt], bfr, c[mt], 0, 0, 0);
  }

  const int col = nB * 64 + w * 16 + (lane & 15);
  const float bb = bias[col];
  #pragma unroll
  for (int mt = 0; mt < 4; ++mt)
    #pragma unroll
    for (int i = 0; i < 4; ++i) {
      const int row = mB * 64 + mt * 16 + 4 * (lane >> 4) + i;
      float val = fmaxf(c[mt][i] + bb, 0.f);
      unsigned short hv = f2h(val);
      out[(size_t)row * 512 + col] = val;
      RP16[((size_t)(z * 64 + (row >> 4)) * 16 + (col >> 5)) * 512 + fragoff(row, col & 31)] = hv;
      if (z == 2) {
        const int m = row & 63;
        AT16[(size_t)(row >> 6) * 32768 + ((col >> 4) * 2 + (m >> 5)) * 512 + fragoff(col & 15, m & 31)] = hv;
      }
    }
}

// ---------------- K2: per-rank proj via fp16 MFMA ----------------
__global__ __launch_bounds__(256) void k_rproj16(
    const unsigned short* __restrict__ RP16, const unsigned short* __restrict__ WN16,
    const float* __restrict__ bnv, const float* __restrict__ bnqa,
    unsigned short* __restrict__ vrT2, unsigned short* __restrict__ qrT2,
    unsigned short* __restrict__ arT2)
{
  const int r = blockIdx.x, mB = blockIdx.y, z = blockIdx.z;
  const int zq = (z == 0) ? 0 : 1;
  const float* bias = ((z == 0) ? bnv : bnqa) + r * 64;
  const int tid = threadIdx.x, lane = tid & 63;
  const int w = __builtin_amdgcn_readfirstlane(tid >> 6);
  const int wm = w >> 1, wn = w & 1;

  f32x4 c[2][2];
  #pragma unroll
  for (int mi = 0; mi < 2; ++mi)
    #pragma unroll
    for (int ni = 0; ni < 2; ++ni) c[mi][ni] = (f32x4){0.f, 0.f, 0.f, 0.f};

  #pragma unroll 4
  for (int ks = 0; ks < 16; ++ks) {
    f16x8 af[2], bf[2];
    #pragma unroll
    for (int mi = 0; mi < 2; ++mi)
      af[mi] = *(const f16x8*)&RP16[((size_t)(z * 64 + mB * 4 + wm * 2 + mi) * 16 + ks) * 512 + lane * 8];
    #pragma unroll
    for (int ni = 0; ni < 2; ++ni)
      bf[ni] = *(const f16x8*)&WN16[((size_t)((zq * 8 + r) * 4 + wn * 2 + ni) * 16 + ks) * 512 + lane * 8];
    #pragma unroll
    for (int mi = 0; mi < 2; ++mi)
      #pragma unroll
      for (int ni = 0; ni < 2; ++ni)
        c[mi][ni] = __builtin_amdgcn_mfma_f32_16x16x32_f16(af[mi], bf[ni], c[mi][ni], 0, 0, 0);
  }

  #pragma unroll
  for (int mi = 0; mi < 2; ++mi)
    #pragma unroll
    for (int ni = 0; ni < 2; ++ni) {
      const int n = (wn * 2 + ni) * 16 + (lane & 15);
      const float bb2 = bias[n];
      #pragma unroll
      for (int i = 0; i < 4; ++i) {
        const int mm = mB * 64 + (wm * 2 + mi) * 16 + 4 * (lane >> 4) + i;
        const int bb = mm >> 6, nr = mm & 63;
        float val = fmaxf(c[mi][ni][i] + bb2, 0.f);
        unsigned short hv = f2h(val);
        if (z == 0)
          vrT2[(size_t)(bb * 8 + r) * 4096 + ((nr >> 4) * 2 + (n >> 5)) * 512 + fragoff(nr, n & 31)] = hv;
        else if (z == 1)
          qrT2[(size_t)(bb * 8 + r) * 4096 + ((nr >> 4) * 2 + (n >> 5)) * 512 + fragoff(nr, n & 31)] = hv;
        else
          arT2[(size_t)(((bb * 8 + r) * 2 + (n >> 5)) * 4 + (nr >> 4)) * 512 + fragoff(nr, n & 31)] = hv;
      }
    }
}

// ---------------- K3a: stage1 (single launch, all g/rh) ----------------
// grid (b16, rq4, z16: z = ntB + 4*(rh*2+g))
__global__ __launch_bounds__(512) void k_stage1(
    const unsigned short* __restrict__ vrT2, const unsigned short* __restrict__ T2,
    unsigned short* __restrict__ U)
{
  const int b = blockIdx.x, rq = blockIdx.y, z = blockIdx.z;
  const int ntB = z & 3, g = (z >> 2) & 1, rh = z >> 3;
  const int r = rh * 4 + rq;
  const int tid = threadIdx.x, lane = tid & 63;
  const int w = __builtin_amdgcn_readfirstlane(tid >> 6);

  __shared__ __align__(16) unsigned short VR[4096];
  __shared__ __align__(16) unsigned short TC[16384];
  __shared__ __align__(16) unsigned short ST[16384];

  {
    const float4* s = (const float4*)(vrT2 + (size_t)(b * 8 + r) * 4096);
    *(float4*)&VR[tid * 8] = s[tid];
  }

  const size_t t2base = ((size_t)(g * 8 + r) * 256 + ntB * 64) * 1024;

  for (int sb = 0; sb < 4; ++sb) {
    {
      const float4* s = (const float4*)(T2 + t2base + (size_t)sb * 16384);
      float4* d = (float4*)TC;
      #pragma unroll
      for (int i = 0; i < 4; ++i) d[tid + i * 512] = s[tid + i * 512];
    }
    __syncthreads();

    f32x4 c[4][2];
    #pragma unroll
    for (int mt = 0; mt < 4; ++mt)
      #pragma unroll
      for (int nt = 0; nt < 2; ++nt)
        c[mt][nt] = (f32x4){0.f, 0.f, 0.f, 0.f};

    f16x8 af[4][2], bf[2][2];
    #pragma unroll
    for (int mt = 0; mt < 4; ++mt)
      #pragma unroll
      for (int ks = 0; ks < 2; ++ks)
        af[mt][ks] = *(const f16x8*)&VR[mt * 1024 + ks * 512 + lane * 8];
    #pragma unroll
    for (int nt = 0; nt < 2; ++nt)
      #pragma unroll
      for (int ks = 0; ks < 2; ++ks)
        bf[nt][ks] = *(const f16x8*)&TC[(w * 2 + nt) * 1024 + ks * 512 + lane * 8];

    #pragma unroll
    for (int mt = 0; mt < 4; ++mt)
      #pragma unroll
      for (int nt = 0; nt < 2; ++nt)
        #pragma unroll
        for (int ks = 0; ks < 2; ++ks)
          c[mt][nt] = __builtin_amdgcn_mfma_f32_16x16x32_f16(af[mt][ks], bf[nt][ks], c[mt][nt], 0, 0, 0);

    #pragma unroll
    for (int mt = 0; mt < 4; ++mt)
      #pragma unroll
      for (int nt = 0; nt < 2; ++nt) {
        const int Nt = ntB * 64 + sb * 16 + w * 2 + nt;
        const int n = Nt * 16 + (lane & 15);
        const int l = n >> 6, k = n & 63;
        #pragma unroll
        for (int i = 0; i < 4; ++i) {
          const int v = mt * 16 + 4 * (lane >> 4) + i;
          const int row16 = 8 * (l & 1) + (v & 7);
          const int el = ((v >> 3) * 2 + ((l >> 1) & 1)) * 1024 + (k >> 5) * 512 + fragoff(row16, k & 31);
          ST[el] = f2h(c[mt][nt][i]);
        }
      }
    __syncthreads();

    {
      const int l0 = ntB * 16 + sb * 4;
      const int lc = l0 >> 5;
      const int mtU0 = (l0 >> 1) & 15;
      const int rg = tid >> 5, idx = tid & 31;
      const int vt = rg >> 1, mtrel = rg & 1;
      unsigned short* dst = U + ((size_t)((((g * 16 + b) * 8 + vt) * 8 + r) * 2 + lc)) * 16384
                              + (size_t)(mtU0 + mtrel) * 1024;
      const float4* s = (const float4*)&ST[rg * 1024];
      float4* d = (float4*)dst;
      #pragma unroll
      for (int i = 0; i < 4; ++i) d[idx + i * 32] = s[idx + i * 32];
    }
    __syncthreads();
  }
}

// ---------------- K3b: stage2+3 (single launch, all r, both qh) ----------------
// grid (b16, vt8, g2), 512 thr. Each U element read ONCE; fout written once (no RMW).
__global__ __launch_bounds__(512) void k_stage23(
    const unsigned short* __restrict__ U, const unsigned short* __restrict__ qrT2,
    const unsigned short* __restrict__ arT2, float* __restrict__ fout)
{
  const int b = blockIdx.x, vt = blockIdx.y, g = blockIdx.z;
  const int tid = threadIdx.x, lane = tid & 63;
  const int w = __builtin_amdgcn_readfirstlane(tid >> 6);

  __shared__ __align__(16) unsigned short UA[16384];  // 32 KB
  __shared__ __align__(16) unsigned short QB[4096];   // 8 KB (all 64 q)
  __shared__ __align__(16) unsigned short AB[2048];   // 4 KB
  __shared__ __align__(16) unsigned short CC[8192];   // 16 KB? no: 8192 halves = 16 KB

  f32x4 f[2][2][4];
  #pragma unroll
  for (int qh = 0; qh < 2; ++qh)
    #pragma unroll
    for (int qt = 0; qt < 2; ++qt)
      #pragma unroll
      for (int nt = 0; nt < 4; ++nt)
        f[qh][qt][nt] = (f32x4){0.f, 0.f, 0.f, 0.f};

  for (int r = 0; r < 8; ++r) {
    const float4* sq = (const float4*)(qrT2 + (size_t)(b * 8 + r) * 4096);

    for (int lc = 0; lc < 2; ++lc) {
      // stage UA (32 KB, all threads)
      {
        const float4* su = (const float4*)(U + ((size_t)((((g * 16 + b) * 8 + vt) * 8 + r) * 2 + lc)) * 16384);
        float4* du = (float4*)UA;
        #pragma unroll
        for (int i = 0; i < 4; ++i) du[tid + i * 512] = su[tid + i * 512];
      }
      // stage AB (4 KB): tid<256
      {
        const float4* sa = (const float4*)(arT2 + ((size_t)((b * 8 + r) * 2 + lc)) * 2048);
        if (tid < 256) ((float4*)AB)[tid] = sa[tid];
      }
      // stage QB (8 KB, once per r): tid>=256 handle 512 float4
      if (lc == 0 && tid >= 256) {
        ((float4*)QB)[tid - 256] = sq[tid - 256];
        ((float4*)QB)[tid] = sq[tid];
      }
      __syncthreads();

      f16x8 b3[4];
      #pragma unroll
      for (int nt = 0; nt < 4; ++nt)
        b3[nt] = *(const f16x8*)&AB[nt * 512 + lane * 8];

      f16x8 a2[2][2];
      #pragma unroll
      for (int mi = 0; mi < 2; ++mi)
        #pragma unroll
        for (int ks = 0; ks < 2; ++ks)
          a2[mi][ks] = *(const f16x8*)&UA[(w * 2 + mi) * 1024 + ks * 512 + lane * 8];

      #pragma unroll
      for (int qh = 0; qh < 2; ++qh) {
        // ---- stage2 for this qh ----
        f32x4 c2[2][2];
        #pragma unroll
        for (int mi = 0; mi < 2; ++mi)
          #pragma unroll
          for (int nt = 0; nt < 2; ++nt)
            c2[mi][nt] = (f32x4){0.f, 0.f, 0.f, 0.f};

        f16x8 b2[2][2];
        #pragma unroll
        for (int nt = 0; nt < 2; ++nt)
          #pragma unroll
          for (int ks = 0; ks < 2; ++ks)
            b2[nt][ks] = *(const f16x8*)&QB[(qh * 2 + nt) * 1024 + ks * 512 + lane * 8];

        #pragma unroll
        for (int mi = 0; mi < 2; ++mi)
          #pragma unroll
          for (int nt = 0; nt < 2; ++nt)
            #pragma unroll
            for (int ks = 0; ks < 2; ++ks)
              c2[mi][nt] = __builtin_amdgcn_mfma_f32_16x16x32_f16(a2[mi][ks], b2[nt][ks], c2[mi][nt], 0, 0, 0);

        // scatter C into CC (stage3-frag order)
        #pragma unroll
        for (int mi = 0; mi < 2; ++mi)
          #pragma unroll
          for (int nt = 0; nt < 2; ++nt)
            #pragma unroll
            for (int i = 0; i < 4; ++i) {
              const int row = (w * 2 + mi) * 16 + 4 * (lane >> 4) + i;
              const int l = row >> 3, v = row & 7;
              const int el = (v * 2 + nt) * 512 + fragoff(lane & 15, l);
              CC[el] = f2h(c2[mi][nt][i]);
            }
        __syncthreads();

        // ---- stage3 for this qh ----
        f16x8 a3[2];
        #pragma unroll
        for (int qt = 0; qt < 2; ++qt)
          a3[qt] = *(const f16x8*)&CC[(w * 2 + qt) * 512 + lane * 8];

        #pragma unroll
        for (int qt = 0; qt < 2; ++qt)
          #pragma unroll
          for (int nt = 0; nt < 4; ++nt)
            f[qh][qt][nt] = __builtin_amdgcn_mfma_f32_16x16x32_f16(a3[qt], b3[nt], f[qh][qt][nt], 0, 0, 0);
        __syncthreads();  // protect CC (qh=0->1) and UA/AB/QB (last -> next staging)
      }
    }
  }

  // epilogue: single write, no accumulate
  #pragma unroll
  for (int qh = 0; qh < 2; ++qh)
    #pragma unroll
    for (int qt = 0; qt < 2; ++qt)
      #pragma unroll
      for (int nt = 0; nt < 4; ++nt)
        #pragma unroll
        for (int i = 0; i < 4; ++i) {
          const int q = qh * 32 + qt * 16 + 4 * (lane >> 4) + i;
          const int m = nt * 16 + (lane & 15);
          size_t addr = ((((size_t)b * 64 + vt * 8 + w) * 64 + q) * 64 + m) * 2 + g;
          fout[addr] = f[qh][qt][nt][i];
        }
}

// ---------------- K4: logits via MFMA per (b,v) ----------------
__global__ __launch_bounds__(512) void k_logits2(
    const float* __restrict__ vt, const float* __restrict__ qt,
    const unsigned short* __restrict__ AT16, const float* __restrict__ fout,
    float* __restrict__ Lp)
{
  const int v = blockIdx.x, b = blockIdx.y;
  const int tid = threadIdx.x, lane = tid & 63;
  const int w = __builtin_amdgcn_readfirstlane(tid >> 6);

  __shared__ __align__(16) unsigned int FAu[2048];

  {
    const float4* fo4 = (const float4*)(fout + ((size_t)(b * 64 + v)) * 8192);
    #pragma unroll
    for (int i = 0; i < 4; ++i) {
      int fi = tid + i * 512;
      int q = fi >> 5, mpair = fi & 31;
      float4 x = fo4[fi];
      float s0 = x.x + x.y, s1 = x.z + x.w;
      int m0 = mpair * 2;
      int off = fragoff(q & 15, m0 & 31);
      int idx2 = (((q >> 4) * 2 + (m0 >> 5)) * 512 + off) >> 1;
      unsigned int pk = (unsigned int)f2h(s0) | ((unsigned int)f2h(s1) << 16);
      FAu[idx2] = pk;
    }
  }
  __syncthreads();

  const unsigned short* FAh = (const unsigned short*)FAu;

  f16x8 af[4][2], bf[4][2];
  #pragma unroll
  for (int mt = 0; mt < 4; ++mt)
    #pragma unroll
    for (int ks = 0; ks < 2; ++ks)
      af[mt][ks] = *(const f16x8*)&FAh[(mt * 2 + ks) * 512 + lane * 8];
  #pragma unroll
  for (int nt = 0; nt < 4; ++nt)
    #pragma unroll
    for (int ks = 0; ks < 2; ++ks)
      bf[nt][ks] = *(const f16x8*)&AT16[(size_t)((b * 32 + w * 4 + nt) * 2 + ks) * 512 + lane * 8];

  f32x4 c[4][4];
  #pragma unroll
  for (int mt = 0; mt < 4; ++mt)
    #pragma unroll
    for (int nt = 0; nt < 4; ++nt)
      c[mt][nt] = (f32x4){0.f, 0.f, 0.f, 0.f};

  #pragma unroll
  for (int mt = 0; mt < 4; ++mt)
    #pragma unroll
    for (int nt = 0; nt < 4; ++nt)
      #pragma unroll
      for (int ks = 0; ks < 2; ++ks)
        c[mt][nt] = __builtin_amdgcn_mfma_f32_16x16x32_f16(af[mt][ks], bf[nt][ks], c[mt][nt], 0, 0, 0);

  const int gr = lane >> 4, dl = lane & 15;
  #pragma unroll
  for (int nt = 0; nt < 4; ++nt) {
    const int d = w * 64 + nt * 16 + dl;
    float partial = 0.f;
    #pragma unroll
    for (int mt = 0; mt < 4; ++mt) {
      #pragma unroll
      for (int i = 0; i < 4; ++i) {
        const int q = mt * 16 + gr * 4 + i;
        partial += qt[(b * 64 + q) * 512 + d] * c[mt][nt][i];
      }
    }
    partial += __shfl_xor(partial, 16);
    partial += __shfl_xor(partial, 32);
    const float val = vt[(b * 64 + v) * 512 + d] * partial;
    if (lane < 16) Lp[((size_t)(b * 64 + v)) * 512 + d] = val;
  }
}

// ---------------- K5: reduce logits over v ----------------
__global__ __launch_bounds__(512) void k_lred(const float* __restrict__ Lp, float* __restrict__ Lraw)
{
  const int b = blockIdx.x, d = threadIdx.x;
  float s = 0.f;
  for (int v = 0; v < 64; ++v) s += Lp[(size_t)(b * 64 + v) * 512 + d];
  Lraw[b * 512 + d] = s;
}

// ---------------- K6: batchnorm over batch dim ----------------
__global__ __launch_bounds__(512) void k_bn(
    const float* __restrict__ Lraw, const float* __restrict__ gamma,
    const float* __restrict__ beta, float* __restrict__ lout)
{
  const int d = threadIdx.x;
  float x[16]; float mu = 0.f;
  #pragma unroll
  for (int b = 0; b < 16; ++b) { x[b] = Lraw[b * 512 + d]; mu += x[b]; }
  mu *= (1.f / 16.f);
  float var = 0.f;
  #pragma unroll
  for (int b = 0; b < 16; ++b) { float t = x[b] - mu; var += t * t; }
  var *= (1.f / 16.f);
  const float sc = gamma[d] / sqrtf(var + 1e-5f);
  const float bt = beta[d];
  #pragma unroll
  for (int b = 0; b < 16; ++b) lout[b * 512 + d] = (x[b] - mu) * sc + bt;
}

extern "C" void kernel_launch(void* const* d_in, const int* in_sizes, int n_in,
                              void* d_out, int out_size, void* d_ws, size_t ws_size,
                              hipStream_t stream)
{
  const float* v    = (const float*)d_in[0];
  const float* q    = (const float*)d_in[1];
  const float* a    = (const float*)d_in[2];
  const float* Vv   = (const float*)d_in[3];
  const float* gv   = (const float*)d_in[4];
  const float* bv   = (const float*)d_in[5];
  const float* Vq   = (const float*)d_in[6];
  const float* gq   = (const float*)d_in[7];
  const float* bq   = (const float*)d_in[8];
  const float* Va   = (const float*)d_in[9];
  const float* ga   = (const float*)d_in[10];
  const float* ba   = (const float*)d_in[11];
  const float* Vnv  = (const float*)d_in[12];
  const float* gnv  = (const float*)d_in[13];
  const float* bnv  = (const float*)d_in[14];
  const float* Vnqa = (const float*)d_in[15];
  const float* gnqa = (const float*)d_in[16];
  const float* bnqa = (const float*)d_in[17];
  const float* Tg   = (const float*)d_in[18];
  const float* gamma= (const float*)d_in[19];
  const float* beta = (const float*)d_in[20];

  float* ws   = (float*)d_ws;
  unsigned short* hb = (unsigned short*)(ws + WS_H);
  float* fout = (float*)d_out;
  float* lout = fout + (size_t)16 * 64 * 64 * 64 * 2;

  k_norms_part<<<320, 256, 0, stream>>>(Vv, Vq, Va, Vnv, Vnqa, ws + WS_PRT);
  k_norms_fin<<<19, 64, 0, stream>>>(ws + WS_PRT, ws + WS_NRM);
  k_inconv16<<<dim3(64, 3), 256, 0, stream>>>(v, q, a, hb + H_IN16);
  k_wconv16<<<dim3(32, 3), 256, 0, stream>>>(Vv, Vq, Va, gv, gq, ga, ws + WS_NRM, hb + H_WB16);
  k_wnconv16<<<64, 256, 0, stream>>>(Vnv, Vnqa, gnv, gnqa, ws + WS_NRM, hb + H_WN16);
  k_repack2b<<<128, 256, 0, stream>>>(Tg, hb + H_T2);
  k_proj16<<<dim3(8, 16, 3), 256, 0, stream>>>(hb + H_IN16, hb + H_WB16, bv, bq, ba,
                                               ws + WS_VT, ws + WS_QT, ws + WS_AT,
                                               hb + H_RP16, hb + H_AT16);
  k_rproj16<<<dim3(8, 16, 3), 256, 0, stream>>>(hb + H_RP16, hb + H_WN16, bnv, bnqa,
                                                hb + H_VR2, hb + H_QR2, hb + H_AR2);
  k_stage1<<<dim3(16, 4, 16), 512, 0, stream>>>(hb + H_VR2, hb + H_T2, hb + H_U);
  k_stage23<<<dim3(16, 8, 2), 512, 0, stream>>>(hb + H_U, hb + H_QR2, hb + H_AR2, fout);
  k_logits2<<<dim3(64, 16), 512, 0, stream>>>(ws + WS_VT, ws + WS_QT,
                                              hb + H_AT16, fout, ws + WS_LP);
  k_lred<<<16, 512, 0, stream>>>(ws + WS_LP, ws + WS_LR);
  k_bn<<<1, 512, 0, stream>>>(ws + WS_LR, gamma, beta, lout);
}

// Round 8
// 156.722 us; speedup vs baseline: 8.0762x; 1.0305x over previous
//
#include <hip/hip_runtime.h>
#include <hip/hip_fp16.h>
#include <math.h>

// Problem dims: B=16, N=64, D=512, H=512, R=8, HK=64, G=2
// Outputs: f_emb [16,64,64,64,2] (8388608 f32) then logits [16,512] (8192 f32)

typedef _Float16 f16x8 __attribute__((ext_vector_type(8)));
typedef float f32x4 __attribute__((ext_vector_type(4)));

__device__ __forceinline__ unsigned short f2h(float x) {
  _Float16 h = (_Float16)x;
  return __builtin_bit_cast(unsigned short, h);
}

// fragment scatter map for 16x16x32 (row16, kr in 0..31):
//   lane = (row&15) + (((kr>>2)&3)<<4) ; j = (kr&3) + (((kr>>4)&1)<<2)
// element offset within a 512-el frag-tile = lane*8 + j
__device__ __forceinline__ int fragoff(int row, int kr) {
  return (((row & 15) + (((kr >> 2) & 3) << 4)) << 3) + (kr & 3) + (((kr >> 4) & 1) << 2);
}

// ---------------- workspace layout ----------------
// float region:
#define WS_NRM 0                      // 32 floats
#define WS_VT  32                     // v_t [1024][512] f32
#define WS_QT  (WS_VT + 524288)
#define WS_AT  (WS_QT + 524288)
#define WS_LP  (WS_AT + 524288)       // logits per-v partial [b][v][d]
#define WS_LR  (WS_LP + 524288)       // raw logits [b][d]
#define WS_PRT (WS_LR + 8192)         // norm partials 19*64 (pad 1280)
#define WS_H   (WS_PRT + 1280)        // half region starts here (16B aligned)
// half (ushort) offsets from hbase:
#define H_VRL 0                        // v_r LINEAR [b][r][v][h] (524288)
#define H_QR2 524288                   // q_r frags
#define H_AR2 1048576                  // a_r frags
#define H_T2  1572864                  // T frags [g][r][Nt256][ks2][512]  (4194304)
#define H_AT16 5767168                 // at fp16 B-frags for logits (524288)
#define H_IN16 6291456                 // raw inputs A-frags (1572864)
#define H_WB16 7864320                 // proj weights B-frags (786432)
#define H_WN16 8650752                 // rank weights B-frags (524288)
#define H_RP16 9175040                 // proj outputs A-frags (1572864) -> end 10747904

// ---------------- K0a: norm partials ----------------
__global__ __launch_bounds__(256) void k_norms_part(
    const float* __restrict__ Vv, const float* __restrict__ Vq, const float* __restrict__ Va,
    const float* __restrict__ Vnv, const float* __restrict__ Vnqa, float* __restrict__ prt)
{
  const int bx = blockIdx.x;
  int n, j;
  const float* base;
  if (bx < 192) {
    n = bx >> 6; j = bx & 63;
    base = (n == 0 ? Vv : n == 1 ? Vq : Va) + j * 4096;
  } else {
    int t = bx - 192;
    n = 3 + (t >> 3); j = t & 7;
    base = (n < 11 ? Vnv + (n - 3) * 32768 : Vnqa + (n - 11) * 32768) + j * 4096;
  }
  const float4* p4 = (const float4*)base;
  float s = 0.f;
  #pragma unroll
  for (int i = 0; i < 4; ++i) {
    float4 x = p4[threadIdx.x + i * 256];
    s += x.x * x.x + x.y * x.y + x.z * x.z + x.w * x.w;
  }
  __shared__ float red[256];
  red[threadIdx.x] = s; __syncthreads();
  for (int off = 128; off > 0; off >>= 1) {
    if (threadIdx.x < off) red[threadIdx.x] += red[threadIdx.x + off];
    __syncthreads();
  }
  if (threadIdx.x == 0) prt[n * 64 + j] = red[0];
}

// ---------------- K0b: finalize norms ----------------
__global__ __launch_bounds__(64) void k_norms_fin(const float* __restrict__ prt, float* __restrict__ wsn)
{
  const int n = blockIdx.x, t = threadIdx.x;
  const int cnt = (n < 3) ? 64 : 8;
  float s = (t < cnt) ? prt[n * 64 + t] : 0.f;
  #pragma unroll
  for (int off = 32; off > 0; off >>= 1) s += __shfl_down(s, off);
  if (t == 0) wsn[n] = sqrtf(s);
}

// ---------------- KC1: raw inputs v/q/a -> fp16 A-frags ----------------
__global__ __launch_bounds__(256) void k_inconv16(
    const float* __restrict__ v, const float* __restrict__ q, const float* __restrict__ a,
    unsigned short* __restrict__ IN16)
{
  const int z = blockIdx.y;
  const float4* src = (const float4*)((z == 0) ? v : (z == 1) ? q : a);
  #pragma unroll
  for (int i = 0; i < 8; ++i) {
    int f = blockIdx.x * 2048 + threadIdx.x + i * 256;
    int row = f >> 7, d0 = (f & 127) * 4;
    float4 x = src[f];
    ushort4 pk;
    pk.x = f2h(x.x); pk.y = f2h(x.y); pk.z = f2h(x.z); pk.w = f2h(x.w);
    int lanep = (row & 15) + (((d0 >> 2) & 3) << 4);
    int jb = ((d0 >> 4) & 1) << 2;
    size_t off = ((size_t)(z * 64 + (row >> 4)) * 16 + (d0 >> 5)) * 512 + lanep * 8 + jb;
    *(ushort4*)&IN16[off] = pk;
  }
}

// ---------------- KC2: proj weights scaled -> fp16 B-frags ----------------
__global__ __launch_bounds__(256) void k_wconv16(
    const float* __restrict__ Wv, const float* __restrict__ Wq, const float* __restrict__ Wa,
    const float* __restrict__ gv, const float* __restrict__ gq, const float* __restrict__ ga,
    const float* __restrict__ wsn, unsigned short* __restrict__ WB16)
{
  const int z = blockIdx.y;
  const float4* src = (const float4*)((z == 0) ? Wv : (z == 1) ? Wq : Wa);
  const float scale = ((z == 0) ? gv[0] : (z == 1) ? gq[0] : ga[0]) / wsn[z];
  #pragma unroll
  for (int i = 0; i < 8; ++i) {
    int f = blockIdx.x * 2048 + threadIdx.x + i * 256;
    int n = f >> 7, d0 = (f & 127) * 4;
    float4 x = src[f];
    ushort4 pk;
    pk.x = f2h(x.x * scale); pk.y = f2h(x.y * scale);
    pk.z = f2h(x.z * scale); pk.w = f2h(x.w * scale);
    int lanep = (n & 15) + (((d0 >> 2) & 3) << 4);
    int jb = ((d0 >> 4) & 1) << 2;
    size_t off = ((size_t)(z * 32 + (n >> 4)) * 16 + (d0 >> 5)) * 512 + lanep * 8 + jb;
    *(ushort4*)&WB16[off] = pk;
  }
}

// ---------------- KC3: rank weights scaled -> fp16 B-frags ----------------
__global__ __launch_bounds__(256) void k_wnconv16(
    const float* __restrict__ Vnv, const float* __restrict__ Vnqa,
    const float* __restrict__ gnv, const float* __restrict__ gnqa,
    const float* __restrict__ wsn, unsigned short* __restrict__ WN16)
{
  const int zr = blockIdx.x >> 2, sub = blockIdx.x & 3;
  const int zq = zr >> 3, r = zr & 7;
  const float4* src = (const float4*)((zq == 0 ? Vnv : Vnqa) + (size_t)r * 32768);
  const float scale = (zq == 0) ? (gnv[r] / wsn[3 + r]) : (gnqa[r] / wsn[11 + r]);
  #pragma unroll
  for (int i = 0; i < 8; ++i) {
    int f = sub * 2048 + threadIdx.x + i * 256;
    int n = f >> 7, d0 = (f & 127) * 4;
    float4 x = src[f];
    ushort4 pk;
    pk.x = f2h(x.x * scale); pk.y = f2h(x.y * scale);
    pk.z = f2h(x.z * scale); pk.w = f2h(x.w * scale);
    int lanep = (n & 15) + (((d0 >> 2) & 3) << 4);
    int jb = ((d0 >> 4) & 1) << 2;
    size_t off = ((size_t)(zr * 4 + (n >> 4)) * 16 + (d0 >> 5)) * 512 + lanep * 8 + jb;
    *(ushort4*)&WN16[off] = pk;
  }
}

// ---------------- KT: repack T via LDS bounce ----------------
__global__ __launch_bounds__(256) void k_repack2b(const float* __restrict__ Tg, unsigned short* __restrict__ T2)
{
  const int r = blockIdx.x >> 4, lB = blockIdx.x & 15;
  __shared__ unsigned short lds[32768];
  const int tid = threadIdx.x;

  #pragma unroll
  for (int i = 0; i < 32; ++i) {
    int f = tid + i * 256;
    int lpair = f & 1, k = (f >> 1) & 63, h = f >> 7;
    int l0 = lB * 4 + lpair * 2;
    const float4 x = *(const float4*)(Tg + ((size_t)((r * 64 + h) * 64 + k) * 64 + l0) * 2);
    const int el = fragoff(k & 15, h & 31);
    const int ks = h >> 5;
    const int ntr0 = (l0 & 3) * 4 + (k >> 4);
    const int ntr1 = ((l0 + 1) & 3) * 4 + (k >> 4);
    lds[((0 * 16 + ntr0) * 2 + ks) * 512 + el] = f2h(x.x);
    lds[((1 * 16 + ntr0) * 2 + ks) * 512 + el] = f2h(x.y);
    lds[((0 * 16 + ntr1) * 2 + ks) * 512 + el] = f2h(x.z);
    lds[((1 * 16 + ntr1) * 2 + ks) * 512 + el] = f2h(x.w);
  }
  __syncthreads();

  #pragma unroll
  for (int g = 0; g < 2; ++g) {
    unsigned short* dst = T2 + ((size_t)(g * 8 + r) * 256 + lB * 16) * 1024;
    const float4* s = (const float4*)&lds[g * 16384];
    float4* d = (float4*)dst;
    #pragma unroll
    for (int i = 0; i < 8; ++i) d[tid + i * 256] = s[tid + i * 256];
  }
}

// ---------------- K1: proj via fp16 MFMA (also emits AT16 when z==2) ----------------
__global__ __launch_bounds__(256) void k_proj16(
    const unsigned short* __restrict__ IN16, const unsigned short* __restrict__ WB16,
    const float* __restrict__ bv, const float* __restrict__ bq, const float* __restrict__ ba,
    float* __restrict__ ov, float* __restrict__ oq, float* __restrict__ oa,
    unsigned short* __restrict__ RP16, unsigned short* __restrict__ AT16)
{
  const int nB = blockIdx.x, mB = blockIdx.y, z = blockIdx.z;
  const float* bias = (z == 0) ? bv : (z == 1) ? bq : ba;
  float* out = (z == 0) ? ov : (z == 1) ? oq : oa;
  const int tid = threadIdx.x, lane = tid & 63;
  const int w = __builtin_amdgcn_readfirstlane(tid >> 6);

  f32x4 c[4];
  #pragma unroll
  for (int mt = 0; mt < 4; ++mt) c[mt] = (f32x4){0.f, 0.f, 0.f, 0.f};

  #pragma unroll 4
  for (int ks = 0; ks < 16; ++ks) {
    f16x8 af[4], bfr;
    #pragma unroll
    for (int mt = 0; mt < 4; ++mt)
      af[mt] = *(const f16x8*)&IN16[((size_t)(z * 64 + mB * 4 + mt) * 16 + ks) * 512 + lane * 8];
    bfr = *(const f16x8*)&WB16[((size_t)(z * 32 + nB * 4 + w) * 16 + ks) * 512 + lane * 8];
    #pragma unroll
    for (int mt = 0; mt < 4; ++mt)
      c[mt] = __builtin_amdgcn_mfma_f32_16x16x32_f16(af[mt], bfr, c[mt], 0, 0, 0);
  }

  const int col = nB * 64 + w * 16 + (lane & 15);
  const float bb = bias[col];
  #pragma unroll
  for (int mt = 0; mt < 4; ++mt)
    #pragma unroll
    for (int i = 0; i < 4; ++i) {
      const int row = mB * 64 + mt * 16 + 4 * (lane >> 4) + i;
      float val = fmaxf(c[mt][i] + bb, 0.f);
      unsigned short hv = f2h(val);
      out[(size_t)row * 512 + col] = val;
      RP16[((size_t)(z * 64 + (row >> 4)) * 16 + (col >> 5)) * 512 + fragoff(row, col & 31)] = hv;
      if (z == 2) {
        const int m = row & 63;
        AT16[(size_t)(row >> 6) * 32768 + ((col >> 4) * 2 + (m >> 5)) * 512 + fragoff(col & 15, m & 31)] = hv;
      }
    }
}

// ---------------- K2: per-rank proj via fp16 MFMA ----------------
// z==0 writes LINEAR v_r (for fused tucker's stage1 A-frag build); z==1/2 write frags.
__global__ __launch_bounds__(256) void k_rproj16(
    const unsigned short* __restrict__ RP16, const unsigned short* __restrict__ WN16,
    const float* __restrict__ bnv, const float* __restrict__ bnqa,
    unsigned short* __restrict__ vrLin, unsigned short* __restrict__ qrT2,
    unsigned short* __restrict__ arT2)
{
  const int r = blockIdx.x, mB = blockIdx.y, z = blockIdx.z;
  const int zq = (z == 0) ? 0 : 1;
  const float* bias = ((z == 0) ? bnv : bnqa) + r * 64;
  const int tid = threadIdx.x, lane = tid & 63;
  const int w = __builtin_amdgcn_readfirstlane(tid >> 6);
  const int wm = w >> 1, wn = w & 1;

  f32x4 c[2][2];
  #pragma unroll
  for (int mi = 0; mi < 2; ++mi)
    #pragma unroll
    for (int ni = 0; ni < 2; ++ni) c[mi][ni] = (f32x4){0.f, 0.f, 0.f, 0.f};

  #pragma unroll 4
  for (int ks = 0; ks < 16; ++ks) {
    f16x8 af[2], bf[2];
    #pragma unroll
    for (int mi = 0; mi < 2; ++mi)
      af[mi] = *(const f16x8*)&RP16[((size_t)(z * 64 + mB * 4 + wm * 2 + mi) * 16 + ks) * 512 + lane * 8];
    #pragma unroll
    for (int ni = 0; ni < 2; ++ni)
      bf[ni] = *(const f16x8*)&WN16[((size_t)((zq * 8 + r) * 4 + wn * 2 + ni) * 16 + ks) * 512 + lane * 8];
    #pragma unroll
    for (int mi = 0; mi < 2; ++mi)
      #pragma unroll
      for (int ni = 0; ni < 2; ++ni)
        c[mi][ni] = __builtin_amdgcn_mfma_f32_16x16x32_f16(af[mi], bf[ni], c[mi][ni], 0, 0, 0);
  }

  #pragma unroll
  for (int mi = 0; mi < 2; ++mi)
    #pragma unroll
    for (int ni = 0; ni < 2; ++ni) {
      const int n = (wn * 2 + ni) * 16 + (lane & 15);
      const float bb2 = bias[n];
      #pragma unroll
      for (int i = 0; i < 4; ++i) {
        const int mm = mB * 64 + (wm * 2 + mi) * 16 + 4 * (lane >> 4) + i;
        const int bb = mm >> 6, nr = mm & 63;
        float val = fmaxf(c[mi][ni][i] + bb2, 0.f);
        unsigned short hv = f2h(val);
        if (z == 0)
          vrLin[((size_t)(bb * 8 + r) * 64 + nr) * 64 + n] = hv;
        else if (z == 1)
          qrT2[(size_t)(bb * 8 + r) * 4096 + ((nr >> 4) * 2 + (n >> 5)) * 512 + fragoff(nr, n & 31)] = hv;
        else
          arT2[(size_t)(((bb * 8 + r) * 2 + (n >> 5)) * 4 + (nr >> 4)) * 512 + fragoff(nr, n & 31)] = hv;
      }
    }
}

// ---------------- K3: FUSED Tucker (stage1+2+3), no U materialization ----------------
// grid (b16, vt8, g2) = 256 blocks, 512 thr. T2 B-frags read direct from global (L2-resident).
__global__ __launch_bounds__(512) void k_tucker16(
    const unsigned short* __restrict__ vrLin, const unsigned short* __restrict__ qrT2,
    const unsigned short* __restrict__ arT2, const unsigned short* __restrict__ T2,
    float* __restrict__ fout)
{
  const int b = blockIdx.x, vt = blockIdx.y, g = blockIdx.z;
  const int tid = threadIdx.x, lane = tid & 63;
  const int w = __builtin_amdgcn_readfirstlane(tid >> 6);

  __shared__ __align__(16) unsigned short UA[16384];  // 32 KB stage2 A-frags
  __shared__ __align__(16) unsigned short QB[4096];   // 8 KB q_r frags (all 64 q)
  __shared__ __align__(16) unsigned short AB[2048];   // 4 KB a_r frags per (r,lc)
  __shared__ __align__(16) unsigned short CC[8192];   // 16 KB stage3 A-frags
  __shared__ __align__(16) unsigned short VRL[512];   // 1 KB v_r rows [8v][64h]

  f32x4 f[2][2][4];
  #pragma unroll
  for (int qh = 0; qh < 2; ++qh)
    #pragma unroll
    for (int qt = 0; qt < 2; ++qt)
      #pragma unroll
      for (int nt = 0; nt < 4; ++nt)
        f[qh][qt][nt] = (f32x4){0.f, 0.f, 0.f, 0.f};

  for (int r = 0; r < 8; ++r) {
    // stage VRL (this block's 8 v_r rows) + QB (q_r frags)
    if (tid < 64)
      *(float4*)&VRL[tid * 8] =
          ((const float4*)(vrLin + (size_t)(b * 8 + r) * 4096 + vt * 512))[tid];
    *(float4*)&QB[tid * 8] = ((const float4*)(qrT2 + (size_t)(b * 8 + r) * 4096))[tid];
    __syncthreads();

    // build stage1 A-frag (16 rows = v 0..7 duplicated; rows 8..15 produce dup outputs, skipped)
    f16x8 af1[2];
    #pragma unroll
    for (int ks = 0; ks < 2; ++ks)
      #pragma unroll
      for (int j = 0; j < 8; ++j) {
        const int kr = (j & 3) + ((lane >> 4) & 3) * 4 + (j >> 2) * 16;
        af1[ks][j] = __builtin_bit_cast(_Float16, VRL[(lane & 7) * 64 + ks * 32 + kr]);
      }

    for (int lc = 0; lc < 2; ++lc) {
      // stage AB for this (r,lc)
      if (tid < 256)
        ((float4*)AB)[tid] = ((const float4*)(arT2 + ((size_t)((b * 8 + r) * 2 + lc)) * 2048))[tid];

      // ---- stage1: UA[(l32,v8) rows][k64] = sum_h v_r * T ; wave w owns 16 N-tiles ----
      const unsigned short* tb = T2 + ((size_t)((g * 8 + r) * 256 + lc * 128 + w * 16)) * 1024;
      for (int tg = 0; tg < 4; ++tg) {
        f16x8 bf[4][2];
        f32x4 d[4];
        #pragma unroll
        for (int tt = 0; tt < 4; ++tt) {
          #pragma unroll
          for (int ks = 0; ks < 2; ++ks)
            bf[tt][ks] = *(const f16x8*)&tb[(size_t)(tg * 4 + tt) * 1024 + ks * 512 + lane * 8];
          d[tt] = (f32x4){0.f, 0.f, 0.f, 0.f};
        }
        #pragma unroll
        for (int tt = 0; tt < 4; ++tt)
          #pragma unroll
          for (int ks = 0; ks < 2; ++ks)
            d[tt] = __builtin_amdgcn_mfma_f32_16x16x32_f16(af1[ks], bf[tt][ks], d[tt], 0, 0, 0);
        if (lane < 32) {
          #pragma unroll
          for (int tt = 0; tt < 4; ++tt) {
            const int t = w * 16 + tg * 4 + tt;
            const int lrel = t >> 2;
            const int k0 = (t & 3) * 16 + (lane & 15);
            #pragma unroll
            for (int i = 0; i < 4; ++i) {
              const int v = 4 * (lane >> 4) + i;   // 0..7 (lane<32)
              const int row = lrel * 8 + v;
              UA[(row >> 4) * 1024 + (k0 >> 5) * 512 + fragoff(row & 15, k0 & 31)] = f2h(d[tt][i]);
            }
          }
        }
      }
      __syncthreads();  // UA + AB ready

      // ---- stage2+3 (same as proven k_stage23) ----
      f16x8 b3[4], a2[2][2];
      #pragma unroll
      for (int nt = 0; nt < 4; ++nt)
        b3[nt] = *(const f16x8*)&AB[nt * 512 + lane * 8];
      #pragma unroll
      for (int mi = 0; mi < 2; ++mi)
        #pragma unroll
        for (int ks = 0; ks < 2; ++ks)
          a2[mi][ks] = *(const f16x8*)&UA[(w * 2 + mi) * 1024 + ks * 512 + lane * 8];

      #pragma unroll
      for (int qh = 0; qh < 2; ++qh) {
        f32x4 c2[2][2];
        #pragma unroll
        for (int mi = 0; mi < 2; ++mi)
          #pragma unroll
          for (int nt = 0; nt < 2; ++nt)
            c2[mi][nt] = (f32x4){0.f, 0.f, 0.f, 0.f};

        f16x8 b2[2][2];
        #pragma unroll
        for (int nt = 0; nt < 2; ++nt)
          #pragma unroll
          for (int ks = 0; ks < 2; ++ks)
            b2[nt][ks] = *(const f16x8*)&QB[(qh * 2 + nt) * 1024 + ks * 512 + lane * 8];

        #pragma unroll
        for (int mi = 0; mi < 2; ++mi)
          #pragma unroll
          for (int nt = 0; nt < 2; ++nt)
            #pragma unroll
            for (int ks = 0; ks < 2; ++ks)
              c2[mi][nt] = __builtin_amdgcn_mfma_f32_16x16x32_f16(a2[mi][ks], b2[nt][ks], c2[mi][nt], 0, 0, 0);

        #pragma unroll
        for (int mi = 0; mi < 2; ++mi)
          #pragma unroll
          for (int nt = 0; nt < 2; ++nt)
            #pragma unroll
            for (int i = 0; i < 4; ++i) {
              const int row = (w * 2 + mi) * 16 + 4 * (lane >> 4) + i;
              const int l = row >> 3, v = row & 7;
              const int el = (v * 2 + nt) * 512 + fragoff(lane & 15, l);
              CC[el] = f2h(c2[mi][nt][i]);
            }
        __syncthreads();  // CC ready

        f16x8 a3[2];
        #pragma unroll
        for (int qt = 0; qt < 2; ++qt)
          a3[qt] = *(const f16x8*)&CC[(w * 2 + qt) * 512 + lane * 8];

        #pragma unroll
        for (int qt = 0; qt < 2; ++qt)
          #pragma unroll
          for (int nt = 0; nt < 4; ++nt)
            f[qh][qt][nt] = __builtin_amdgcn_mfma_f32_16x16x32_f16(a3[qt], b3[nt], f[qh][qt][nt], 0, 0, 0);
        __syncthreads();  // CC/UA/QB/AB free for next phase
      }
    }
  }

  // epilogue: single write, no accumulate
  #pragma unroll
  for (int qh = 0; qh < 2; ++qh)
    #pragma unroll
    for (int qt = 0; qt < 2; ++qt)
      #pragma unroll
      for (int nt = 0; nt < 4; ++nt)
        #pragma unroll
        for (int i = 0; i < 4; ++i) {
          const int q = qh * 32 + qt * 16 + 4 * (lane >> 4) + i;
          const int m = nt * 16 + (lane & 15);
          size_t addr = ((((size_t)b * 64 + vt * 8 + w) * 64 + q) * 64 + m) * 2 + g;
          fout[addr] = f[qh][qt][nt][i];
        }
}

// ---------------- K4: logits via MFMA per (b,v) ----------------
__global__ __launch_bounds__(512) void k_logits2(
    const float* __restrict__ vt, const float* __restrict__ qt,
    const unsigned short* __restrict__ AT16, const float* __restrict__ fout,
    float* __restrict__ Lp)
{
  const int v = blockIdx.x, b = blockIdx.y;
  const int tid = threadIdx.x, lane = tid & 63;
  const int w = __builtin_amdgcn_readfirstlane(tid >> 6);

  __shared__ __align__(16) unsigned int FAu[2048];

  {
    const float4* fo4 = (const float4*)(fout + ((size_t)(b * 64 + v)) * 8192);
    #pragma unroll
    for (int i = 0; i < 4; ++i) {
      int fi = tid + i * 512;
      int q = fi >> 5, mpair = fi & 31;
      float4 x = fo4[fi];
      float s0 = x.x + x.y, s1 = x.z + x.w;
      int m0 = mpair * 2;
      int off = fragoff(q & 15, m0 & 31);
      int idx2 = (((q >> 4) * 2 + (m0 >> 5)) * 512 + off) >> 1;
      unsigned int pk = (unsigned int)f2h(s0) | ((unsigned int)f2h(s1) << 16);
      FAu[idx2] = pk;
    }
  }
  __syncthreads();

  const unsigned short* FAh = (const unsigned short*)FAu;

  f16x8 af[4][2], bf[4][2];
  #pragma unroll
  for (int mt = 0; mt < 4; ++mt)
    #pragma unroll
    for (int ks = 0; ks < 2; ++ks)
      af[mt][ks] = *(const f16x8*)&FAh[(mt * 2 + ks) * 512 + lane * 8];
  #pragma unroll
  for (int nt = 0; nt < 4; ++nt)
    #pragma unroll
    for (int ks = 0; ks < 2; ++ks)
      bf[nt][ks] = *(const f16x8*)&AT16[(size_t)((b * 32 + w * 4 + nt) * 2 + ks) * 512 + lane * 8];

  f32x4 c[4][4];
  #pragma unroll
  for (int mt = 0; mt < 4; ++mt)
    #pragma unroll
    for (int nt = 0; nt < 4; ++nt)
      c[mt][nt] = (f32x4){0.f, 0.f, 0.f, 0.f};

  #pragma unroll
  for (int mt = 0; mt < 4; ++mt)
    #pragma unroll
    for (int nt = 0; nt < 4; ++nt)
      #pragma unroll
      for (int ks = 0; ks < 2; ++ks)
        c[mt][nt] = __builtin_amdgcn_mfma_f32_16x16x32_f16(af[mt][ks], bf[nt][ks], c[mt][nt], 0, 0, 0);

  const int gr = lane >> 4, dl = lane & 15;
  #pragma unroll
  for (int nt = 0; nt < 4; ++nt) {
    const int d = w * 64 + nt * 16 + dl;
    float partial = 0.f;
    #pragma unroll
    for (int mt = 0; mt < 4; ++mt) {
      #pragma unroll
      for (int i = 0; i < 4; ++i) {
        const int q = mt * 16 + gr * 4 + i;
        partial += qt[(b * 64 + q) * 512 + d] * c[mt][nt][i];
      }
    }
    partial += __shfl_xor(partial, 16);
    partial += __shfl_xor(partial, 32);
    const float val = vt[(b * 64 + v) * 512 + d] * partial;
    if (lane < 16) Lp[((size_t)(b * 64 + v)) * 512 + d] = val;
  }
}

// ---------------- K5: reduce logits over v ----------------
__global__ __launch_bounds__(512) void k_lred(const float* __restrict__ Lp, float* __restrict__ Lraw)
{
  const int b = blockIdx.x, d = threadIdx.x;
  float s = 0.f;
  for (int v = 0; v < 64; ++v) s += Lp[(size_t)(b * 64 + v) * 512 + d];
  Lraw[b * 512 + d] = s;
}

// ---------------- K6: batchnorm over batch dim ----------------
__global__ __launch_bounds__(512) void k_bn(
    const float* __restrict__ Lraw, const float* __restrict__ gamma,
    const float* __restrict__ beta, float* __restrict__ lout)
{
  const int d = threadIdx.x;
  float x[16]; float mu = 0.f;
  #pragma unroll
  for (int b = 0; b < 16; ++b) { x[b] = Lraw[b * 512 + d]; mu += x[b]; }
  mu *= (1.f / 16.f);
  float var = 0.f;
  #pragma unroll
  for (int b = 0; b < 16; ++b) { float t = x[b] - mu; var += t * t; }
  var *= (1.f / 16.f);
  const float sc = gamma[d] / sqrtf(var + 1e-5f);
  const float bt = beta[d];
  #pragma unroll
  for (int b = 0; b < 16; ++b) lout[b * 512 + d] = (x[b] - mu) * sc + bt;
}

extern "C" void kernel_launch(void* const* d_in, const int* in_sizes, int n_in,
                              void* d_out, int out_size, void* d_ws, size_t ws_size,
                              hipStream_t stream)
{
  const float* v    = (const float*)d_in[0];
  const float* q    = (const float*)d_in[1];
  const float* a    = (const float*)d_in[2];
  const float* Vv   = (const float*)d_in[3];
  const float* gv   = (const float*)d_in[4];
  const float* bv   = (const float*)d_in[5];
  const float* Vq   = (const float*)d_in[6];
  const float* gq   = (const float*)d_in[7];
  const float* bq   = (const float*)d_in[8];
  const float* Va   = (const float*)d_in[9];
  const float* ga   = (const float*)d_in[10];
  const float* ba   = (const float*)d_in[11];
  const float* Vnv  = (const float*)d_in[12];
  const float* gnv  = (const float*)d_in[13];
  const float* bnv  = (const float*)d_in[14];
  const float* Vnqa = (const float*)d_in[15];
  const float* gnqa = (const float*)d_in[16];
  const float* bnqa = (const float*)d_in[17];
  const float* Tg   = (const float*)d_in[18];
  const float* gamma= (const float*)d_in[19];
  const float* beta = (const float*)d_in[20];

  float* ws   = (float*)d_ws;
  unsigned short* hb = (unsigned short*)(ws + WS_H);
  float* fout = (float*)d_out;
  float* lout = fout + (size_t)16 * 64 * 64 * 64 * 2;

  k_norms_part<<<320, 256, 0, stream>>>(Vv, Vq, Va, Vnv, Vnqa, ws + WS_PRT);
  k_norms_fin<<<19, 64, 0, stream>>>(ws + WS_PRT, ws + WS_NRM);
  k_inconv16<<<dim3(64, 3), 256, 0, stream>>>(v, q, a, hb + H_IN16);
  k_wconv16<<<dim3(32, 3), 256, 0, stream>>>(Vv, Vq, Va, gv, gq, ga, ws + WS_NRM, hb + H_WB16);
  k_wnconv16<<<64, 256, 0, stream>>>(Vnv, Vnqa, gnv, gnqa, ws + WS_NRM, hb + H_WN16);
  k_repack2b<<<128, 256, 0, stream>>>(Tg, hb + H_T2);
  k_proj16<<<dim3(8, 16, 3), 256, 0, stream>>>(hb + H_IN16, hb + H_WB16, bv, bq, ba,
                                               ws + WS_VT, ws + WS_QT, ws + WS_AT,
                                               hb + H_RP16, hb + H_AT16);
  k_rproj16<<<dim3(8, 16, 3), 256, 0, stream>>>(hb + H_RP16, hb + H_WN16, bnv, bnqa,
                                                hb + H_VRL, hb + H_QR2, hb + H_AR2);
  k_tucker16<<<dim3(16, 8, 2), 512, 0, stream>>>(hb + H_VRL, hb + H_QR2, hb + H_AR2,
                                                 hb + H_T2, fout);
  k_logits2<<<dim3(64, 16), 512, 0, stream>>>(ws + WS_VT, ws + WS_QT,
                                              hb + H_AT16, fout, ws + WS_LP);
  k_lred<<<16, 512, 0, stream>>>(ws + WS_LP, ws + WS_LR);
  k_bn<<<1, 512, 0, stream>>>(ws + WS_LR, gamma, beta, lout);
}